// Round 5
// baseline (299.466 us; speedup 1.0000x reference)
//
#include <hip/hip_runtime.h>
#include <hip/hip_bf16.h>
#include <cstdio>

#define NB 2
#define NN 4096
#define NC 64
#define NQ 16
#define POS_COEF 0.1f

// ---- workspace layout (float offsets) ----
#define OFF_QT   0u            // [B][N][16] row-major q
#define OFF_QK   131072u       // [B][16][N] planar k-major q (coalesced stream)
#define OFF_XYZ4 262144u       // [B][N][4]  row-major xyz+sq
#define OFF_XYZK 294912u       // [B][4][N]  planar xyz+sq
#define OFF_IRS1 327680u       // [B][N]
#define OFF_IRS2 335872u       // [B][N]
#define OFF_THR  344064u       // [B][N]
#define OFF_ICS1 352256u       // [B][N]  1/(1e-9+cs1)
#define OFF_FLAG 360448u       // [16]
#define OFF_XVB  360464u       // [B][64][N] bf16 (262144 floats)
// --- zeroed region below ---
#define OFF_SUMS 622608u       // [B][4]
#define OFF_GN   622616u       // [2][B][8]
#define OFF_CS2  622648u       // [B][N] colsum of local
#define OFF_GMA  630840u       // [B][N][64]  G1/combined gma -> res in k8
#define OFF_G2   1155128u      // [B][N][64]  G2 (fallback path only)
#define WS_TOTAL 1679416u
#define ZERO_F   (WS_TOTAL - OFF_SUMS)
// --- optional materialized exp matrix (bf16), used iff ws_size permits ---
#define OFF_A0   1679424u      // [B][N][N] bf16 exp(corr)     (16777216 floats)
#define BIG_F    18456640u     // end of a0 (ae no longer materialized)

using bf16x8 = __attribute__((ext_vector_type(8))) short;
using f32x4v = __attribute__((ext_vector_type(4))) float;

__device__ __forceinline__ float rcpf_(float x) { return __builtin_amdgcn_rcpf(x); }
__device__ __forceinline__ unsigned short f2bf(float x) {
  __hip_bfloat16 h = __float2bfloat16(x);
  return *(unsigned short*)&h;
}
__device__ __forceinline__ float bf2f(unsigned short u) {
  unsigned v = ((unsigned)u) << 16;
  return __builtin_bit_cast(float, v);
}

__device__ __forceinline__ float ldin(const void* p, size_t i, bool f32) {
  return f32 ? ((const float*)p)[i]
             : __bfloat162float(((const __hip_bfloat16*)p)[i]);
}

// Shared recompute of ae[m][n] = bf16(exp(l0)) from the rounded a0 value.
// Used by p3r (irs2), p4 (cs2) and k7n (staging) so all three are
// bit-consistent with each other.
__device__ __forceinline__ unsigned short ae_bits(
    unsigned short a0u, float r1, float ic, float4 pm,
    float px, float py, float pz, float pw, float th) {
  float a1v = bf2f(a0u) * r1 * ic;
  float dd = pm.w + pw - 2.f * (pm.x * px + pm.y * py + pm.z * pz);
  dd = fmaxf(dd, 0.f);
  float l0 = (dd <= th) ? a1v : 0.f;
  return f2bf(__expf(l0));
}

// 16-term fma tree, named float4 row against named float4 row
#define DOT16M(A0,A1,A2,A3,B0,B1,B2,B3) \
  fmaf((A0).x,(B0).x, fmaf((A0).y,(B0).y, fmaf((A0).z,(B0).z, fmaf((A0).w,(B0).w, \
  fmaf((A1).x,(B1).x, fmaf((A1).y,(B1).y, fmaf((A1).z,(B1).z, fmaf((A1).w,(B1).w, \
  fmaf((A2).x,(B2).x, fmaf((A2).y,(B2).y, fmaf((A2).z,(B2).z, fmaf((A2).w,(B2).w, \
  fmaf((A3).x,(B3).x, fmaf((A3).y,(B3).y, fmaf((A3).z,(B3).z, (A3).w*(B3).w)))))))))))))))

// dot of named row (M0..M3) against column C of k-planes k0..k15
#define DOTC(M0,M1,M2,M3,C) \
  fmaf((M0).x,k0.C, fmaf((M0).y,k1.C, fmaf((M0).z,k2.C, fmaf((M0).w,k3.C, \
  fmaf((M1).x,k4.C, fmaf((M1).y,k5.C, fmaf((M1).z,k6.C, fmaf((M1).w,k7.C, \
  fmaf((M2).x,k8.C, fmaf((M2).y,k9.C, fmaf((M2).z,k10.C, fmaf((M2).w,k11.C, \
  fmaf((M3).x,k12.C, fmaf((M3).y,k13.C, fmaf((M3).z,k14.C, (M3).w*k15.C)))))))))))))))

// planar k-plane loads: lanes read consecutive float4 -> fully coalesced
#define LKPL(base, n0) \
  const float4 k0  = *(const float4*)((base) + 0*NN  + (n0)); \
  const float4 k1  = *(const float4*)((base) + 1*NN  + (n0)); \
  const float4 k2  = *(const float4*)((base) + 2*NN  + (n0)); \
  const float4 k3  = *(const float4*)((base) + 3*NN  + (n0)); \
  const float4 k4  = *(const float4*)((base) + 4*NN  + (n0)); \
  const float4 k5  = *(const float4*)((base) + 5*NN  + (n0)); \
  const float4 k6  = *(const float4*)((base) + 6*NN  + (n0)); \
  const float4 k7  = *(const float4*)((base) + 7*NN  + (n0)); \
  const float4 k8  = *(const float4*)((base) + 8*NN  + (n0)); \
  const float4 k9  = *(const float4*)((base) + 9*NN  + (n0)); \
  const float4 k10 = *(const float4*)((base) + 10*NN + (n0)); \
  const float4 k11 = *(const float4*)((base) + 11*NN + (n0)); \
  const float4 k12 = *(const float4*)((base) + 12*NN + (n0)); \
  const float4 k13 = *(const float4*)((base) + 13*NN + (n0)); \
  const float4 k14 = *(const float4*)((base) + 14*NN + (n0)); \
  const float4 k15 = *(const float4*)((base) + 15*NN + (n0));

#define WRED(s) { s += __shfl_xor(s, 32); s += __shfl_xor(s, 16); \
  s += __shfl_xor(s, 8); s += __shfl_xor(s, 4); s += __shfl_xor(s, 2); s += __shfl_xor(s, 1); }

#define LQROW(v, base) \
  const float4 v##0 = *(const float4*)((base)); \
  const float4 v##1 = *(const float4*)((base) + 4); \
  const float4 v##2 = *(const float4*)((base) + 8); \
  const float4 v##3 = *(const float4*)((base) + 12);

// K0: detect input dtype
__global__ __launch_bounds__(256) void k0_detect(
    const unsigned short* __restrict__ ctx_u16, float* __restrict__ flag) {
  const int tid = threadIdx.x;
  int bad = 0;
  for (int i = tid; i < 8192; i += 256) {
    const unsigned short u = ctx_u16[i];
    const int e = (u >> 7) & 0xFF;
    if (e >= 134 || (e >= 1 && e <= 100)) bad++;
  }
  __shared__ int cnt;
  if (tid == 0) cnt = 0;
  __syncthreads();
  atomicAdd(&cnt, bad);
  __syncthreads();
  if (tid == 0) flag[0] = (cnt > 256) ? 1.0f : 0.0f;
}

// K1: q = Wqk @ ctx (row-major + planar), xyz (row + planar), batch sums
__global__ __launch_bounds__(256) void k1_q_xyz(
    const void* __restrict__ ctx, const void* __restrict__ xyz,
    const void* __restrict__ wqk, const float* __restrict__ flag,
    float* __restrict__ qt, float* __restrict__ qk,
    float* __restrict__ xyz4, float* __restrict__ xyzk,
    float* __restrict__ sums) {
  const bool f32 = flag[0] > 0.5f;
  const int tid = threadIdx.x;
  const int b = blockIdx.x >> 4;
  const int n = ((blockIdx.x & 15) << 8) + tid;
  __shared__ float wqT[NQ * NC];  // [c][o]
  for (int i = tid; i < NQ * NC; i += 256) {
    int o = i & 15, c = i >> 4;
    wqT[c * 16 + o] = ldin(wqk, o * 64 + c, f32);
  }
  __syncthreads();
  float4 a0 = {0,0,0,0}, a1 = {0,0,0,0}, a2 = {0,0,0,0}, a3 = {0,0,0,0};
  const size_t cbase = (size_t)b * 64 * NN + n;
#pragma unroll 4
  for (int c = 0; c < 64; ++c) {
    float x = ldin(ctx, cbase + (size_t)c * NN, f32);
    const float4 w0 = *(const float4*)(wqT + c * 16 + 0);
    const float4 w1 = *(const float4*)(wqT + c * 16 + 4);
    const float4 w2 = *(const float4*)(wqT + c * 16 + 8);
    const float4 w3 = *(const float4*)(wqT + c * 16 + 12);
    a0.x = fmaf(w0.x, x, a0.x); a0.y = fmaf(w0.y, x, a0.y); a0.z = fmaf(w0.z, x, a0.z); a0.w = fmaf(w0.w, x, a0.w);
    a1.x = fmaf(w1.x, x, a1.x); a1.y = fmaf(w1.y, x, a1.y); a1.z = fmaf(w1.z, x, a1.z); a1.w = fmaf(w1.w, x, a1.w);
    a2.x = fmaf(w2.x, x, a2.x); a2.y = fmaf(w2.y, x, a2.y); a2.z = fmaf(w2.z, x, a2.z); a2.w = fmaf(w2.w, x, a2.w);
    a3.x = fmaf(w3.x, x, a3.x); a3.y = fmaf(w3.y, x, a3.y); a3.z = fmaf(w3.z, x, a3.z); a3.w = fmaf(w3.w, x, a3.w);
  }
  float* qp = qt + (size_t)(b * NN + n) * 16;
  *(float4*)(qp + 0) = a0; *(float4*)(qp + 4) = a1;
  *(float4*)(qp + 8) = a2; *(float4*)(qp + 12) = a3;
  float* kq = qk + (size_t)b * 16 * NN + n;
  kq[0*NN]=a0.x;  kq[1*NN]=a0.y;  kq[2*NN]=a0.z;  kq[3*NN]=a0.w;
  kq[4*NN]=a1.x;  kq[5*NN]=a1.y;  kq[6*NN]=a1.z;  kq[7*NN]=a1.w;
  kq[8*NN]=a2.x;  kq[9*NN]=a2.y;  kq[10*NN]=a2.z; kq[11*NN]=a2.w;
  kq[12*NN]=a3.x; kq[13*NN]=a3.y; kq[14*NN]=a3.z; kq[15*NN]=a3.w;
  float xx = ldin(xyz, (size_t)(b * NN + n) * 3 + 0, f32);
  float yy = ldin(xyz, (size_t)(b * NN + n) * 3 + 1, f32);
  float zz = ldin(xyz, (size_t)(b * NN + n) * 3 + 2, f32);
  float4 p; p.x = xx; p.y = yy; p.z = zz; p.w = fmaf(xx, xx, fmaf(yy, yy, zz * zz));
  *(float4*)(xyz4 + (size_t)(b * NN + n) * 4) = p;
  float* kx = xyzk + (size_t)b * 4 * NN + n;
  kx[0*NN]=p.x; kx[1*NN]=p.y; kx[2*NN]=p.z; kx[3*NN]=p.w;
  float sx = p.x, sy = p.y, sz = p.z, sw = p.w;
  WRED(sx) WRED(sy) WRED(sz) WRED(sw)
  if ((tid & 63) == 0) {
    atomicAdd(&sums[b * 4 + 0], sx);
    atomicAdd(&sums[b * 4 + 1], sy);
    atomicAdd(&sums[b * 4 + 2], sz);
    atomicAdd(&sums[b * 4 + 3], sw);
  }
}

// K2: xv = Wv @ motion + bv, bf16 channel-major [b][c][n]
__global__ __launch_bounds__(256) void k2_xv(
    const void* __restrict__ mot, const void* __restrict__ wv,
    const void* __restrict__ bv, const float* __restrict__ flag,
    unsigned short* __restrict__ xvb) {
  const bool f32 = flag[0] > 0.5f;
  const int tid = threadIdx.x;
  const int b = blockIdx.x >> 6;
  const int n = ((blockIdx.x & 63) << 6) + (tid >> 2);
  const int og = tid & 3;
  __shared__ float wvT[NC * NC];
  __shared__ float bvs[NC];
  for (int i = tid; i < NC * NC; i += 256) {
    int o = i & 63, c = i >> 6;
    wvT[c * 64 + o] = ldin(wv, o * 64 + c, f32);
  }
  if (tid < 64) bvs[tid] = ldin(bv, tid, f32);
  __syncthreads();
  float4 a0 = *(const float4*)(bvs + og * 16 + 0);
  float4 a1 = *(const float4*)(bvs + og * 16 + 4);
  float4 a2 = *(const float4*)(bvs + og * 16 + 8);
  float4 a3 = *(const float4*)(bvs + og * 16 + 12);
  const size_t mbase = (size_t)b * 64 * NN + n;
#pragma unroll 4
  for (int c = 0; c < 64; ++c) {
    float x = ldin(mot, mbase + (size_t)c * NN, f32);
    const float4 w0 = *(const float4*)(wvT + c * 64 + og * 16 + 0);
    const float4 w1 = *(const float4*)(wvT + c * 64 + og * 16 + 4);
    const float4 w2 = *(const float4*)(wvT + c * 64 + og * 16 + 8);
    const float4 w3 = *(const float4*)(wvT + c * 64 + og * 16 + 12);
    a0.x = fmaf(w0.x, x, a0.x); a0.y = fmaf(w0.y, x, a0.y); a0.z = fmaf(w0.z, x, a0.z); a0.w = fmaf(w0.w, x, a0.w);
    a1.x = fmaf(w1.x, x, a1.x); a1.y = fmaf(w1.y, x, a1.y); a1.z = fmaf(w1.z, x, a1.z); a1.w = fmaf(w1.w, x, a1.w);
    a2.x = fmaf(w2.x, x, a2.x); a2.y = fmaf(w2.y, x, a2.y); a2.z = fmaf(w2.z, x, a2.z); a2.w = fmaf(w2.w, x, a2.w);
    a3.x = fmaf(w3.x, x, a3.x); a3.y = fmaf(w3.y, x, a3.y); a3.z = fmaf(w3.z, x, a3.z); a3.w = fmaf(w3.w, x, a3.w);
  }
  unsigned short* xb = xvb + (size_t)b * 64 * NN + n;
  const int o0 = og * 16;
  xb[(size_t)(o0 + 0) * NN] = f2bf(a0.x);  xb[(size_t)(o0 + 1) * NN] = f2bf(a0.y);
  xb[(size_t)(o0 + 2) * NN] = f2bf(a0.z);  xb[(size_t)(o0 + 3) * NN] = f2bf(a0.w);
  xb[(size_t)(o0 + 4) * NN] = f2bf(a1.x);  xb[(size_t)(o0 + 5) * NN] = f2bf(a1.y);
  xb[(size_t)(o0 + 6) * NN] = f2bf(a1.z);  xb[(size_t)(o0 + 7) * NN] = f2bf(a1.w);
  xb[(size_t)(o0 + 8) * NN] = f2bf(a2.x);  xb[(size_t)(o0 + 9) * NN] = f2bf(a2.y);
  xb[(size_t)(o0 +10) * NN] = f2bf(a2.z);  xb[(size_t)(o0 +11) * NN] = f2bf(a2.w);
  xb[(size_t)(o0 +12) * NN] = f2bf(a3.x);  xb[(size_t)(o0 +13) * NN] = f2bf(a3.y);
  xb[(size_t)(o0 +14) * NN] = f2bf(a3.z);  xb[(size_t)(o0 +15) * NN] = f2bf(a3.w);
}

// K2b: thr[n] = 0.1*(1e-9 + csd[n]) analytic
__global__ __launch_bounds__(256) void k2b_thr(
    const float* __restrict__ xyz4, const float* __restrict__ sums,
    float* __restrict__ thr) {
  const int idx = blockIdx.x * 256 + threadIdx.x;
  const int b = idx >> 12;
  const float4 pn = *(const float4*)(xyz4 + (size_t)idx * 4);
  const float Px = sums[b * 4 + 0], Py = sums[b * 4 + 1];
  const float Pz = sums[b * 4 + 2], S1 = sums[b * 4 + 3];
  float csd = fmaf((float)NN, pn.w, S1)
            - 2.f * (pn.x * Px + pn.y * Py + pn.z * Pz);
  thr[idx] = POS_COEF * (1e-9f + csd);
}

// ===================== fallback (round-13) p1/p3/k7 =====================

__global__ __launch_bounds__(256) void p1_rs1(
    const float* __restrict__ qt, const float* __restrict__ qk,
    float* __restrict__ irs1) {
  const int tid = threadIdx.x;
  const int b = blockIdx.x >> 8;
  const int m0 = (blockIdx.x & 255) << 4;
  const int w = tid >> 6, lane = tid & 63;
  const float* qb = qt + (size_t)b * NN * 16;
  const float* kb = qk + (size_t)b * 16 * NN;
  const int mA = m0 + w, mB = m0 + w + 4, mC = m0 + w + 8, mD = m0 + w + 12;
  LQROW(ma, qb + (size_t)mA * 16)
  LQROW(mb, qb + (size_t)mB * 16)
  LQROW(mc, qb + (size_t)mC * 16)
  LQROW(md, qb + (size_t)mD * 16)
  float sA = 0.f, sB = 0.f, sC = 0.f, sD = 0.f;
  for (int it = 0; it < 16; ++it) {
    const int n0 = (it << 8) + (lane << 2);
    LKPL(kb, n0)
    sA += __expf(fminf(DOTC(ma0,ma1,ma2,ma3,x), 80.f));
    sA += __expf(fminf(DOTC(ma0,ma1,ma2,ma3,y), 80.f));
    sA += __expf(fminf(DOTC(ma0,ma1,ma2,ma3,z), 80.f));
    sA += __expf(fminf(DOTC(ma0,ma1,ma2,ma3,w), 80.f));
    sB += __expf(fminf(DOTC(mb0,mb1,mb2,mb3,x), 80.f));
    sB += __expf(fminf(DOTC(mb0,mb1,mb2,mb3,y), 80.f));
    sB += __expf(fminf(DOTC(mb0,mb1,mb2,mb3,z), 80.f));
    sB += __expf(fminf(DOTC(mb0,mb1,mb2,mb3,w), 80.f));
    sC += __expf(fminf(DOTC(mc0,mc1,mc2,mc3,x), 80.f));
    sC += __expf(fminf(DOTC(mc0,mc1,mc2,mc3,y), 80.f));
    sC += __expf(fminf(DOTC(mc0,mc1,mc2,mc3,z), 80.f));
    sC += __expf(fminf(DOTC(mc0,mc1,mc2,mc3,w), 80.f));
    sD += __expf(fminf(DOTC(md0,md1,md2,md3,x), 80.f));
    sD += __expf(fminf(DOTC(md0,md1,md2,md3,y), 80.f));
    sD += __expf(fminf(DOTC(md0,md1,md2,md3,z), 80.f));
    sD += __expf(fminf(DOTC(md0,md1,md2,md3,w), 80.f));
  }
  WRED(sA) WRED(sB) WRED(sC) WRED(sD)
  if (lane == 0) {
    irs1[b * NN + mA] = rcpf_(sA);
    irs1[b * NN + mB] = rcpf_(sB);
    irs1[b * NN + mC] = rcpf_(sC);
    irs1[b * NN + mD] = rcpf_(sD);
  }
}

__global__ __launch_bounds__(256) void p3_rs2(
    const float* __restrict__ qt, const float* __restrict__ qk,
    const float* __restrict__ xyz4, const float* __restrict__ xyzk,
    const float* __restrict__ irs1, const float* __restrict__ ics1,
    const float* __restrict__ thr, float* __restrict__ irs2) {
  const int tid = threadIdx.x;
  const int b = blockIdx.x >> 8;
  const int m0 = (blockIdx.x & 255) << 4;
  const int w = tid >> 6, lane = tid & 63;
  const float* qb = qt + (size_t)b * NN * 16;
  const float* kb = qk + (size_t)b * 16 * NN;
  const float* xk = xyzk + (size_t)b * 4 * NN;
  const int mA = m0 + w, mB = m0 + w + 4, mC = m0 + w + 8, mD = m0 + w + 12;
  LQROW(ma, qb + (size_t)mA * 16)
  LQROW(mb, qb + (size_t)mB * 16)
  LQROW(mc, qb + (size_t)mC * 16)
  LQROW(md, qb + (size_t)mD * 16)
  const float4 pmA = *(const float4*)(xyz4 + ((size_t)b * NN + mA) * 4);
  const float4 pmB = *(const float4*)(xyz4 + ((size_t)b * NN + mB) * 4);
  const float4 pmC = *(const float4*)(xyz4 + ((size_t)b * NN + mC) * 4);
  const float4 pmD = *(const float4*)(xyz4 + ((size_t)b * NN + mD) * 4);
  const float rA = irs1[b * NN + mA];
  const float rB = irs1[b * NN + mB];
  const float rC = irs1[b * NN + mC];
  const float rD = irs1[b * NN + mD];
  float sA = 0.f, sB = 0.f, sC = 0.f, sD = 0.f;
#define P3C(S, M0,M1,M2,M3, PM, R, C) { \
    float corr_ = DOTC(M0,M1,M2,M3,C); \
    float a1v_ = __expf(fminf(corr_, 80.f)) * (R) * ic.C; \
    float dd_ = (PM).w + pw.C - 2.f * ((PM).x * px.C + (PM).y * py.C + (PM).z * pz.C); \
    dd_ = fmaxf(dd_, 0.f); \
    float l0_ = (dd_ <= th.C) ? a1v_ : 0.f; \
    S += __expf(l0_); }
  for (int it = 0; it < 16; ++it) {
    const int n0 = (it << 8) + (lane << 2);
    LKPL(kb, n0)
    const float4 px = *(const float4*)(xk + 0*NN + n0);
    const float4 py = *(const float4*)(xk + 1*NN + n0);
    const float4 pz = *(const float4*)(xk + 2*NN + n0);
    const float4 pw = *(const float4*)(xk + 3*NN + n0);
    const float4 ic = *(const float4*)(ics1 + b * NN + n0);
    const float4 th = *(const float4*)(thr + b * NN + n0);
    P3C(sA, ma0,ma1,ma2,ma3, pmA, rA, x)
    P3C(sA, ma0,ma1,ma2,ma3, pmA, rA, y)
    P3C(sA, ma0,ma1,ma2,ma3, pmA, rA, z)
    P3C(sA, ma0,ma1,ma2,ma3, pmA, rA, w)
    P3C(sB, mb0,mb1,mb2,mb3, pmB, rB, x)
    P3C(sB, mb0,mb1,mb2,mb3, pmB, rB, y)
    P3C(sB, mb0,mb1,mb2,mb3, pmB, rB, z)
    P3C(sB, mb0,mb1,mb2,mb3, pmB, rB, w)
    P3C(sC, mc0,mc1,mc2,mc3, pmC, rC, x)
    P3C(sC, mc0,mc1,mc2,mc3, pmC, rC, y)
    P3C(sC, mc0,mc1,mc2,mc3, pmC, rC, z)
    P3C(sC, mc0,mc1,mc2,mc3, pmC, rC, w)
    P3C(sD, md0,md1,md2,md3, pmD, rD, x)
    P3C(sD, md0,md1,md2,md3, pmD, rD, y)
    P3C(sD, md0,md1,md2,md3, pmD, rD, z)
    P3C(sD, md0,md1,md2,md3, pmD, rD, w)
  }
#undef P3C
  WRED(sA) WRED(sB) WRED(sC) WRED(sD)
  if (lane == 0) {
    irs2[b * NN + mA] = rcpf_(sA);
    irs2[b * NN + mB] = rcpf_(sB);
    irs2[b * NN + mC] = rcpf_(sC);
    irs2[b * NN + mD] = rcpf_(sD);
  }
}

__global__ __launch_bounds__(256) void k7_gma(
    const float* __restrict__ qt, const float* __restrict__ xyz4,
    const unsigned short* __restrict__ xvb,
    const float* __restrict__ irs1, const float* __restrict__ irs2,
    const float* __restrict__ ics1, const float* __restrict__ thr,
    float* __restrict__ g1, float* __restrict__ g2, float* __restrict__ cs2) {
  const int tid = threadIdx.x;
  const int bid = blockIdx.x;
  const int msl = bid & 7;
  const int nb = (bid >> 3) & 63;
  const int b = bid >> 9;
  const int n0 = nb << 6;
  const int mstart = msl << 9;
  __shared__ __align__(16) unsigned short attns1[64 * 72];
  __shared__ __align__(16) unsigned short attns2[64 * 72];
  __shared__ __align__(16) unsigned short xvs[64 * 72];
  const float* qb = qt + (size_t)b * NN * 16;
  const float* pb = xyz4 + (size_t)b * NN * 4;
  const int ni = tid & 63, aw = tid >> 6;
  const int na = n0 + ni;
  const float* qnp = qb + (size_t)na * 16;
  LQROW(q, qnp)
  const float4 pn = *(const float4*)(pb + (size_t)na * 4);
  const float ics1n = ics1[b * NN + na];
  const float thr_n = thr[b * NN + na];
  const int lane = tid & 63, wv = tid >> 6;
  const int lr = lane & 15, quad = lane >> 4;
  const int nw = wv << 4;
  f32x4v acc0 = {0,0,0,0}, acc1 = {0,0,0,0}, acc2 = {0,0,0,0}, acc3 = {0,0,0,0};
  f32x4v d0 = {0,0,0,0}, d1 = {0,0,0,0}, d2 = {0,0,0,0}, d3 = {0,0,0,0};
  float csacc = 0.f;
#define COMPA(MOFF, D1, D2) { \
    const int m_ = __builtin_amdgcn_readfirstlane(mw + (MOFF)); \
    const float* qm_ = qb + (size_t)m_ * 16; \
    LQROW(wq, qm_) \
    float corr_ = DOT16M(q0, q1, q2, q3, wq0, wq1, wq2, wq3); \
    const float4 pm_ = *(const float4*)(pb + (size_t)m_ * 4); \
    float a1v_ = __expf(fminf(corr_, 80.f)) * irs1[b * NN + m_] * ics1n; \
    float dd_ = pm_.w + pn.w - 2.f * (pm_.x * pn.x + pm_.y * pn.y + pm_.z * pn.z); \
    dd_ = fmaxf(dd_, 0.f); \
    float l0_ = (dd_ <= thr_n) ? a1v_ : 0.f; \
    float l2n_ = __expf(l0_) * irs2[b * NN + m_]; \
    D1 = f2bf(a1v_); D2 = f2bf(l2n_); csacc += l2n_; }
  for (int mt = 0; mt < 8; ++mt) {
    const int m0 = mstart + (mt << 6);
    __syncthreads();
    {
      const int c = tid >> 2, part = tid & 3;
      const unsigned short* src = xvb + ((size_t)b * 64 + c) * NN + m0 + part * 16;
      unsigned short* dst = xvs + c * 72 + part * 16;
      *(uint4*)dst = *(const uint4*)src;
      *(uint4*)(dst + 8) = *(const uint4*)(src + 8);
    }
    const int mw = m0 + (aw << 4);
#pragma unroll
    for (int g = 0; g < 4; ++g) {
      ushort4 u1, u2;
      COMPA(g * 4 + 0, u1.x, u2.x)
      COMPA(g * 4 + 1, u1.y, u2.y)
      COMPA(g * 4 + 2, u1.z, u2.z)
      COMPA(g * 4 + 3, u1.w, u2.w)
      *(ushort4*)(attns1 + ni * 72 + (aw << 4) + (g << 2)) = u1;
      *(ushort4*)(attns2 + ni * 72 + (aw << 4) + (g << 2)) = u2;
    }
    __syncthreads();
#pragma unroll
    for (int h = 0; h < 2; ++h) {
      const bf16x8 a1 = *(const bf16x8*)(attns1 + (nw + lr) * 72 + h * 32 + quad * 8);
      const bf16x8 a2 = *(const bf16x8*)(attns2 + (nw + lr) * 72 + h * 32 + quad * 8);
      const bf16x8 b0 = *(const bf16x8*)(xvs + (lr) * 72 + h * 32 + quad * 8);
      const bf16x8 b1 = *(const bf16x8*)(xvs + (16 + lr) * 72 + h * 32 + quad * 8);
      const bf16x8 b2 = *(const bf16x8*)(xvs + (32 + lr) * 72 + h * 32 + quad * 8);
      const bf16x8 b3 = *(const bf16x8*)(xvs + (48 + lr) * 72 + h * 32 + quad * 8);
      acc0 = __builtin_amdgcn_mfma_f32_16x16x32_bf16(a1, b0, acc0, 0, 0, 0);
      acc1 = __builtin_amdgcn_mfma_f32_16x16x32_bf16(a1, b1, acc1, 0, 0, 0);
      acc2 = __builtin_amdgcn_mfma_f32_16x16x32_bf16(a1, b2, acc2, 0, 0, 0);
      acc3 = __builtin_amdgcn_mfma_f32_16x16x32_bf16(a1, b3, acc3, 0, 0, 0);
      d0 = __builtin_amdgcn_mfma_f32_16x16x32_bf16(a2, b0, d0, 0, 0, 0);
      d1 = __builtin_amdgcn_mfma_f32_16x16x32_bf16(a2, b1, d1, 0, 0, 0);
      d2 = __builtin_amdgcn_mfma_f32_16x16x32_bf16(a2, b2, d2, 0, 0, 0);
      d3 = __builtin_amdgcn_mfma_f32_16x16x32_bf16(a2, b3, d3, 0, 0, 0);
    }
  }
#undef COMPA
  atomicAdd(&cs2[b * NN + na], csacc);
#define EPI(ACC, DST, CT) { \
    float* g_ = (DST) + ((size_t)b * NN + n0 + nw + (quad << 2)) * 64 + (CT) * 16 + lr; \
    atomicAdd(g_ + 0,   ACC[0]); \
    atomicAdd(g_ + 64,  ACC[1]); \
    atomicAdd(g_ + 128, ACC[2]); \
    atomicAdd(g_ + 192, ACC[3]); }
  EPI(acc0, g1, 0) EPI(acc1, g1, 1) EPI(acc2, g1, 2) EPI(acc3, g1, 3)
  EPI(d0, g2, 0) EPI(d1, g2, 1) EPI(d2, g2, 2) EPI(d3, g2, 3)
#undef EPI
}

// ============ materialized-a0 path (used iff ws_size permits) ============

// P1W: stores a0[m][n]=bf16(exp(corr)), sums the ROUNDED values.
__global__ __launch_bounds__(256) void p1w_rs1(
    const float* __restrict__ qt, const float* __restrict__ qk,
    float* __restrict__ irs1, unsigned short* __restrict__ a0g) {
  const int tid = threadIdx.x;
  const int b = blockIdx.x >> 9;
  const int m0 = (blockIdx.x & 511) << 3;
  const int w = tid >> 6, lane = tid & 63;
  const float* qb = qt + (size_t)b * NN * 16;
  const float* kb = qk + (size_t)b * 16 * NN;
  unsigned short* ab = a0g + (size_t)b * NN * NN;
  const int mA = m0 + (w << 1), mB = mA + 1;
  LQROW(ma, qb + (size_t)mA * 16)
  LQROW(mb, qb + (size_t)mB * 16)
  float sA = 0.f, sB = 0.f;
  for (int it = 0; it < 8; ++it) {
    const int n0 = (it << 9) + (lane << 3);
    float4 aAl = {0,0,0,0}, aAh = {0,0,0,0}, aBl = {0,0,0,0}, aBh = {0,0,0,0};
#define PLN(QA_, QB_, P) { \
      const float4 kl_ = *(const float4*)(kb + (size_t)(P) * NN + n0); \
      const float4 kh_ = *(const float4*)(kb + (size_t)(P) * NN + n0 + 4); \
      aAl.x = fmaf(QA_, kl_.x, aAl.x); aAl.y = fmaf(QA_, kl_.y, aAl.y); \
      aAl.z = fmaf(QA_, kl_.z, aAl.z); aAl.w = fmaf(QA_, kl_.w, aAl.w); \
      aAh.x = fmaf(QA_, kh_.x, aAh.x); aAh.y = fmaf(QA_, kh_.y, aAh.y); \
      aAh.z = fmaf(QA_, kh_.z, aAh.z); aAh.w = fmaf(QA_, kh_.w, aAh.w); \
      aBl.x = fmaf(QB_, kl_.x, aBl.x); aBl.y = fmaf(QB_, kl_.y, aBl.y); \
      aBl.z = fmaf(QB_, kl_.z, aBl.z); aBl.w = fmaf(QB_, kl_.w, aBl.w); \
      aBh.x = fmaf(QB_, kh_.x, aBh.x); aBh.y = fmaf(QB_, kh_.y, aBh.y); \
      aBh.z = fmaf(QB_, kh_.z, aBh.z); aBh.w = fmaf(QB_, kh_.w, aBh.w); }
    PLN(ma0.x, mb0.x, 0)   PLN(ma0.y, mb0.y, 1)
    PLN(ma0.z, mb0.z, 2)   PLN(ma0.w, mb0.w, 3)
    PLN(ma1.x, mb1.x, 4)   PLN(ma1.y, mb1.y, 5)
    PLN(ma1.z, mb1.z, 6)   PLN(ma1.w, mb1.w, 7)
    PLN(ma2.x, mb2.x, 8)   PLN(ma2.y, mb2.y, 9)
    PLN(ma2.z, mb2.z, 10)  PLN(ma2.w, mb2.w, 11)
    PLN(ma3.x, mb3.x, 12)  PLN(ma3.y, mb3.y, 13)
    PLN(ma3.z, mb3.z, 14)  PLN(ma3.w, mb3.w, 15)
#undef PLN
#define EX8(AL, AH, S, ROWPTR) { \
      const unsigned short u0_ = f2bf(__expf(fminf((AL).x, 80.f))); \
      const unsigned short u1_ = f2bf(__expf(fminf((AL).y, 80.f))); \
      const unsigned short u2_ = f2bf(__expf(fminf((AL).z, 80.f))); \
      const unsigned short u3_ = f2bf(__expf(fminf((AL).w, 80.f))); \
      const unsigned short u4_ = f2bf(__expf(fminf((AH).x, 80.f))); \
      const unsigned short u5_ = f2bf(__expf(fminf((AH).y, 80.f))); \
      const unsigned short u6_ = f2bf(__expf(fminf((AH).z, 80.f))); \
      const unsigned short u7_ = f2bf(__expf(fminf((AH).w, 80.f))); \
      uint4 U_; \
      U_.x = (unsigned)u0_ | ((unsigned)u1_ << 16); \
      U_.y = (unsigned)u2_ | ((unsigned)u3_ << 16); \
      U_.z = (unsigned)u4_ | ((unsigned)u5_ << 16); \
      U_.w = (unsigned)u6_ | ((unsigned)u7_ << 16); \
      *(uint4*)((ROWPTR) + n0) = U_; \
      S += bf2f(u0_) + bf2f(u1_) + bf2f(u2_) + bf2f(u3_) \
         + bf2f(u4_) + bf2f(u5_) + bf2f(u6_) + bf2f(u7_); }
    EX8(aAl, aAh, sA, ab + (size_t)mA * NN)
    EX8(aBl, aBh, sB, ab + (size_t)mB * NN)
#undef EX8
  }
  WRED(sA) WRED(sB)
  if (lane == 0) {
    irs1[b * NN + mA] = rcpf_(sA);
    irs1[b * NN + mB] = rcpf_(sB);
  }
}

// P2R: cs1 via SYMMETRY of corr: cs1[n] = sum_m a0[n][m]*irs1[m].
__global__ __launch_bounds__(256) void p2r_cs1(
    const unsigned short* __restrict__ a0g, const float* __restrict__ irs1,
    float* __restrict__ ics1) {
  const int tid = threadIdx.x;
  const int w = tid >> 6, l = tid & 63;
  const int bi = blockIdx.x;                 // 0..2047
  const int b = bi >> 10;
  const int n = ((bi & 1023) << 2) + w;      // 4 rows per block, 1 per wave
  const unsigned short* row = a0g + ((size_t)b * NN + n) * NN;
  const float* ir = irs1 + b * NN;
  float s = 0.f;
#pragma unroll
  for (int it = 0; it < 8; ++it) {
    const int m = (it << 9) + (l << 3);
    const uint4 u = *(const uint4*)(row + m);
    const float4 i0 = *(const float4*)(ir + m);
    const float4 i1 = *(const float4*)(ir + m + 4);
    s = fmaf(bf2f((unsigned short)(u.x & 0xffffu)), i0.x, s);
    s = fmaf(bf2f((unsigned short)(u.x >> 16)),     i0.y, s);
    s = fmaf(bf2f((unsigned short)(u.y & 0xffffu)), i0.z, s);
    s = fmaf(bf2f((unsigned short)(u.y >> 16)),     i0.w, s);
    s = fmaf(bf2f((unsigned short)(u.z & 0xffffu)), i1.x, s);
    s = fmaf(bf2f((unsigned short)(u.z >> 16)),     i1.y, s);
    s = fmaf(bf2f((unsigned short)(u.w & 0xffffu)), i1.z, s);
    s = fmaf(bf2f((unsigned short)(u.w >> 16)),     i1.w, s);
  }
  WRED(s)
  if (l == 0) ics1[b * NN + n] = rcpf_(1e-9f + s);
}

// P3R: irs2 row sums WITHOUT materializing ae (recompute via ae_bits).
// Reads a0 rows (16B/lane); no stores.  2 rows/wave, 1024 blocks.
__global__ __launch_bounds__(256) void p3r_rs2(
    const float* __restrict__ xyz4, const float* __restrict__ xyzk,
    const float* __restrict__ irs1, const float* __restrict__ ics1,
    const float* __restrict__ thr, float* __restrict__ irs2,
    const unsigned short* __restrict__ a0g) {
  const int tid = threadIdx.x;
  const int b = blockIdx.x >> 9;
  const int m0 = (blockIdx.x & 511) << 3;
  const int w = tid >> 6, lane = tid & 63;
  const float* xk = xyzk + (size_t)b * 4 * NN;
  const unsigned short* ab = a0g + (size_t)b * NN * NN;
  const int mA = m0 + (w << 1), mB = mA + 1;
  const float4 pmA = *(const float4*)(xyz4 + ((size_t)b * NN + mA) * 4);
  const float4 pmB = *(const float4*)(xyz4 + ((size_t)b * NN + mB) * 4);
  const float rA = irs1[b * NN + mA];
  const float rB = irs1[b * NN + mB];
  float sA = 0.f, sB = 0.f;
  for (int it = 0; it < 8; ++it) {
    const int n0 = (it << 9) + (lane << 3);
    const float4 pxl = *(const float4*)(xk + 0*NN + n0);
    const float4 pxh = *(const float4*)(xk + 0*NN + n0 + 4);
    const float4 pyl = *(const float4*)(xk + 1*NN + n0);
    const float4 pyh = *(const float4*)(xk + 1*NN + n0 + 4);
    const float4 pzl = *(const float4*)(xk + 2*NN + n0);
    const float4 pzh = *(const float4*)(xk + 2*NN + n0 + 4);
    const float4 pwl = *(const float4*)(xk + 3*NN + n0);
    const float4 pwh = *(const float4*)(xk + 3*NN + n0 + 4);
    const float4 icl = *(const float4*)(ics1 + b * NN + n0);
    const float4 ich = *(const float4*)(ics1 + b * NN + n0 + 4);
    const float4 thl = *(const float4*)(thr + b * NN + n0);
    const float4 thh = *(const float4*)(thr + b * NN + n0 + 4);
    const uint4 rAu = *(const uint4*)(ab + (size_t)mA * NN + n0);
    const uint4 rBu = *(const uint4*)(ab + (size_t)mB * NN + n0);
#define P3R1(S, A0W, SH, PM, R, PX, PY, PZ, PW, IC, TH) \
    S += bf2f(ae_bits((unsigned short)(((A0W) >> (SH)) & 0xffffu), (R), (IC), \
                      (PM), (PX), (PY), (PZ), (PW), (TH)));
    P3R1(sA, rAu.x, 0,  pmA, rA, pxl.x, pyl.x, pzl.x, pwl.x, icl.x, thl.x)
    P3R1(sA, rAu.x, 16, pmA, rA, pxl.y, pyl.y, pzl.y, pwl.y, icl.y, thl.y)
    P3R1(sA, rAu.y, 0,  pmA, rA, pxl.z, pyl.z, pzl.z, pwl.z, icl.z, thl.z)
    P3R1(sA, rAu.y, 16, pmA, rA, pxl.w, pyl.w, pzl.w, pwl.w, icl.w, thl.w)
    P3R1(sA, rAu.z, 0,  pmA, rA, pxh.x, pyh.x, pzh.x, pwh.x, ich.x, thh.x)
    P3R1(sA, rAu.z, 16, pmA, rA, pxh.y, pyh.y, pzh.y, pwh.y, ich.y, thh.y)
    P3R1(sA, rAu.w, 0,  pmA, rA, pxh.z, pyh.z, pzh.z, pwh.z, ich.z, thh.z)
    P3R1(sA, rAu.w, 16, pmA, rA, pxh.w, pyh.w, pzh.w, pwh.w, ich.w, thh.w)
    P3R1(sB, rBu.x, 0,  pmB, rB, pxl.x, pyl.x, pzl.x, pwl.x, icl.x, thl.x)
    P3R1(sB, rBu.x, 16, pmB, rB, pxl.y, pyl.y, pzl.y, pwl.y, icl.y, thl.y)
    P3R1(sB, rBu.y, 0,  pmB, rB, pxl.z, pyl.z, pzl.z, pwl.z, icl.z, thl.z)
    P3R1(sB, rBu.y, 16, pmB, rB, pxl.w, pyl.w, pzl.w, pwl.w, icl.w, thl.w)
    P3R1(sB, rBu.z, 0,  pmB, rB, pxh.x, pyh.x, pzh.x, pwh.x, ich.x, thh.x)
    P3R1(sB, rBu.z, 16, pmB, rB, pxh.y, pyh.y, pzh.y, pwh.y, ich.y, thh.y)
    P3R1(sB, rBu.w, 0,  pmB, rB, pxh.z, pyh.z, pzh.z, pwh.z, ich.z, thh.z)
    P3R1(sB, rBu.w, 16, pmB, rB, pxh.w, pyh.w, pzh.w, pwh.w, ich.w, thh.w)
#undef P3R1
  }
  WRED(sA) WRED(sB)
  if (lane == 0) {
    irs2[b * NN + mA] = rcpf_(sA);
    irs2[b * NN + mB] = rcpf_(sB);
  }
}

// P4: cs2[n] = sum_m bf16(bf16(ae[m][n]) * irs2[m]), ae recomputed from a0.
// 1024 blocks (64-row m strips).  m-side loads are block-uniform -> scalar.
__global__ __launch_bounds__(256) void p4_cs2(
    const unsigned short* __restrict__ a0g, const float* __restrict__ irs1,
    const float* __restrict__ irs2, const float* __restrict__ ics1,
    const float* __restrict__ xyz4, const float* __restrict__ xyzk,
    const float* __restrict__ thr, float* __restrict__ cs2) {
  const int tid = threadIdx.x;
  const int bid = blockIdx.x;              // B*8*64 = 1024 blocks
  const int ms = bid & 63;                 // m strip (64 rows)
  const int ng = (bid >> 6) & 7;           // n group (512 cols)
  const int b  = bid >> 9;
  const int n2 = (ng << 9) + (tid << 1);   // 2 columns per thread
  const unsigned short* ab = a0g + (size_t)b * NN * NN + n2;
  const float* r1p = irs1 + b * NN;
  const float* r2p = irs2 + b * NN;
  const float* xk = xyzk + (size_t)b * 4 * NN;
  const float px0 = xk[0*NN + n2],     px1 = xk[0*NN + n2 + 1];
  const float py0 = xk[1*NN + n2],     py1 = xk[1*NN + n2 + 1];
  const float pz0 = xk[2*NN + n2],     pz1 = xk[2*NN + n2 + 1];
  const float pw0 = xk[3*NN + n2],     pw1 = xk[3*NN + n2 + 1];
  const float ic0 = ics1[b * NN + n2], ic1 = ics1[b * NN + n2 + 1];
  const float th0 = thr[b * NN + n2],  th1 = thr[b * NN + n2 + 1];
  float s0 = 0.f, s1 = 0.f;
  const int m0 = ms << 6;
#pragma unroll 4
  for (int m = m0; m < m0 + 64; ++m) {
    const unsigned u = *(const unsigned*)(ab + (size_t)m * NN);
    const float r1 = r1p[m];
    const float r2 = r2p[m];
    const float4 pm = *(const float4*)(xyz4 + ((size_t)b * NN + m) * 4);
    const unsigned short e0 = ae_bits((unsigned short)(u & 0xffffu), r1, ic0,
                                      pm, px0, py0, pz0, pw0, th0);
    const unsigned short e1 = ae_bits((unsigned short)(u >> 16), r1, ic1,
                                      pm, px1, py1, pz1, pw1, th1);
    s0 += bf2f(f2bf(bf2f(e0) * r2));
    s1 += bf2f(f2bf(bf2f(e1) * r2));
  }
  atomicAdd(&cs2[b * NN + n2], s0);
  atomicAdd(&cs2[b * NN + n2 + 1], s1);
}

// LDS swizzle: spreads both the b32 transpose-writes (2-way, free) and the
// b128 reads (uniform) across banks.
#define SW(r) ((((r) & 7) << 4) ^ ((((r) >> 3) & 3) << 5))

// K7N: GMA with fused g1/g2 combine; attns2 RECOMPUTED from a0 + mask
// (ae matrix no longer materialized -> half the a-stream fetch traffic).
__global__ __launch_bounds__(256) void k7n_gma(
    const unsigned short* __restrict__ a0g,
    const unsigned short* __restrict__ xvb,
    const float* __restrict__ irs1, const float* __restrict__ irs2,
    const float* __restrict__ ics1, const float* __restrict__ cs2,
    const float* __restrict__ xyz4, const float* __restrict__ xyzk,
    const float* __restrict__ thr,
    float* __restrict__ gma) {
  const int tid = threadIdx.x;
  const int bid = blockIdx.x;              // 512 blocks: B * 64 nb * 4 msl
  const int msl = bid & 3;
  const int nb  = (bid >> 2) & 63;
  const int b   = bid >> 8;
  const int n0 = nb << 6;
  const int mstart = msl << 10;            // 1024-row m strip -> 16 tiles
  __shared__ __align__(16) unsigned short attns1[2][64 * 64];
  __shared__ __align__(16) unsigned short attns2[2][64 * 64];
  __shared__ __align__(16) unsigned short xvs[2][64 * 64];
  const unsigned short* ab = a0g + (size_t)b * NN * NN;
  const float* irs1b = irs1 + b * NN;
  const float* irs2b = irs2 + b * NN;
  const float* x4 = xyz4 + (size_t)b * NN * 4;
  const float* xk = xyzk + (size_t)b * 4 * NN;
  const int w = tid >> 6, l = tid & 63;
  const int lrow0 = (w << 4) + ((l >> 3) << 1);
  const int nc8 = (l & 7) << 3;
  const int gcol = n0 + nc8;
  const int xc = tid >> 2, xpart = tid & 3;
  const unsigned short* xvp = xvb + ((size_t)b * 64 + xc) * NN;
  const int lr = l & 15, quad = l >> 4;
  const int nw = w << 4;
  // hoisted n-side mask constants for this thread's 8 columns
  const float4 pxl = *(const float4*)(xk + 0*NN + gcol);
  const float4 pxh = *(const float4*)(xk + 0*NN + gcol + 4);
  const float4 pyl = *(const float4*)(xk + 1*NN + gcol);
  const float4 pyh = *(const float4*)(xk + 1*NN + gcol + 4);
  const float4 pzl = *(const float4*)(xk + 2*NN + gcol);
  const float4 pzh = *(const float4*)(xk + 2*NN + gcol + 4);
  const float4 pwl = *(const float4*)(xk + 3*NN + gcol);
  const float4 pwh = *(const float4*)(xk + 3*NN + gcol + 4);
  const float4 icl = *(const float4*)(ics1 + b * NN + gcol);
  const float4 ich = *(const float4*)(ics1 + b * NN + gcol + 4);
  const float4 thl = *(const float4*)(thr + b * NN + gcol);
  const float4 thh = *(const float4*)(thr + b * NN + gcol + 4);
  f32x4v acc0 = {0,0,0,0}, acc1 = {0,0,0,0}, acc2 = {0,0,0,0}, acc3 = {0,0,0,0};
  f32x4v d0 = {0,0,0,0}, d1 = {0,0,0,0}, d2 = {0,0,0,0}, d3 = {0,0,0,0};

  uint4 pa0A, pa1A, pv0A, pv1A;
  uint4 pa0B, pa1B, pv0B, pv1B;
  float r1aA, r1bA, r2aA, r2bA, r1aB, r1bB, r2aB, r2bB;
  float4 pmaA, pmbA, pmaB, pmbB;

#define ISSUE(S, MT) { \
    const int m0_ = mstart + ((MT) << 6); \
    const size_t ra_ = (size_t)(m0_ + lrow0) * NN + gcol; \
    pa0##S = *(const uint4*)(ab + ra_); \
    pa1##S = *(const uint4*)(ab + ra_ + NN); \
    pv0##S = *(const uint4*)(xvp + m0_ + (xpart << 4)); \
    pv1##S = *(const uint4*)(xvp + m0_ + (xpart << 4) + 8); \
    r1a##S = irs1b[m0_ + lrow0]; r1b##S = irs1b[m0_ + lrow0 + 1]; \
    r2a##S = irs2b[m0_ + lrow0]; r2b##S = irs2b[m0_ + lrow0 + 1]; \
    pma##S = *(const float4*)(x4 + (size_t)(m0_ + lrow0) * 4); \
    pmb##S = *(const float4*)(x4 + (size_t)(m0_ + lrow0 + 1) * 4); }

// convert a pair of rows' element J: attns1 = bf16(a0*r1);
// attns2 = bf16(bf16(exp(l0)) * r2) with l0 recomputed via ae_bits.
#define CVW(D0, D1, SH, J, R1A, R1B, R2A, R2B, PMA, PMB, A1ARR, A2ARR, PX, PY, PZ, PW, IC, TH) { \
    const unsigned short a0u0_ = (unsigned short)(((D0) >> (SH)) & 0xffffu); \
    const unsigned short a0u1_ = (unsigned short)(((D1) >> (SH)) & 0xffffu); \
    const float v0_ = bf2f(a0u0_) * (R1A); \
    const float v1_ = bf2f(a0u1_) * (R1B); \
    const unsigned pk1_ = (unsigned)f2bf(v0_) | ((unsigned)f2bf(v1_) << 16); \
    const unsigned short e0_ = ae_bits(a0u0_, (R1A), (IC), (PMA), (PX), (PY), (PZ), (PW), (TH)); \
    const unsigned short e1_ = ae_bits(a0u1_, (R1B), (IC), (PMB), (PX), (PY), (PZ), (PW), (TH)); \
    const unsigned pk2_ = (unsigned)f2bf(bf2f(e0_) * (R2A)) \
                        | ((unsigned)f2bf(bf2f(e1_) * (R2B)) << 16); \
    const int nl_ = nc8 + (J); \
    const int off_ = (((nl_) << 7) + (lrow0 << 1)) ^ SW(nl_); \
    *(unsigned*)((char*)(A1ARR) + off_) = pk1_; \
    *(unsigned*)((char*)(A2ARR) + off_) = pk2_; }

#define WR8(U0, U1, R1A, R1B, R2A, R2B, PMA, PMB, A1ARR, A2ARR) \
    CVW(U0.x, U1.x, 0,  0, R1A, R1B, R2A, R2B, PMA, PMB, A1ARR, A2ARR, pxl.x, pyl.x, pzl.x, pwl.x, icl.x, thl.x) \
    CVW(U0.x, U1.x, 16, 1, R1A, R1B, R2A, R2B, PMA, PMB, A1ARR, A2ARR, pxl.y, pyl.y, pzl.y, pwl.y, icl.y, thl.y) \
    CVW(U0.y, U1.y, 0,  2, R1A, R1B, R2A, R2B, PMA, PMB, A1ARR, A2ARR, pxl.z, pyl.z, pzl.z, pwl.z, icl.z, thl.z) \
    CVW(U0.y, U1.y, 16, 3, R1A, R1B, R2A, R2B, PMA, PMB, A1ARR, A2ARR, pxl.w, pyl.w, pzl.w, pwl.w, icl.w, thl.w) \
    CVW(U0.z, U1.z, 0,  4, R1A, R1B, R2A, R2B, PMA, PMB, A1ARR, A2ARR, pxh.x, pyh.x, pzh.x, pwh.x, ich.x, thh.x) \
    CVW(U0.z, U1.z, 16, 5, R1A, R1B, R2A, R2B, PMA, PMB, A1ARR, A2ARR, pxh.y, pyh.y, pzh.y, pwh.y, ich.y, thh.y) \
    CVW(U0.w, U1.w, 0,  6, R1A, R1B, R2A, R2B, PMA, PMB, A1ARR, A2ARR, pxh.z, pyh.z, pzh.z, pwh.z, ich.z, thh.z) \
    CVW(U0.w, U1.w, 16, 7, R1A, R1B, R2A, R2B, PMA, PMB, A1ARR, A2ARR, pxh.w, pyh.w, pzh.w, pwh.w, ich.w, thh.w)

#define STX(XARR, PV0, PV1) { \
    const int xb_ = (xc << 7) + (xpart << 5); \
    *(uint4*)((char*)(XARR) + ((xb_) ^ SW(xc))) = PV0; \
    *(uint4*)((char*)(XARR) + ((xb_ + 16) ^ SW(xc))) = PV1; }

#define LDSW(ARR, ROW, H, Q) \
    (*(const bf16x8*)((const char*)(ARR) + \
      ((((ROW) << 7) + ((H) << 6) + ((Q) << 4)) ^ SW(ROW))))

#define MPH(A1P, A2P, XVP_) { \
    for (int h = 0; h < 2; ++h) { \
      const bf16x8 fa1 = LDSW(A1P, nw + lr, h, quad); \
      const bf16x8 fa2 = LDSW(A2P, nw + lr, h, quad); \
      const bf16x8 fb0 = LDSW(XVP_, lr, h, quad); \
      const bf16x8 fb1 = LDSW(XVP_, 16 + lr, h, quad); \
      const bf16x8 fb2 = LDSW(XVP_, 32 + lr, h, quad); \
      const bf16x8 fb3 = LDSW(XVP_, 48 + lr, h, quad); \
      acc0 = __builtin_amdgcn_mfma_f32_16x16x32_bf16(fa1, fb0, acc0, 0, 0, 0); \
      acc1 = __builtin_amdgcn_mfma_f32_16x16x32_bf16(fa1, fb1, acc1, 0, 0, 0); \
      acc2 = __builtin_amdgcn_mfma_f32_16x16x32_bf16(fa1, fb2, acc2, 0, 0, 0); \
      acc3 = __builtin_amdgcn_mfma_f32_16x16x32_bf16(fa1, fb3, acc3, 0, 0, 0); \
      d0 = __builtin_amdgcn_mfma_f32_16x16x32_bf16(fa2, fb0, d0, 0, 0, 0); \
      d1 = __builtin_amdgcn_mfma_f32_16x16x32_bf16(fa2, fb1, d1, 0, 0, 0); \
      d2 = __builtin_amdgcn_mfma_f32_16x16x32_bf16(fa2, fb2, d2, 0, 0, 0); \
      d3 = __builtin_amdgcn_mfma_f32_16x16x32_bf16(fa2, fb3, d3, 0, 0, 0); \
    } }

  ISSUE(A, 0)
  ISSUE(B, 1)
  for (int mt = 0; mt < 16; mt += 2) {
    WR8(pa0A, pa1A, r1aA, r1bA, r2aA, r2bA, pmaA, pmbA, attns1[0], attns2[0])
    STX(xvs[0], pv0A, pv1A)
    __syncthreads();
    if (mt + 2 < 16) { ISSUE(A, mt + 2) }
    MPH(attns1[0], attns2[0], xvs[0])
    WR8(pa0B, pa1B, r1aB, r1bB, r2aB, r2bB, pmaB, pmbB, attns1[1], attns2[1])
    STX(xvs[1], pv0B, pv1B)
    __syncthreads();
    if (mt + 3 < 16) { ISSUE(B, mt + 3) }
    MPH(attns1[1], attns2[1], xvs[1])
  }
#undef ISSUE
#undef CVW
#undef WR8
#undef STX
#undef LDSW
#undef MPH
  float w10, w11, w12, w13, w20, w21, w22, w23;
  {
    const int nr = n0 + nw + (quad << 2);
    w10 = ics1[b * NN + nr + 0]; w20 = rcpf_(1e-9f + cs2[b * NN + nr + 0]);
    w11 = ics1[b * NN + nr + 1]; w21 = rcpf_(1e-9f + cs2[b * NN + nr + 1]);
    w12 = ics1[b * NN + nr + 2]; w22 = rcpf_(1e-9f + cs2[b * NN + nr + 2]);
    w13 = ics1[b * NN + nr + 3]; w23 = rcpf_(1e-9f + cs2[b * NN + nr + 3]);
  }
#define EPI(ACC, DD, CT) { \
    float* g_ = gma + ((size_t)b * NN + n0 + nw + (quad << 2)) * 64 + (CT) * 16 + lr; \
    atomicAdd(g_ + 0,   fmaf(ACC[0], w10, DD[0] * w20)); \
    atomicAdd(g_ + 64,  fmaf(ACC[1], w11, DD[1] * w21)); \
    atomicAdd(g_ + 128, fmaf(ACC[2], w12, DD[2] * w22)); \
    atomicAdd(g_ + 192, fmaf(ACC[3], w13, DD[3] * w23)); }
  EPI(acc0, d0, 0) EPI(acc1, d1, 1) EPI(acc2, d2, 2) EPI(acc3, d3, 3)
#undef EPI
}

// ===================== common p2 / k8 / k9 =====================

__global__ __launch_bounds__(256) void p2_cs1(
    const float* __restrict__ qt, const float* __restrict__ qk,
    const float* __restrict__ irs1, float* __restrict__ ics1) {
  const int tid = threadIdx.x;
  const int b = blockIdx.x >> 8;
  const int n0t = (blockIdx.x & 255) << 4;
  const int w = tid >> 6, lane = tid & 63;
  const float* qb = qt + (size_t)b * NN * 16;
  const float* kb = qk + (size_t)b * 16 * NN;
  const int nA = n0t + w, nB = n0t + w + 4, nC = n0t + w + 8, nD = n0t + w + 12;
  LQROW(na, qb + (size_t)nA * 16)
  LQROW(nb, qb + (size_t)nB * 16)
  LQROW(nc, qb + (size_t)nC * 16)
  LQROW(nd, qb + (size_t)nD * 16)
  float sA = 0.f, sB = 0.f, sC = 0.f, sD = 0.f;
  for (int it = 0; it < 16; ++it) {
    const int m0 = (it << 8) + (lane << 2);
    LKPL(kb, m0)
    const float4 r1 = *(const float4*)(irs1 + b * NN + m0);
    sA = fmaf(__expf(fminf(DOTC(na0,na1,na2,na3,x), 80.f)), r1.x, sA);
    sA = fmaf(__expf(fminf(DOTC(na0,na1,na2,na3,y), 80.f)), r1.y, sA);
    sA = fmaf(__expf(fminf(DOTC(na0,na1,na2,na3,z), 80.f)), r1.z, sA);
    sA = fmaf(__expf(fminf(DOTC(na0,na1,na2,na3,w), 80.f)), r1.w, sA);
    sB = fmaf(__expf(fminf(DOTC(nb0,nb1,nb2,nb3,x), 80.f)), r1.x, sB);
    sB = fmaf(__expf(fminf(DOTC(nb0,nb1,nb2,nb3,y), 80.f)), r1.y, sB);
    sB = fmaf(__expf(fminf(DOTC(nb0,nb1,nb2,nb3,z), 80.f)), r1.z, sB);
    sB = fmaf(__expf(fminf(DOTC(nb0,nb1,nb2,nb3,w), 80.f)), r1.w, sB);
    sC = fmaf(__expf(fminf(DOTC(nc0,nc1,nc2,nc3,x), 80.f)), r1.x, sC);
    sC = fmaf(__expf(fminf(DOTC(nc0,nc1,nc2,nc3,y), 80.f)), r1.y, sC);
    sC = fmaf(__expf(fminf(DOTC(nc0,nc1,nc2,nc3,z), 80.f)), r1.z, sC);
    sC = fmaf(__expf(fminf(DOTC(nc0,nc1,nc2,nc3,w), 80.f)), r1.w, sC);
    sD = fmaf(__expf(fminf(DOTC(nd0,nd1,nd2,nd3,x), 80.f)), r1.x, sD);
    sD = fmaf(__expf(fminf(DOTC(nd0,nd1,nd2,nd3,y), 80.f)), r1.y, sD);
    sD = fmaf(__expf(fminf(DOTC(nd0,nd1,nd2,nd3,z), 80.f)), r1.z, sD);
    sD = fmaf(__expf(fminf(DOTC(nd0,nd1,nd2,nd3,w), 80.f)), r1.w, sD);
  }
  WRED(sA) WRED(sB) WRED(sC) WRED(sD)
  if (lane == 0) {
    ics1[b * NN + nA] = rcpf_(1e-9f + sA);
    ics1[b * NN + nB] = rcpf_(1e-9f + sB);
    ics1[b * NN + nC] = rcpf_(1e-9f + sC);
    ics1[b * NN + nD] = rcpf_(1e-9f + sD);
  }
}

// mode 0: gma = g1 + g2*ics2 (fallback);  mode 2: gma already combined in g1.
__global__ __launch_bounds__(256) void k8_res(
    const void* __restrict__ mot, const void* __restrict__ wt,
    const void* __restrict__ bt, const float* __restrict__ flag,
    float* __restrict__ g1_res, const float* __restrict__ g2,
    const float* __restrict__ cs2, float* __restrict__ gn,
    const float* __restrict__ ics1, int g1mode) {
  const bool f32 = flag[0] > 0.5f;
  const int tid = threadIdx.x;
  const int bid = blockIdx.x;
  const int b = bid >> 9;
  const int n0 = (bid & 511) << 3;
  __shared__ float wtT[64 * 65];
  __shared__ float bts[64];
  __shared__ float md[8 * 64];
  __shared__ float gs[8], gss[8];
  for (int i = tid; i < 4096; i += 256) {
    int o = i & 63, c = i >> 6;
    wtT[c * 65 + o] = ldin(wt, o * 64 + c, f32);
  }
  if (tid < 64) bts[tid] = ldin(bt, tid, f32);
  if (tid < 8) { gs[tid] = 0.f; gss[tid] = 0.f; }
#pragma unroll
  for (int r = 0; r < 2; ++r) {
    const int idx = tid * 2 + r;
    const int c = idx & 63, nl = idx >> 6;
    const size_t gi = ((size_t)b * NN + n0 + nl) * 64 + c;
    float gmav;
    if (g1mode == 2) {
      gmav = g1_res[gi];
    } else {
      const float ics2n = rcpf_(1e-9f + cs2[b * NN + n0 + nl]);
      float g1v = g1_res[gi];
      if (g1mode == 1) g1v *= ics1[b * NN + n0 + nl];
      gmav = fmaf(g2[gi], ics2n, g1v);
    }
    md[nl * 64 + c] = ldin(mot, ((size_t)b * 64 + c) * NN + n0 + nl, f32) - gmav;
  }
  __syncthreads();
  const int o = tid & 63, ng = tid >> 6;
  const int nl0 = ng * 2, nl1 = ng * 2 + 1;
  float a0 = bts[o], a1 = bts[o];
#pragma unroll 8
  for (int c = 0; c < 64; ++c) {
    float w = wtT[c * 65 + o];
    a0 = fmaf(w, md[nl0 * 64 + c], a0);
    a1 = fmaf(w, md[nl1 * 64 + c], a1);
  }
  g1_res[((size_t)b * NN + n0 + nl0) * 64 + o] = a0;
  g1_res[((size_t)b * NN + n0 + nl1) * 64 + o] = a1;
  atomicAdd(&gs[o >> 3], a0 + a1);
  atomicAdd(&gss[o >> 3], a0 * a0 + a1 * a1);
  __syncthreads();
  if (tid < 8) atomicAdd(&gn[b * 8 + tid], gs[tid]);
  else if (tid < 16) atomicAdd(&gn[16 + b * 8 + (tid - 8)], gss[tid - 8]);
}

__global__ __launch_bounds__(256) void k9_out(
    const float* __restrict__ res, const float* __restrict__ gn,
    const void* __restrict__ mot,
    const void* __restrict__ gnw, const void* __restrict__ gnb,
    const void* __restrict__ pa, const void* __restrict__ al,
    const float* __restrict__ flag, void* __restrict__ out) {
  const bool f32 = flag[0] > 0.5f;
  const int idx = blockIdx.x * 256 + threadIdx.x;
  const int n = idx & 4095;
  const int c = (idx >> 12) & 63;
  const int b = idx >> 18;
  const int g = c >> 3;
  const float inv_cnt = 1.f / 32768.f;
  float mean = gn[b * 8 + g] * inv_cnt;
  float var = gn[16 + b * 8 + g] * inv_cnt - mean * mean;
  var = fmaxf(var, 0.f);
  float rstd = rsqrtf(var + 1e-5f);
  float r = res[((size_t)b * NN + n) * 64 + c];
  float y = (r - mean) * rstd * ldin(gnw, c, f32) + ldin(gnb, c, f32);
  float slope = ldin(pa, 0, f32);
  y = (y >= 0.f) ? y : slope * y;
  float o = ldin(al, 0, f32) * y + ldin(mot, idx, f32);
  if (f32) ((float*)out)[idx] = o;
  else     ((__hip_bfloat16*)out)[idx] = __float2bfloat16(o);
}

extern "C" void kernel_launch(void* const* d_in, const int* in_sizes, int n_in,
                              void* d_out, int out_size, void* d_ws, size_t ws_size,
                              hipStream_t stream) {
  const void* ctx = d_in[0];
  const void* mot = d_in[1];
  const void* xyz = d_in[2];
  const void* wqk = d_in[3];
  const void* wv  = d_in[4];
  const void* bv  = d_in[5];
  const void* wt  = d_in[6];
  const void* bt  = d_in[7];
  const void* gnw = d_in[8];
  const void* gnb = d_in[9];
  const void* pa  = d_in[10];
  const void* al  = d_in[11];
  float* ws = (float*)d_ws;
  const bool big = ws_size >= (size_t)BIG_F * sizeof(float);

  if (ws_size < (size_t)WS_TOTAL * sizeof(float))
    fprintf(stderr, "[gma3d] WARNING ws_size=%zu < needed %zu\n",
            ws_size, (size_t)WS_TOTAL * sizeof(float));

  hipMemsetAsync(ws + OFF_SUMS, 0, (size_t)ZERO_F * sizeof(float), stream);

  k0_detect<<<1, 256, 0, stream>>>((const unsigned short*)ctx, ws + OFF_FLAG);
  k1_q_xyz<<<32, 256, 0, stream>>>(ctx, xyz, wqk, ws + OFF_FLAG,
                                   ws + OFF_QT, ws + OFF_QK,
                                   ws + OFF_XYZ4, ws + OFF_XYZK, ws + OFF_SUMS);
  k2_xv<<<128, 256, 0, stream>>>(mot, wv, bv, ws + OFF_FLAG,
                                 (unsigned short*)(ws + OFF_XVB));
  k2b_thr<<<32, 256, 0, stream>>>(ws + OFF_XYZ4, ws + OFF_SUMS, ws + OFF_THR);

  if (big) {
    unsigned short* a0 = (unsigned short*)(ws + OFF_A0);
    p1w_rs1<<<1024, 256, 0, stream>>>(ws + OFF_QT, ws + OFF_QK, ws + OFF_IRS1, a0);
    p2r_cs1<<<2048, 256, 0, stream>>>(a0, ws + OFF_IRS1, ws + OFF_ICS1);
    p3r_rs2<<<1024, 256, 0, stream>>>(ws + OFF_XYZ4, ws + OFF_XYZK,
                                      ws + OFF_IRS1, ws + OFF_ICS1, ws + OFF_THR,
                                      ws + OFF_IRS2, a0);
    p4_cs2<<<1024, 256, 0, stream>>>(a0, ws + OFF_IRS1, ws + OFF_IRS2,
                                     ws + OFF_ICS1, ws + OFF_XYZ4,
                                     ws + OFF_XYZK, ws + OFF_THR, ws + OFF_CS2);
    k7n_gma<<<512, 256, 0, stream>>>(a0,
                                     (const unsigned short*)(ws + OFF_XVB),
                                     ws + OFF_IRS1, ws + OFF_IRS2,
                                     ws + OFF_ICS1, ws + OFF_CS2,
                                     ws + OFF_XYZ4, ws + OFF_XYZK, ws + OFF_THR,
                                     ws + OFF_GMA);
    k8_res<<<1024, 256, 0, stream>>>(mot, wt, bt, ws + OFF_FLAG,
                                     ws + OFF_GMA, ws + OFF_G2, ws + OFF_CS2,
                                     ws + OFF_GN, ws + OFF_ICS1, 2);
  } else {
    p1_rs1<<<512, 256, 0, stream>>>(ws + OFF_QT, ws + OFF_QK, ws + OFF_IRS1);
    p2_cs1<<<512, 256, 0, stream>>>(ws + OFF_QT, ws + OFF_QK, ws + OFF_IRS1, ws + OFF_ICS1);
    p3_rs2<<<512, 256, 0, stream>>>(ws + OFF_QT, ws + OFF_QK,
                                    ws + OFF_XYZ4, ws + OFF_XYZK,
                                    ws + OFF_IRS1, ws + OFF_ICS1, ws + OFF_THR,
                                    ws + OFF_IRS2);
    k7_gma<<<1024, 256, 0, stream>>>(ws + OFF_QT, ws + OFF_XYZ4,
                                     (const unsigned short*)(ws + OFF_XVB),
                                     ws + OFF_IRS1, ws + OFF_IRS2,
                                     ws + OFF_ICS1, ws + OFF_THR,
                                     ws + OFF_GMA, ws + OFF_G2, ws + OFF_CS2);
    k8_res<<<1024, 256, 0, stream>>>(mot, wt, bt, ws + OFF_FLAG,
                                     ws + OFF_GMA, ws + OFF_G2, ws + OFF_CS2,
                                     ws + OFF_GN, ws + OFF_ICS1, 0);
  }

  k9_out<<<2048, 256, 0, stream>>>(ws + OFF_GMA, ws + OFF_GN, mot, gnw, gnb, pa, al,
                                   ws + OFF_FLAG, d_out);
}

// Round 6
// 283.950 us; speedup vs baseline: 1.0546x; 1.0546x over previous
//
#include <hip/hip_runtime.h>
#include <hip/hip_bf16.h>
#include <cstdio>

#define NB 2
#define NN 4096
#define NC 64
#define NQ 16
#define POS_COEF 0.1f

// ---- workspace layout (float offsets) ----
#define OFF_QT   0u            // [B][N][16] row-major q
#define OFF_QK   131072u       // [B][16][N] planar k-major q (coalesced stream)
#define OFF_XYZ4 262144u       // [B][N][4]  row-major xyz+sq
#define OFF_XYZK 294912u       // [B][4][N]  planar xyz+sq
#define OFF_IRS1 327680u       // [B][N]
#define OFF_IRS2 335872u       // [B][N]
#define OFF_THR  344064u       // [B][N]
#define OFF_ICS1 352256u       // [B][N]  1/(1e-9+cs1)
#define OFF_FLAG 360448u       // [16]
#define OFF_XVB  360464u       // [B][64][N] bf16 (262144 floats)
// --- zeroed region below ---
#define OFF_SUMS 622608u       // [B][4]
#define OFF_GN   622616u       // [2][B][8]
#define OFF_CS2  622648u       // [B][N] colsum of local
#define OFF_GMA  630840u       // [B][N][64]  G1/combined gma -> res in k8
#define OFF_G2   1155128u      // [B][N][64]  G2 (fallback path only)
#define WS_TOTAL 1679416u
#define ZERO_F   (WS_TOTAL - OFF_SUMS)
// --- optional materialized exp matrices (bf16), used iff ws_size permits ---
#define OFF_A0   1679424u      // [B][N][N] bf16 exp(corr)     (16777216 floats)
#define OFF_AE   18456640u     // [B][N][N] bf16 exp(l0)       (16777216 floats)
#define FULL_F   35233856u

using bf16x8 = __attribute__((ext_vector_type(8))) short;
using f32x4v = __attribute__((ext_vector_type(4))) float;

__device__ __forceinline__ float rcpf_(float x) { return __builtin_amdgcn_rcpf(x); }
__device__ __forceinline__ unsigned short f2bf(float x) {
  __hip_bfloat16 h = __float2bfloat16(x);
  return *(unsigned short*)&h;
}
__device__ __forceinline__ float bf2f(unsigned short u) {
  unsigned v = ((unsigned)u) << 16;
  return __builtin_bit_cast(float, v);
}

__device__ __forceinline__ float ldin(const void* p, size_t i, bool f32) {
  return f32 ? ((const float*)p)[i]
             : __bfloat162float(((const __hip_bfloat16*)p)[i]);
}

// 16-term fma tree, named float4 row against named float4 row
#define DOT16M(A0,A1,A2,A3,B0,B1,B2,B3) \
  fmaf((A0).x,(B0).x, fmaf((A0).y,(B0).y, fmaf((A0).z,(B0).z, fmaf((A0).w,(B0).w, \
  fmaf((A1).x,(B1).x, fmaf((A1).y,(B1).y, fmaf((A1).z,(B1).z, fmaf((A1).w,(B1).w, \
  fmaf((A2).x,(B2).x, fmaf((A2).y,(B2).y, fmaf((A2).z,(B2).z, fmaf((A2).w,(B2).w, \
  fmaf((A3).x,(B3).x, fmaf((A3).y,(B3).y, fmaf((A3).z,(B3).z, (A3).w*(B3).w)))))))))))))))

// dot of named row (M0..M3) against column C of k-planes k0..k15
#define DOTC(M0,M1,M2,M3,C) \
  fmaf((M0).x,k0.C, fmaf((M0).y,k1.C, fmaf((M0).z,k2.C, fmaf((M0).w,k3.C, \
  fmaf((M1).x,k4.C, fmaf((M1).y,k5.C, fmaf((M1).z,k6.C, fmaf((M1).w,k7.C, \
  fmaf((M2).x,k8.C, fmaf((M2).y,k9.C, fmaf((M2).z,k10.C, fmaf((M2).w,k11.C, \
  fmaf((M3).x,k12.C, fmaf((M3).y,k13.C, fmaf((M3).z,k14.C, (M3).w*k15.C)))))))))))))))

// planar k-plane loads: lanes read consecutive float4 -> fully coalesced
#define LKPL(base, n0) \
  const float4 k0  = *(const float4*)((base) + 0*NN  + (n0)); \
  const float4 k1  = *(const float4*)((base) + 1*NN  + (n0)); \
  const float4 k2  = *(const float4*)((base) + 2*NN  + (n0)); \
  const float4 k3  = *(const float4*)((base) + 3*NN  + (n0)); \
  const float4 k4  = *(const float4*)((base) + 4*NN  + (n0)); \
  const float4 k5  = *(const float4*)((base) + 5*NN  + (n0)); \
  const float4 k6  = *(const float4*)((base) + 6*NN  + (n0)); \
  const float4 k7  = *(const float4*)((base) + 7*NN  + (n0)); \
  const float4 k8  = *(const float4*)((base) + 8*NN  + (n0)); \
  const float4 k9  = *(const float4*)((base) + 9*NN  + (n0)); \
  const float4 k10 = *(const float4*)((base) + 10*NN + (n0)); \
  const float4 k11 = *(const float4*)((base) + 11*NN + (n0)); \
  const float4 k12 = *(const float4*)((base) + 12*NN + (n0)); \
  const float4 k13 = *(const float4*)((base) + 13*NN + (n0)); \
  const float4 k14 = *(const float4*)((base) + 14*NN + (n0)); \
  const float4 k15 = *(const float4*)((base) + 15*NN + (n0));

#define WRED(s) { s += __shfl_xor(s, 32); s += __shfl_xor(s, 16); \
  s += __shfl_xor(s, 8); s += __shfl_xor(s, 4); s += __shfl_xor(s, 2); s += __shfl_xor(s, 1); }

#define LQROW(v, base) \
  const float4 v##0 = *(const float4*)((base)); \
  const float4 v##1 = *(const float4*)((base) + 4); \
  const float4 v##2 = *(const float4*)((base) + 8); \
  const float4 v##3 = *(const float4*)((base) + 12);

// K0: detect input dtype
__global__ __launch_bounds__(256) void k0_detect(
    const unsigned short* __restrict__ ctx_u16, float* __restrict__ flag) {
  const int tid = threadIdx.x;
  int bad = 0;
  for (int i = tid; i < 8192; i += 256) {
    const unsigned short u = ctx_u16[i];
    const int e = (u >> 7) & 0xFF;
    if (e >= 134 || (e >= 1 && e <= 100)) bad++;
  }
  __shared__ int cnt;
  if (tid == 0) cnt = 0;
  __syncthreads();
  atomicAdd(&cnt, bad);
  __syncthreads();
  if (tid == 0) flag[0] = (cnt > 256) ? 1.0f : 0.0f;
}

// K1: q = Wqk @ ctx (row-major + planar), xyz (row + planar), batch sums
__global__ __launch_bounds__(256) void k1_q_xyz(
    const void* __restrict__ ctx, const void* __restrict__ xyz,
    const void* __restrict__ wqk, const float* __restrict__ flag,
    float* __restrict__ qt, float* __restrict__ qk,
    float* __restrict__ xyz4, float* __restrict__ xyzk,
    float* __restrict__ sums) {
  const bool f32 = flag[0] > 0.5f;
  const int tid = threadIdx.x;
  const int b = blockIdx.x >> 4;
  const int n = ((blockIdx.x & 15) << 8) + tid;
  __shared__ float wqT[NQ * NC];  // [c][o]
  for (int i = tid; i < NQ * NC; i += 256) {
    int o = i & 15, c = i >> 4;
    wqT[c * 16 + o] = ldin(wqk, o * 64 + c, f32);
  }
  __syncthreads();
  float4 a0 = {0,0,0,0}, a1 = {0,0,0,0}, a2 = {0,0,0,0}, a3 = {0,0,0,0};
  const size_t cbase = (size_t)b * 64 * NN + n;
#pragma unroll 4
  for (int c = 0; c < 64; ++c) {
    float x = ldin(ctx, cbase + (size_t)c * NN, f32);
    const float4 w0 = *(const float4*)(wqT + c * 16 + 0);
    const float4 w1 = *(const float4*)(wqT + c * 16 + 4);
    const float4 w2 = *(const float4*)(wqT + c * 16 + 8);
    const float4 w3 = *(const float4*)(wqT + c * 16 + 12);
    a0.x = fmaf(w0.x, x, a0.x); a0.y = fmaf(w0.y, x, a0.y); a0.z = fmaf(w0.z, x, a0.z); a0.w = fmaf(w0.w, x, a0.w);
    a1.x = fmaf(w1.x, x, a1.x); a1.y = fmaf(w1.y, x, a1.y); a1.z = fmaf(w1.z, x, a1.z); a1.w = fmaf(w1.w, x, a1.w);
    a2.x = fmaf(w2.x, x, a2.x); a2.y = fmaf(w2.y, x, a2.y); a2.z = fmaf(w2.z, x, a2.z); a2.w = fmaf(w2.w, x, a2.w);
    a3.x = fmaf(w3.x, x, a3.x); a3.y = fmaf(w3.y, x, a3.y); a3.z = fmaf(w3.z, x, a3.z); a3.w = fmaf(w3.w, x, a3.w);
  }
  float* qp = qt + (size_t)(b * NN + n) * 16;
  *(float4*)(qp + 0) = a0; *(float4*)(qp + 4) = a1;
  *(float4*)(qp + 8) = a2; *(float4*)(qp + 12) = a3;
  float* kq = qk + (size_t)b * 16 * NN + n;
  kq[0*NN]=a0.x;  kq[1*NN]=a0.y;  kq[2*NN]=a0.z;  kq[3*NN]=a0.w;
  kq[4*NN]=a1.x;  kq[5*NN]=a1.y;  kq[6*NN]=a1.z;  kq[7*NN]=a1.w;
  kq[8*NN]=a2.x;  kq[9*NN]=a2.y;  kq[10*NN]=a2.z; kq[11*NN]=a2.w;
  kq[12*NN]=a3.x; kq[13*NN]=a3.y; kq[14*NN]=a3.z; kq[15*NN]=a3.w;
  float xx = ldin(xyz, (size_t)(b * NN + n) * 3 + 0, f32);
  float yy = ldin(xyz, (size_t)(b * NN + n) * 3 + 1, f32);
  float zz = ldin(xyz, (size_t)(b * NN + n) * 3 + 2, f32);
  float4 p; p.x = xx; p.y = yy; p.z = zz; p.w = fmaf(xx, xx, fmaf(yy, yy, zz * zz));
  *(float4*)(xyz4 + (size_t)(b * NN + n) * 4) = p;
  float* kx = xyzk + (size_t)b * 4 * NN + n;
  kx[0*NN]=p.x; kx[1*NN]=p.y; kx[2*NN]=p.z; kx[3*NN]=p.w;
  float sx = p.x, sy = p.y, sz = p.z, sw = p.w;
  WRED(sx) WRED(sy) WRED(sz) WRED(sw)
  if ((tid & 63) == 0) {
    atomicAdd(&sums[b * 4 + 0], sx);
    atomicAdd(&sums[b * 4 + 1], sy);
    atomicAdd(&sums[b * 4 + 2], sz);
    atomicAdd(&sums[b * 4 + 3], sw);
  }
}

// K2: xv = Wv @ motion + bv, bf16 channel-major [b][c][n]
__global__ __launch_bounds__(256) void k2_xv(
    const void* __restrict__ mot, const void* __restrict__ wv,
    const void* __restrict__ bv, const float* __restrict__ flag,
    unsigned short* __restrict__ xvb) {
  const bool f32 = flag[0] > 0.5f;
  const int tid = threadIdx.x;
  const int b = blockIdx.x >> 6;
  const int n = ((blockIdx.x & 63) << 6) + (tid >> 2);
  const int og = tid & 3;
  __shared__ float wvT[NC * NC];
  __shared__ float bvs[NC];
  for (int i = tid; i < NC * NC; i += 256) {
    int o = i & 63, c = i >> 6;
    wvT[c * 64 + o] = ldin(wv, o * 64 + c, f32);
  }
  if (tid < 64) bvs[tid] = ldin(bv, tid, f32);
  __syncthreads();
  float4 a0 = *(const float4*)(bvs + og * 16 + 0);
  float4 a1 = *(const float4*)(bvs + og * 16 + 4);
  float4 a2 = *(const float4*)(bvs + og * 16 + 8);
  float4 a3 = *(const float4*)(bvs + og * 16 + 12);
  const size_t mbase = (size_t)b * 64 * NN + n;
#pragma unroll 4
  for (int c = 0; c < 64; ++c) {
    float x = ldin(mot, mbase + (size_t)c * NN, f32);
    const float4 w0 = *(const float4*)(wvT + c * 64 + og * 16 + 0);
    const float4 w1 = *(const float4*)(wvT + c * 64 + og * 16 + 4);
    const float4 w2 = *(const float4*)(wvT + c * 64 + og * 16 + 8);
    const float4 w3 = *(const float4*)(wvT + c * 64 + og * 16 + 12);
    a0.x = fmaf(w0.x, x, a0.x); a0.y = fmaf(w0.y, x, a0.y); a0.z = fmaf(w0.z, x, a0.z); a0.w = fmaf(w0.w, x, a0.w);
    a1.x = fmaf(w1.x, x, a1.x); a1.y = fmaf(w1.y, x, a1.y); a1.z = fmaf(w1.z, x, a1.z); a1.w = fmaf(w1.w, x, a1.w);
    a2.x = fmaf(w2.x, x, a2.x); a2.y = fmaf(w2.y, x, a2.y); a2.z = fmaf(w2.z, x, a2.z); a2.w = fmaf(w2.w, x, a2.w);
    a3.x = fmaf(w3.x, x, a3.x); a3.y = fmaf(w3.y, x, a3.y); a3.z = fmaf(w3.z, x, a3.z); a3.w = fmaf(w3.w, x, a3.w);
  }
  unsigned short* xb = xvb + (size_t)b * 64 * NN + n;
  const int o0 = og * 16;
  xb[(size_t)(o0 + 0) * NN] = f2bf(a0.x);  xb[(size_t)(o0 + 1) * NN] = f2bf(a0.y);
  xb[(size_t)(o0 + 2) * NN] = f2bf(a0.z);  xb[(size_t)(o0 + 3) * NN] = f2bf(a0.w);
  xb[(size_t)(o0 + 4) * NN] = f2bf(a1.x);  xb[(size_t)(o0 + 5) * NN] = f2bf(a1.y);
  xb[(size_t)(o0 + 6) * NN] = f2bf(a1.z);  xb[(size_t)(o0 + 7) * NN] = f2bf(a1.w);
  xb[(size_t)(o0 + 8) * NN] = f2bf(a2.x);  xb[(size_t)(o0 + 9) * NN] = f2bf(a2.y);
  xb[(size_t)(o0 +10) * NN] = f2bf(a2.z);  xb[(size_t)(o0 +11) * NN] = f2bf(a2.w);
  xb[(size_t)(o0 +12) * NN] = f2bf(a3.x);  xb[(size_t)(o0 +13) * NN] = f2bf(a3.y);
  xb[(size_t)(o0 +14) * NN] = f2bf(a3.z);  xb[(size_t)(o0 +15) * NN] = f2bf(a3.w);
}

// K2b: thr[n] = 0.1*(1e-9 + csd[n]) analytic
__global__ __launch_bounds__(256) void k2b_thr(
    const float* __restrict__ xyz4, const float* __restrict__ sums,
    float* __restrict__ thr) {
  const int idx = blockIdx.x * 256 + threadIdx.x;
  const int b = idx >> 12;
  const float4 pn = *(const float4*)(xyz4 + (size_t)idx * 4);
  const float Px = sums[b * 4 + 0], Py = sums[b * 4 + 1];
  const float Pz = sums[b * 4 + 2], S1 = sums[b * 4 + 3];
  float csd = fmaf((float)NN, pn.w, S1)
            - 2.f * (pn.x * Px + pn.y * Py + pn.z * Pz);
  thr[idx] = POS_COEF * (1e-9f + csd);
}

// ===================== fallback (round-13) p1/p3/k7 =====================

__global__ __launch_bounds__(256) void p1_rs1(
    const float* __restrict__ qt, const float* __restrict__ qk,
    float* __restrict__ irs1) {
  const int tid = threadIdx.x;
  const int b = blockIdx.x >> 8;
  const int m0 = (blockIdx.x & 255) << 4;
  const int w = tid >> 6, lane = tid & 63;
  const float* qb = qt + (size_t)b * NN * 16;
  const float* kb = qk + (size_t)b * 16 * NN;
  const int mA = m0 + w, mB = m0 + w + 4, mC = m0 + w + 8, mD = m0 + w + 12;
  LQROW(ma, qb + (size_t)mA * 16)
  LQROW(mb, qb + (size_t)mB * 16)
  LQROW(mc, qb + (size_t)mC * 16)
  LQROW(md, qb + (size_t)mD * 16)
  float sA = 0.f, sB = 0.f, sC = 0.f, sD = 0.f;
  for (int it = 0; it < 16; ++it) {
    const int n0 = (it << 8) + (lane << 2);
    LKPL(kb, n0)
    sA += __expf(fminf(DOTC(ma0,ma1,ma2,ma3,x), 80.f));
    sA += __expf(fminf(DOTC(ma0,ma1,ma2,ma3,y), 80.f));
    sA += __expf(fminf(DOTC(ma0,ma1,ma2,ma3,z), 80.f));
    sA += __expf(fminf(DOTC(ma0,ma1,ma2,ma3,w), 80.f));
    sB += __expf(fminf(DOTC(mb0,mb1,mb2,mb3,x), 80.f));
    sB += __expf(fminf(DOTC(mb0,mb1,mb2,mb3,y), 80.f));
    sB += __expf(fminf(DOTC(mb0,mb1,mb2,mb3,z), 80.f));
    sB += __expf(fminf(DOTC(mb0,mb1,mb2,mb3,w), 80.f));
    sC += __expf(fminf(DOTC(mc0,mc1,mc2,mc3,x), 80.f));
    sC += __expf(fminf(DOTC(mc0,mc1,mc2,mc3,y), 80.f));
    sC += __expf(fminf(DOTC(mc0,mc1,mc2,mc3,z), 80.f));
    sC += __expf(fminf(DOTC(mc0,mc1,mc2,mc3,w), 80.f));
    sD += __expf(fminf(DOTC(md0,md1,md2,md3,x), 80.f));
    sD += __expf(fminf(DOTC(md0,md1,md2,md3,y), 80.f));
    sD += __expf(fminf(DOTC(md0,md1,md2,md3,z), 80.f));
    sD += __expf(fminf(DOTC(md0,md1,md2,md3,w), 80.f));
  }
  WRED(sA) WRED(sB) WRED(sC) WRED(sD)
  if (lane == 0) {
    irs1[b * NN + mA] = rcpf_(sA);
    irs1[b * NN + mB] = rcpf_(sB);
    irs1[b * NN + mC] = rcpf_(sC);
    irs1[b * NN + mD] = rcpf_(sD);
  }
}

__global__ __launch_bounds__(256) void p3_rs2(
    const float* __restrict__ qt, const float* __restrict__ qk,
    const float* __restrict__ xyz4, const float* __restrict__ xyzk,
    const float* __restrict__ irs1, const float* __restrict__ ics1,
    const float* __restrict__ thr, float* __restrict__ irs2) {
  const int tid = threadIdx.x;
  const int b = blockIdx.x >> 8;
  const int m0 = (blockIdx.x & 255) << 4;
  const int w = tid >> 6, lane = tid & 63;
  const float* qb = qt + (size_t)b * NN * 16;
  const float* kb = qk + (size_t)b * 16 * NN;
  const float* xk = xyzk + (size_t)b * 4 * NN;
  const int mA = m0 + w, mB = m0 + w + 4, mC = m0 + w + 8, mD = m0 + w + 12;
  LQROW(ma, qb + (size_t)mA * 16)
  LQROW(mb, qb + (size_t)mB * 16)
  LQROW(mc, qb + (size_t)mC * 16)
  LQROW(md, qb + (size_t)mD * 16)
  const float4 pmA = *(const float4*)(xyz4 + ((size_t)b * NN + mA) * 4);
  const float4 pmB = *(const float4*)(xyz4 + ((size_t)b * NN + mB) * 4);
  const float4 pmC = *(const float4*)(xyz4 + ((size_t)b * NN + mC) * 4);
  const float4 pmD = *(const float4*)(xyz4 + ((size_t)b * NN + mD) * 4);
  const float rA = irs1[b * NN + mA];
  const float rB = irs1[b * NN + mB];
  const float rC = irs1[b * NN + mC];
  const float rD = irs1[b * NN + mD];
  float sA = 0.f, sB = 0.f, sC = 0.f, sD = 0.f;
#define P3C(S, M0,M1,M2,M3, PM, R, C) { \
    float corr_ = DOTC(M0,M1,M2,M3,C); \
    float a1v_ = __expf(fminf(corr_, 80.f)) * (R) * ic.C; \
    float dd_ = (PM).w + pw.C - 2.f * ((PM).x * px.C + (PM).y * py.C + (PM).z * pz.C); \
    dd_ = fmaxf(dd_, 0.f); \
    float l0_ = (dd_ <= th.C) ? a1v_ : 0.f; \
    S += __expf(l0_); }
  for (int it = 0; it < 16; ++it) {
    const int n0 = (it << 8) + (lane << 2);
    LKPL(kb, n0)
    const float4 px = *(const float4*)(xk + 0*NN + n0);
    const float4 py = *(const float4*)(xk + 1*NN + n0);
    const float4 pz = *(const float4*)(xk + 2*NN + n0);
    const float4 pw = *(const float4*)(xk + 3*NN + n0);
    const float4 ic = *(const float4*)(ics1 + b * NN + n0);
    const float4 th = *(const float4*)(thr + b * NN + n0);
    P3C(sA, ma0,ma1,ma2,ma3, pmA, rA, x)
    P3C(sA, ma0,ma1,ma2,ma3, pmA, rA, y)
    P3C(sA, ma0,ma1,ma2,ma3, pmA, rA, z)
    P3C(sA, ma0,ma1,ma2,ma3, pmA, rA, w)
    P3C(sB, mb0,mb1,mb2,mb3, pmB, rB, x)
    P3C(sB, mb0,mb1,mb2,mb3, pmB, rB, y)
    P3C(sB, mb0,mb1,mb2,mb3, pmB, rB, z)
    P3C(sB, mb0,mb1,mb2,mb3, pmB, rB, w)
    P3C(sC, mc0,mc1,mc2,mc3, pmC, rC, x)
    P3C(sC, mc0,mc1,mc2,mc3, pmC, rC, y)
    P3C(sC, mc0,mc1,mc2,mc3, pmC, rC, z)
    P3C(sC, mc0,mc1,mc2,mc3, pmC, rC, w)
    P3C(sD, md0,md1,md2,md3, pmD, rD, x)
    P3C(sD, md0,md1,md2,md3, pmD, rD, y)
    P3C(sD, md0,md1,md2,md3, pmD, rD, z)
    P3C(sD, md0,md1,md2,md3, pmD, rD, w)
  }
#undef P3C
  WRED(sA) WRED(sB) WRED(sC) WRED(sD)
  if (lane == 0) {
    irs2[b * NN + mA] = rcpf_(sA);
    irs2[b * NN + mB] = rcpf_(sB);
    irs2[b * NN + mC] = rcpf_(sC);
    irs2[b * NN + mD] = rcpf_(sD);
  }
}

__global__ __launch_bounds__(256) void k7_gma(
    const float* __restrict__ qt, const float* __restrict__ xyz4,
    const unsigned short* __restrict__ xvb,
    const float* __restrict__ irs1, const float* __restrict__ irs2,
    const float* __restrict__ ics1, const float* __restrict__ thr,
    float* __restrict__ g1, float* __restrict__ g2, float* __restrict__ cs2) {
  const int tid = threadIdx.x;
  const int bid = blockIdx.x;
  const int msl = bid & 7;
  const int nb = (bid >> 3) & 63;
  const int b = bid >> 9;
  const int n0 = nb << 6;
  const int mstart = msl << 9;
  __shared__ __align__(16) unsigned short attns1[64 * 72];
  __shared__ __align__(16) unsigned short attns2[64 * 72];
  __shared__ __align__(16) unsigned short xvs[64 * 72];
  const float* qb = qt + (size_t)b * NN * 16;
  const float* pb = xyz4 + (size_t)b * NN * 4;
  const int ni = tid & 63, aw = tid >> 6;
  const int na = n0 + ni;
  const float* qnp = qb + (size_t)na * 16;
  LQROW(q, qnp)
  const float4 pn = *(const float4*)(pb + (size_t)na * 4);
  const float ics1n = ics1[b * NN + na];
  const float thr_n = thr[b * NN + na];
  const int lane = tid & 63, wv = tid >> 6;
  const int lr = lane & 15, quad = lane >> 4;
  const int nw = wv << 4;
  f32x4v acc0 = {0,0,0,0}, acc1 = {0,0,0,0}, acc2 = {0,0,0,0}, acc3 = {0,0,0,0};
  f32x4v d0 = {0,0,0,0}, d1 = {0,0,0,0}, d2 = {0,0,0,0}, d3 = {0,0,0,0};
  float csacc = 0.f;
#define COMPA(MOFF, D1, D2) { \
    const int m_ = __builtin_amdgcn_readfirstlane(mw + (MOFF)); \
    const float* qm_ = qb + (size_t)m_ * 16; \
    LQROW(wq, qm_) \
    float corr_ = DOT16M(q0, q1, q2, q3, wq0, wq1, wq2, wq3); \
    const float4 pm_ = *(const float4*)(pb + (size_t)m_ * 4); \
    float a1v_ = __expf(fminf(corr_, 80.f)) * irs1[b * NN + m_] * ics1n; \
    float dd_ = pm_.w + pn.w - 2.f * (pm_.x * pn.x + pm_.y * pn.y + pm_.z * pn.z); \
    dd_ = fmaxf(dd_, 0.f); \
    float l0_ = (dd_ <= thr_n) ? a1v_ : 0.f; \
    float l2n_ = __expf(l0_) * irs2[b * NN + m_]; \
    D1 = f2bf(a1v_); D2 = f2bf(l2n_); csacc += l2n_; }
  for (int mt = 0; mt < 8; ++mt) {
    const int m0 = mstart + (mt << 6);
    __syncthreads();
    {
      const int c = tid >> 2, part = tid & 3;
      const unsigned short* src = xvb + ((size_t)b * 64 + c) * NN + m0 + part * 16;
      unsigned short* dst = xvs + c * 72 + part * 16;
      *(uint4*)dst = *(const uint4*)src;
      *(uint4*)(dst + 8) = *(const uint4*)(src + 8);
    }
    const int mw = m0 + (aw << 4);
#pragma unroll
    for (int g = 0; g < 4; ++g) {
      ushort4 u1, u2;
      COMPA(g * 4 + 0, u1.x, u2.x)
      COMPA(g * 4 + 1, u1.y, u2.y)
      COMPA(g * 4 + 2, u1.z, u2.z)
      COMPA(g * 4 + 3, u1.w, u2.w)
      *(ushort4*)(attns1 + ni * 72 + (aw << 4) + (g << 2)) = u1;
      *(ushort4*)(attns2 + ni * 72 + (aw << 4) + (g << 2)) = u2;
    }
    __syncthreads();
#pragma unroll
    for (int h = 0; h < 2; ++h) {
      const bf16x8 a1 = *(const bf16x8*)(attns1 + (nw + lr) * 72 + h * 32 + quad * 8);
      const bf16x8 a2 = *(const bf16x8*)(attns2 + (nw + lr) * 72 + h * 32 + quad * 8);
      const bf16x8 b0 = *(const bf16x8*)(xvs + (lr) * 72 + h * 32 + quad * 8);
      const bf16x8 b1 = *(const bf16x8*)(xvs + (16 + lr) * 72 + h * 32 + quad * 8);
      const bf16x8 b2 = *(const bf16x8*)(xvs + (32 + lr) * 72 + h * 32 + quad * 8);
      const bf16x8 b3 = *(const bf16x8*)(xvs + (48 + lr) * 72 + h * 32 + quad * 8);
      acc0 = __builtin_amdgcn_mfma_f32_16x16x32_bf16(a1, b0, acc0, 0, 0, 0);
      acc1 = __builtin_amdgcn_mfma_f32_16x16x32_bf16(a1, b1, acc1, 0, 0, 0);
      acc2 = __builtin_amdgcn_mfma_f32_16x16x32_bf16(a1, b2, acc2, 0, 0, 0);
      acc3 = __builtin_amdgcn_mfma_f32_16x16x32_bf16(a1, b3, acc3, 0, 0, 0);
      d0 = __builtin_amdgcn_mfma_f32_16x16x32_bf16(a2, b0, d0, 0, 0, 0);
      d1 = __builtin_amdgcn_mfma_f32_16x16x32_bf16(a2, b1, d1, 0, 0, 0);
      d2 = __builtin_amdgcn_mfma_f32_16x16x32_bf16(a2, b2, d2, 0, 0, 0);
      d3 = __builtin_amdgcn_mfma_f32_16x16x32_bf16(a2, b3, d3, 0, 0, 0);
    }
  }
#undef COMPA
  atomicAdd(&cs2[b * NN + na], csacc);
#define EPI(ACC, DST, CT) { \
    float* g_ = (DST) + ((size_t)b * NN + n0 + nw + (quad << 2)) * 64 + (CT) * 16 + lr; \
    atomicAdd(g_ + 0,   ACC[0]); \
    atomicAdd(g_ + 64,  ACC[1]); \
    atomicAdd(g_ + 128, ACC[2]); \
    atomicAdd(g_ + 192, ACC[3]); }
  EPI(acc0, g1, 0) EPI(acc1, g1, 1) EPI(acc2, g1, 2) EPI(acc3, g1, 3)
  EPI(d0, g2, 0) EPI(d1, g2, 1) EPI(d2, g2, 2) EPI(d3, g2, 3)
#undef EPI
}

// ============ materialized-exp path (used iff ws_size permits) ============

// P1W: stores a0[m][n]=bf16(exp(corr)), sums the ROUNDED values.
// Latency fix (r6): ALL 32 k-plane float4 loads staged into named registers
// BEFORE any fma -> 32-deep memory-level parallelism per wave, one waitcnt
// batch instead of 16 serialized load->use chains.  Per-element fma order
// (plane 0..15) preserved -> bit-identical numerics to r4.
__global__ __launch_bounds__(256) void p1w_rs1(
    const float* __restrict__ qt, const float* __restrict__ qk,
    float* __restrict__ irs1, unsigned short* __restrict__ a0g) {
  const int tid = threadIdx.x;
  const int b = blockIdx.x >> 9;
  const int m0 = (blockIdx.x & 511) << 3;
  const int w = tid >> 6, lane = tid & 63;
  const float* qb = qt + (size_t)b * NN * 16;
  const float* kb = qk + (size_t)b * 16 * NN;
  unsigned short* ab = a0g + (size_t)b * NN * NN;
  const int mA = m0 + (w << 1), mB = mA + 1;
  LQROW(ma, qb + (size_t)mA * 16)
  LQROW(mb, qb + (size_t)mB * 16)
  float sA = 0.f, sB = 0.f;
  for (int it = 0; it < 8; ++it) {
    const int n0 = (it << 9) + (lane << 3);
    // ---- stage: issue all 32 loads up front (MLP depth 32) ----
#define LD2(P) \
    const float4 kl##P = *(const float4*)(kb + (size_t)(P) * NN + n0); \
    const float4 kh##P = *(const float4*)(kb + (size_t)(P) * NN + n0 + 4);
    LD2(0)  LD2(1)  LD2(2)  LD2(3)  LD2(4)  LD2(5)  LD2(6)  LD2(7)
    LD2(8)  LD2(9)  LD2(10) LD2(11) LD2(12) LD2(13) LD2(14) LD2(15)
#undef LD2
    float4 aAl = {0,0,0,0}, aAh = {0,0,0,0}, aBl = {0,0,0,0}, aBh = {0,0,0,0};
#define PLN(QA_, QB_, P) { \
      const float4 kl_ = kl##P; \
      const float4 kh_ = kh##P; \
      aAl.x = fmaf(QA_, kl_.x, aAl.x); aAl.y = fmaf(QA_, kl_.y, aAl.y); \
      aAl.z = fmaf(QA_, kl_.z, aAl.z); aAl.w = fmaf(QA_, kl_.w, aAl.w); \
      aAh.x = fmaf(QA_, kh_.x, aAh.x); aAh.y = fmaf(QA_, kh_.y, aAh.y); \
      aAh.z = fmaf(QA_, kh_.z, aAh.z); aAh.w = fmaf(QA_, kh_.w, aAh.w); \
      aBl.x = fmaf(QB_, kl_.x, aBl.x); aBl.y = fmaf(QB_, kl_.y, aBl.y); \
      aBl.z = fmaf(QB_, kl_.z, aBl.z); aBl.w = fmaf(QB_, kl_.w, aBl.w); \
      aBh.x = fmaf(QB_, kh_.x, aBh.x); aBh.y = fmaf(QB_, kh_.y, aBh.y); \
      aBh.z = fmaf(QB_, kh_.z, aBh.z); aBh.w = fmaf(QB_, kh_.w, aBh.w); }
    PLN(ma0.x, mb0.x, 0)   PLN(ma0.y, mb0.y, 1)
    PLN(ma0.z, mb0.z, 2)   PLN(ma0.w, mb0.w, 3)
    PLN(ma1.x, mb1.x, 4)   PLN(ma1.y, mb1.y, 5)
    PLN(ma1.z, mb1.z, 6)   PLN(ma1.w, mb1.w, 7)
    PLN(ma2.x, mb2.x, 8)   PLN(ma2.y, mb2.y, 9)
    PLN(ma2.z, mb2.z, 10)  PLN(ma2.w, mb2.w, 11)
    PLN(ma3.x, mb3.x, 12)  PLN(ma3.y, mb3.y, 13)
    PLN(ma3.z, mb3.z, 14)  PLN(ma3.w, mb3.w, 15)
#undef PLN
#define EX8(AL, AH, S, ROWPTR) { \
      const unsigned short u0_ = f2bf(__expf(fminf((AL).x, 80.f))); \
      const unsigned short u1_ = f2bf(__expf(fminf((AL).y, 80.f))); \
      const unsigned short u2_ = f2bf(__expf(fminf((AL).z, 80.f))); \
      const unsigned short u3_ = f2bf(__expf(fminf((AL).w, 80.f))); \
      const unsigned short u4_ = f2bf(__expf(fminf((AH).x, 80.f))); \
      const unsigned short u5_ = f2bf(__expf(fminf((AH).y, 80.f))); \
      const unsigned short u6_ = f2bf(__expf(fminf((AH).z, 80.f))); \
      const unsigned short u7_ = f2bf(__expf(fminf((AH).w, 80.f))); \
      uint4 U_; \
      U_.x = (unsigned)u0_ | ((unsigned)u1_ << 16); \
      U_.y = (unsigned)u2_ | ((unsigned)u3_ << 16); \
      U_.z = (unsigned)u4_ | ((unsigned)u5_ << 16); \
      U_.w = (unsigned)u6_ | ((unsigned)u7_ << 16); \
      *(uint4*)((ROWPTR) + n0) = U_; \
      S += bf2f(u0_) + bf2f(u1_) + bf2f(u2_) + bf2f(u3_) \
         + bf2f(u4_) + bf2f(u5_) + bf2f(u6_) + bf2f(u7_); }
    EX8(aAl, aAh, sA, ab + (size_t)mA * NN)
    EX8(aBl, aBh, sB, ab + (size_t)mB * NN)
#undef EX8
  }
  WRED(sA) WRED(sB)
  if (lane == 0) {
    irs1[b * NN + mA] = rcpf_(sA);
    irs1[b * NN + mB] = rcpf_(sB);
  }
}

// P2R: cs1 via SYMMETRY of corr: cs1[n] = sum_m a0[n][m]*irs1[m].
__global__ __launch_bounds__(256) void p2r_cs1(
    const unsigned short* __restrict__ a0g, const float* __restrict__ irs1,
    float* __restrict__ ics1) {
  const int tid = threadIdx.x;
  const int w = tid >> 6, l = tid & 63;
  const int bi = blockIdx.x;                 // 0..2047
  const int b = bi >> 10;
  const int n = ((bi & 1023) << 2) + w;      // 4 rows per block, 1 per wave
  const unsigned short* row = a0g + ((size_t)b * NN + n) * NN;
  const float* ir = irs1 + b * NN;
  float s = 0.f;
#pragma unroll
  for (int it = 0; it < 8; ++it) {
    const int m = (it << 9) + (l << 3);
    const uint4 u = *(const uint4*)(row + m);
    const float4 i0 = *(const float4*)(ir + m);
    const float4 i1 = *(const float4*)(ir + m + 4);
    s = fmaf(bf2f((unsigned short)(u.x & 0xffffu)), i0.x, s);
    s = fmaf(bf2f((unsigned short)(u.x >> 16)),     i0.y, s);
    s = fmaf(bf2f((unsigned short)(u.y & 0xffffu)), i0.z, s);
    s = fmaf(bf2f((unsigned short)(u.y >> 16)),     i0.w, s);
    s = fmaf(bf2f((unsigned short)(u.z & 0xffffu)), i1.x, s);
    s = fmaf(bf2f((unsigned short)(u.z >> 16)),     i1.y, s);
    s = fmaf(bf2f((unsigned short)(u.w & 0xffffu)), i1.z, s);
    s = fmaf(bf2f((unsigned short)(u.w >> 16)),     i1.w, s);
  }
  WRED(s)
  if (l == 0) ics1[b * NN + n] = rcpf_(1e-9f + s);
}

// P3W: reads a0 rows (16B/lane), stores ae[m][n]=bf16(exp(l0)) (16B/lane),
// sums ROUNDED values.  8 cols/lane wide layout, 2 rows/wave, 1024 blocks.
__global__ __launch_bounds__(256) void p3w_rs2(
    const float* __restrict__ xyz4, const float* __restrict__ xyzk,
    const float* __restrict__ irs1, const float* __restrict__ ics1,
    const float* __restrict__ thr, float* __restrict__ irs2,
    const unsigned short* __restrict__ a0g, unsigned short* __restrict__ aeg) {
  const int tid = threadIdx.x;
  const int b = blockIdx.x >> 9;
  const int m0 = (blockIdx.x & 511) << 3;
  const int w = tid >> 6, lane = tid & 63;
  const float* xk = xyzk + (size_t)b * 4 * NN;
  const unsigned short* ab = a0g + (size_t)b * NN * NN;
  unsigned short* eb = aeg + (size_t)b * NN * NN;
  const int mA = m0 + (w << 1), mB = mA + 1;
  const float4 pmA = *(const float4*)(xyz4 + ((size_t)b * NN + mA) * 4);
  const float4 pmB = *(const float4*)(xyz4 + ((size_t)b * NN + mB) * 4);
  const float rA = irs1[b * NN + mA];
  const float rB = irs1[b * NN + mB];
  float sA = 0.f, sB = 0.f;
#define P3E(S, OUT, A0W, SH, PM, R, PX, PY, PZ, PW, IC, TH) { \
    float a1v_ = bf2f((unsigned short)(((A0W) >> (SH)) & 0xffffu)) * (R) * (IC); \
    float dd_ = (PM).w + (PW) - 2.f * ((PM).x * (PX) + (PM).y * (PY) + (PM).z * (PZ)); \
    dd_ = fmaxf(dd_, 0.f); \
    float l0_ = (dd_ <= (TH)) ? a1v_ : 0.f; \
    const unsigned short us_ = f2bf(__expf(l0_)); OUT = us_; S += bf2f(us_); }
  for (int it = 0; it < 8; ++it) {
    const int n0 = (it << 9) + (lane << 3);
    const float4 pxl = *(const float4*)(xk + 0*NN + n0);
    const float4 pxh = *(const float4*)(xk + 0*NN + n0 + 4);
    const float4 pyl = *(const float4*)(xk + 1*NN + n0);
    const float4 pyh = *(const float4*)(xk + 1*NN + n0 + 4);
    const float4 pzl = *(const float4*)(xk + 2*NN + n0);
    const float4 pzh = *(const float4*)(xk + 2*NN + n0 + 4);
    const float4 pwl = *(const float4*)(xk + 3*NN + n0);
    const float4 pwh = *(const float4*)(xk + 3*NN + n0 + 4);
    const float4 icl = *(const float4*)(ics1 + b * NN + n0);
    const float4 ich = *(const float4*)(ics1 + b * NN + n0 + 4);
    const float4 thl = *(const float4*)(thr + b * NN + n0);
    const float4 thh = *(const float4*)(thr + b * NN + n0 + 4);
    const uint4 rAu = *(const uint4*)(ab + (size_t)mA * NN + n0);
    const uint4 rBu = *(const uint4*)(ab + (size_t)mB * NN + n0);
    unsigned short e0, e1, e2, e3, e4, e5, e6, e7;
    P3E(sA, e0, rAu.x, 0,  pmA, rA, pxl.x, pyl.x, pzl.x, pwl.x, icl.x, thl.x)
    P3E(sA, e1, rAu.x, 16, pmA, rA, pxl.y, pyl.y, pzl.y, pwl.y, icl.y, thl.y)
    P3E(sA, e2, rAu.y, 0,  pmA, rA, pxl.z, pyl.z, pzl.z, pwl.z, icl.z, thl.z)
    P3E(sA, e3, rAu.y, 16, pmA, rA, pxl.w, pyl.w, pzl.w, pwl.w, icl.w, thl.w)
    P3E(sA, e4, rAu.z, 0,  pmA, rA, pxh.x, pyh.x, pzh.x, pwh.x, ich.x, thh.x)
    P3E(sA, e5, rAu.z, 16, pmA, rA, pxh.y, pyh.y, pzh.y, pwh.y, ich.y, thh.y)
    P3E(sA, e6, rAu.w, 0,  pmA, rA, pxh.z, pyh.z, pzh.z, pwh.z, ich.z, thh.z)
    P3E(sA, e7, rAu.w, 16, pmA, rA, pxh.w, pyh.w, pzh.w, pwh.w, ich.w, thh.w)
    {
      uint4 U_;
      U_.x = (unsigned)e0 | ((unsigned)e1 << 16);
      U_.y = (unsigned)e2 | ((unsigned)e3 << 16);
      U_.z = (unsigned)e4 | ((unsigned)e5 << 16);
      U_.w = (unsigned)e6 | ((unsigned)e7 << 16);
      *(uint4*)(eb + (size_t)mA * NN + n0) = U_;
    }
    P3E(sB, e0, rBu.x, 0,  pmB, rB, pxl.x, pyl.x, pzl.x, pwl.x, icl.x, thl.x)
    P3E(sB, e1, rBu.x, 16, pmB, rB, pxl.y, pyl.y, pzl.y, pwl.y, icl.y, thl.y)
    P3E(sB, e2, rBu.y, 0,  pmB, rB, pxl.z, pyl.z, pzl.z, pwl.z, icl.z, thl.z)
    P3E(sB, e3, rBu.y, 16, pmB, rB, pxl.w, pyl.w, pzl.w, pwl.w, icl.w, thl.w)
    P3E(sB, e4, rBu.z, 0,  pmB, rB, pxh.x, pyh.x, pzh.x, pwh.x, ich.x, thh.x)
    P3E(sB, e5, rBu.z, 16, pmB, rB, pxh.y, pyh.y, pzh.y, pwh.y, ich.y, thh.y)
    P3E(sB, e6, rBu.w, 0,  pmB, rB, pxh.z, pyh.z, pzh.z, pwh.z, ich.z, thh.z)
    P3E(sB, e7, rBu.w, 16, pmB, rB, pxh.w, pyh.w, pzh.w, pwh.w, ich.w, thh.w)
    {
      uint4 U_;
      U_.x = (unsigned)e0 | ((unsigned)e1 << 16);
      U_.y = (unsigned)e2 | ((unsigned)e3 << 16);
      U_.z = (unsigned)e4 | ((unsigned)e5 << 16);
      U_.w = (unsigned)e6 | ((unsigned)e7 << 16);
      *(uint4*)(eb + (size_t)mB * NN + n0) = U_;
    }
  }
#undef P3E
  WRED(sA) WRED(sB)
  if (lane == 0) {
    irs2[b * NN + mA] = rcpf_(sA);
    irs2[b * NN + mB] = rcpf_(sB);
  }
}

// P4: cs2[n] = sum_m bf16(bf16(ae[m][n]) * irs2[m]) -- exact match of what
// k7n stages into the MFMA.  1024 blocks (64-row m strips).
__global__ __launch_bounds__(256) void p4_cs2(
    const unsigned short* __restrict__ aeg, const float* __restrict__ irs2,
    float* __restrict__ cs2) {
  const int tid = threadIdx.x;
  const int bid = blockIdx.x;              // B*8*64 = 1024 blocks
  const int ms = bid & 63;                 // m strip (64 rows)
  const int ng = (bid >> 6) & 7;           // n group (512 cols)
  const int b  = bid >> 9;
  const int n2 = (ng << 9) + (tid << 1);   // 2 columns per thread
  const unsigned short* eb = aeg + (size_t)b * NN * NN + n2;
  const float* r2 = irs2 + b * NN;
  float s0 = 0.f, s1 = 0.f;
  const int m0 = ms << 6;
#pragma unroll 4
  for (int m = m0; m < m0 + 64; ++m) {
    const unsigned u = *(const unsigned*)(eb + (size_t)m * NN);
    const float r = r2[m];
    s0 += bf2f(f2bf(bf2f((unsigned short)(u & 0xffffu)) * r));
    s1 += bf2f(f2bf(bf2f((unsigned short)(u >> 16)) * r));
  }
  atomicAdd(&cs2[b * NN + n2], s0);
  atomicAdd(&cs2[b * NN + n2 + 1], s1);
}

// LDS swizzle: spreads both the b32 transpose-writes (2-way, free) and the
// b128 reads (uniform) across banks.
#define SW(r) ((((r) & 7) << 4) ^ ((((r) >> 3) & 3) << 5))

// K7N: GMA with fused g1/g2 combine (needs cs2 from p4).
__global__ __launch_bounds__(256) void k7n_gma(
    const unsigned short* __restrict__ a0g, const unsigned short* __restrict__ aeg,
    const unsigned short* __restrict__ xvb,
    const float* __restrict__ irs1, const float* __restrict__ irs2,
    const float* __restrict__ ics1, const float* __restrict__ cs2,
    float* __restrict__ gma) {
  const int tid = threadIdx.x;
  const int bid = blockIdx.x;              // 512 blocks: B * 64 nb * 4 msl
  const int msl = bid & 3;
  const int nb  = (bid >> 2) & 63;
  const int b   = bid >> 8;
  const int n0 = nb << 6;
  const int mstart = msl << 10;            // 1024-row m strip -> 16 tiles
  __shared__ __align__(16) unsigned short attns1[2][64 * 64];
  __shared__ __align__(16) unsigned short attns2[2][64 * 64];
  __shared__ __align__(16) unsigned short xvs[2][64 * 64];
  const unsigned short* ab = a0g + (size_t)b * NN * NN;
  const unsigned short* ebp = aeg + (size_t)b * NN * NN;
  const float* irs1b = irs1 + b * NN;
  const float* irs2b = irs2 + b * NN;
  const int w = tid >> 6, l = tid & 63;
  const int lrow0 = (w << 4) + ((l >> 3) << 1);
  const int nc8 = (l & 7) << 3;
  const int gcol = n0 + nc8;
  const int xc = tid >> 2, xpart = tid & 3;
  const unsigned short* xvp = xvb + ((size_t)b * 64 + xc) * NN;
  const int lr = l & 15, quad = l >> 4;
  const int nw = w << 4;
  f32x4v acc0 = {0,0,0,0}, acc1 = {0,0,0,0}, acc2 = {0,0,0,0}, acc3 = {0,0,0,0};
  f32x4v d0 = {0,0,0,0}, d1 = {0,0,0,0}, d2 = {0,0,0,0}, d3 = {0,0,0,0};

  uint4 pa0A, pa1A, pe0A, pe1A, pv0A, pv1A;
  uint4 pa0B, pa1B, pe0B, pe1B, pv0B, pv1B;
  float r1aA, r1bA, r2aA, r2bA, r1aB, r1bB, r2aB, r2bB;

#define ISSUE(S, MT) { \
    const int m0_ = mstart + ((MT) << 6); \
    const size_t ra_ = (size_t)(m0_ + lrow0) * NN + gcol; \
    pa0##S = *(const uint4*)(ab + ra_); \
    pa1##S = *(const uint4*)(ab + ra_ + NN); \
    pe0##S = *(const uint4*)(ebp + ra_); \
    pe1##S = *(const uint4*)(ebp + ra_ + NN); \
    pv0##S = *(const uint4*)(xvp + m0_ + (xpart << 4)); \
    pv1##S = *(const uint4*)(xvp + m0_ + (xpart << 4) + 8); \
    r1a##S = irs1b[m0_ + lrow0]; r1b##S = irs1b[m0_ + lrow0 + 1]; \
    r2a##S = irs2b[m0_ + lrow0]; r2b##S = irs2b[m0_ + lrow0 + 1]; }

#define CVW(D0, D1, SH, J, R0, R1, ARR) { \
    const float v0_ = bf2f((unsigned short)(((D0) >> (SH)) & 0xffffu)) * (R0); \
    const float v1_ = bf2f((unsigned short)(((D1) >> (SH)) & 0xffffu)) * (R1); \
    const unsigned pk_ = (unsigned)f2bf(v0_) | ((unsigned)f2bf(v1_) << 16); \
    const int nl_ = nc8 + (J); \
    *(unsigned*)((char*)(ARR) + ((((nl_) << 7) + (lrow0 << 1)) ^ SW(nl_))) = pk_; }

#define WR8(U0, U1, R0, R1, ARR) \
    CVW(U0.x, U1.x, 0,  0, R0, R1, ARR) CVW(U0.x, U1.x, 16, 1, R0, R1, ARR) \
    CVW(U0.y, U1.y, 0,  2, R0, R1, ARR) CVW(U0.y, U1.y, 16, 3, R0, R1, ARR) \
    CVW(U0.z, U1.z, 0,  4, R0, R1, ARR) CVW(U0.z, U1.z, 16, 5, R0, R1, ARR) \
    CVW(U0.w, U1.w, 0,  6, R0, R1, ARR) CVW(U0.w, U1.w, 16, 7, R0, R1, ARR)

#define STX(XARR, PV0, PV1) { \
    const int xb_ = (xc << 7) + (xpart << 5); \
    *(uint4*)((char*)(XARR) + ((xb_) ^ SW(xc))) = PV0; \
    *(uint4*)((char*)(XARR) + ((xb_ + 16) ^ SW(xc))) = PV1; }

#define LDSW(ARR, ROW, H, Q) \
    (*(const bf16x8*)((const char*)(ARR) + \
      ((((ROW) << 7) + ((H) << 6) + ((Q) << 4)) ^ SW(ROW))))

#define MPH(A1P, A2P, XVP_) { \
    for (int h = 0; h < 2; ++h) { \
      const bf16x8 fa1 = LDSW(A1P, nw + lr, h, quad); \
      const bf16x8 fa2 = LDSW(A2P, nw + lr, h, quad); \
      const bf16x8 fb0 = LDSW(XVP_, lr, h, quad); \
      const bf16x8 fb1 = LDSW(XVP_, 16 + lr, h, quad); \
      const bf16x8 fb2 = LDSW(XVP_, 32 + lr, h, quad); \
      const bf16x8 fb3 = LDSW(XVP_, 48 + lr, h, quad); \
      acc0 = __builtin_amdgcn_mfma_f32_16x16x32_bf16(fa1, fb0, acc0, 0, 0, 0); \
      acc1 = __builtin_amdgcn_mfma_f32_16x16x32_bf16(fa1, fb1, acc1, 0, 0, 0); \
      acc2 = __builtin_amdgcn_mfma_f32_16x16x32_bf16(fa1, fb2, acc2, 0, 0, 0); \
      acc3 = __builtin_amdgcn_mfma_f32_16x16x32_bf16(fa1, fb3, acc3, 0, 0, 0); \
      d0 = __builtin_amdgcn_mfma_f32_16x16x32_bf16(fa2, fb0, d0, 0, 0, 0); \
      d1 = __builtin_amdgcn_mfma_f32_16x16x32_bf16(fa2, fb1, d1, 0, 0, 0); \
      d2 = __builtin_amdgcn_mfma_f32_16x16x32_bf16(fa2, fb2, d2, 0, 0, 0); \
      d3 = __builtin_amdgcn_mfma_f32_16x16x32_bf16(fa2, fb3, d3, 0, 0, 0); \
    } }

  ISSUE(A, 0)
  ISSUE(B, 1)
  for (int mt = 0; mt < 16; mt += 2) {
    WR8(pa0A, pa1A, r1aA, r1bA, attns1[0])
    WR8(pe0A, pe1A, r2aA, r2bA, attns2[0])
    STX(xvs[0], pv0A, pv1A)
    __syncthreads();
    if (mt + 2 < 16) { ISSUE(A, mt + 2) }
    MPH(attns1[0], attns2[0], xvs[0])
    WR8(pa0B, pa1B, r1aB, r1bB, attns1[1])
    WR8(pe0B, pe1B, r2aB, r2bB, attns2[1])
    STX(xvs[1], pv0B, pv1B)
    __syncthreads();
    if (mt + 3 < 16) { ISSUE(B, mt + 3) }
    MPH(attns1[1], attns2[1], xvs[1])
  }
#undef ISSUE
#undef CVW
#undef WR8
#undef STX
#undef LDSW
#undef MPH
  float w10, w11, w12, w13, w20, w21, w22, w23;
  {
    const int nr = n0 + nw + (quad << 2);
    w10 = ics1[b * NN + nr + 0]; w20 = rcpf_(1e-9f + cs2[b * NN + nr + 0]);
    w11 = ics1[b * NN + nr + 1]; w21 = rcpf_(1e-9f + cs2[b * NN + nr + 1]);
    w12 = ics1[b * NN + nr + 2]; w22 = rcpf_(1e-9f + cs2[b * NN + nr + 2]);
    w13 = ics1[b * NN + nr + 3]; w23 = rcpf_(1e-9f + cs2[b * NN + nr + 3]);
  }
#define EPI(ACC, DD, CT) { \
    float* g_ = gma + ((size_t)b * NN + n0 + nw + (quad << 2)) * 64 + (CT) * 16 + lr; \
    atomicAdd(g_ + 0,   fmaf(ACC[0], w10, DD[0] * w20)); \
    atomicAdd(g_ + 64,  fmaf(ACC[1], w11, DD[1] * w21)); \
    atomicAdd(g_ + 128, fmaf(ACC[2], w12, DD[2] * w22)); \
    atomicAdd(g_ + 192, fmaf(ACC[3], w13, DD[3] * w23)); }
  EPI(acc0, d0, 0) EPI(acc1, d1, 1) EPI(acc2, d2, 2) EPI(acc3, d3, 3)
#undef EPI
}

// ===================== common p2 / k8 / k9 =====================

__global__ __launch_bounds__(256) void p2_cs1(
    const float* __restrict__ qt, const float* __restrict__ qk,
    const float* __restrict__ irs1, float* __restrict__ ics1) {
  const int tid = threadIdx.x;
  const int b = blockIdx.x >> 8;
  const int n0t = (blockIdx.x & 255) << 4;
  const int w = tid >> 6, lane = tid & 63;
  const float* qb = qt + (size_t)b * NN * 16;
  const float* kb = qk + (size_t)b * 16 * NN;
  const int nA = n0t + w, nB = n0t + w + 4, nC = n0t + w + 8, nD = n0t + w + 12;
  LQROW(na, qb + (size_t)nA * 16)
  LQROW(nb, qb + (size_t)nB * 16)
  LQROW(nc, qb + (size_t)nC * 16)
  LQROW(nd, qb + (size_t)nD * 16)
  float sA = 0.f, sB = 0.f, sC = 0.f, sD = 0.f;
  for (int it = 0; it < 16; ++it) {
    const int m0 = (it << 8) + (lane << 2);
    LKPL(kb, m0)
    const float4 r1 = *(const float4*)(irs1 + b * NN + m0);
    sA = fmaf(__expf(fminf(DOTC(na0,na1,na2,na3,x), 80.f)), r1.x, sA);
    sA = fmaf(__expf(fminf(DOTC(na0,na1,na2,na3,y), 80.f)), r1.y, sA);
    sA = fmaf(__expf(fminf(DOTC(na0,na1,na2,na3,z), 80.f)), r1.z, sA);
    sA = fmaf(__expf(fminf(DOTC(na0,na1,na2,na3,w), 80.f)), r1.w, sA);
    sB = fmaf(__expf(fminf(DOTC(nb0,nb1,nb2,nb3,x), 80.f)), r1.x, sB);
    sB = fmaf(__expf(fminf(DOTC(nb0,nb1,nb2,nb3,y), 80.f)), r1.y, sB);
    sB = fmaf(__expf(fminf(DOTC(nb0,nb1,nb2,nb3,z), 80.f)), r1.z, sB);
    sB = fmaf(__expf(fminf(DOTC(nb0,nb1,nb2,nb3,w), 80.f)), r1.w, sB);
    sC = fmaf(__expf(fminf(DOTC(nc0,nc1,nc2,nc3,x), 80.f)), r1.x, sC);
    sC = fmaf(__expf(fminf(DOTC(nc0,nc1,nc2,nc3,y), 80.f)), r1.y, sC);
    sC = fmaf(__expf(fminf(DOTC(nc0,nc1,nc2,nc3,z), 80.f)), r1.z, sC);
    sC = fmaf(__expf(fminf(DOTC(nc0,nc1,nc2,nc3,w), 80.f)), r1.w, sC);
    sD = fmaf(__expf(fminf(DOTC(nd0,nd1,nd2,nd3,x), 80.f)), r1.x, sD);
    sD = fmaf(__expf(fminf(DOTC(nd0,nd1,nd2,nd3,y), 80.f)), r1.y, sD);
    sD = fmaf(__expf(fminf(DOTC(nd0,nd1,nd2,nd3,z), 80.f)), r1.z, sD);
    sD = fmaf(__expf(fminf(DOTC(nd0,nd1,nd2,nd3,w), 80.f)), r1.w, sD);
  }
  WRED(sA) WRED(sB) WRED(sC) WRED(sD)
  if (lane == 0) {
    ics1[b * NN + nA] = rcpf_(1e-9f + sA);
    ics1[b * NN + nB] = rcpf_(1e-9f + sB);
    ics1[b * NN + nC] = rcpf_(1e-9f + sC);
    ics1[b * NN + nD] = rcpf_(1e-9f + sD);
  }
}

// mode 0: gma = g1 + g2*ics2 (fallback);  mode 2: gma already combined in g1.
__global__ __launch_bounds__(256) void k8_res(
    const void* __restrict__ mot, const void* __restrict__ wt,
    const void* __restrict__ bt, const float* __restrict__ flag,
    float* __restrict__ g1_res, const float* __restrict__ g2,
    const float* __restrict__ cs2, float* __restrict__ gn,
    const float* __restrict__ ics1, int g1mode) {
  const bool f32 = flag[0] > 0.5f;
  const int tid = threadIdx.x;
  const int bid = blockIdx.x;
  const int b = bid >> 9;
  const int n0 = (bid & 511) << 3;
  __shared__ float wtT[64 * 65];
  __shared__ float bts[64];
  __shared__ float md[8 * 64];
  __shared__ float gs[8], gss[8];
  for (int i = tid; i < 4096; i += 256) {
    int o = i & 63, c = i >> 6;
    wtT[c * 65 + o] = ldin(wt, o * 64 + c, f32);
  }
  if (tid < 64) bts[tid] = ldin(bt, tid, f32);
  if (tid < 8) { gs[tid] = 0.f; gss[tid] = 0.f; }
#pragma unroll
  for (int r = 0; r < 2; ++r) {
    const int idx = tid * 2 + r;
    const int c = idx & 63, nl = idx >> 6;
    const size_t gi = ((size_t)b * NN + n0 + nl) * 64 + c;
    float gmav;
    if (g1mode == 2) {
      gmav = g1_res[gi];
    } else {
      const float ics2n = rcpf_(1e-9f + cs2[b * NN + n0 + nl]);
      float g1v = g1_res[gi];
      if (g1mode == 1) g1v *= ics1[b * NN + n0 + nl];
      gmav = fmaf(g2[gi], ics2n, g1v);
    }
    md[nl * 64 + c] = ldin(mot, ((size_t)b * 64 + c) * NN + n0 + nl, f32) - gmav;
  }
  __syncthreads();
  const int o = tid & 63, ng = tid >> 6;
  const int nl0 = ng * 2, nl1 = ng * 2 + 1;
  float a0 = bts[o], a1 = bts[o];
#pragma unroll 8
  for (int c = 0; c < 64; ++c) {
    float w = wtT[c * 65 + o];
    a0 = fmaf(w, md[nl0 * 64 + c], a0);
    a1 = fmaf(w, md[nl1 * 64 + c], a1);
  }
  g1_res[((size_t)b * NN + n0 + nl0) * 64 + o] = a0;
  g1_res[((size_t)b * NN + n0 + nl1) * 64 + o] = a1;
  atomicAdd(&gs[o >> 3], a0 + a1);
  atomicAdd(&gss[o >> 3], a0 * a0 + a1 * a1);
  __syncthreads();
  if (tid < 8) atomicAdd(&gn[b * 8 + tid], gs[tid]);
  else if (tid < 16) atomicAdd(&gn[16 + b * 8 + (tid - 8)], gss[tid - 8]);
}

__global__ __launch_bounds__(256) void k9_out(
    const float* __restrict__ res, const float* __restrict__ gn,
    const void* __restrict__ mot,
    const void* __restrict__ gnw, const void* __restrict__ gnb,
    const void* __restrict__ pa, const void* __restrict__ al,
    const float* __restrict__ flag, void* __restrict__ out) {
  const bool f32 = flag[0] > 0.5f;
  const int idx = blockIdx.x * 256 + threadIdx.x;
  const int n = idx & 4095;
  const int c = (idx >> 12) & 63;
  const int b = idx >> 18;
  const int g = c >> 3;
  const float inv_cnt = 1.f / 32768.f;
  float mean = gn[b * 8 + g] * inv_cnt;
  float var = gn[16 + b * 8 + g] * inv_cnt - mean * mean;
  var = fmaxf(var, 0.f);
  float rstd = rsqrtf(var + 1e-5f);
  float r = res[((size_t)b * NN + n) * 64 + c];
  float y = (r - mean) * rstd * ldin(gnw, c, f32) + ldin(gnb, c, f32);
  float slope = ldin(pa, 0, f32);
  y = (y >= 0.f) ? y : slope * y;
  float o = ldin(al, 0, f32) * y + ldin(mot, idx, f32);
  if (f32) ((float*)out)[idx] = o;
  else     ((__hip_bfloat16*)out)[idx] = __float2bfloat16(o);
}

extern "C" void kernel_launch(void* const* d_in, const int* in_sizes, int n_in,
                              void* d_out, int out_size, void* d_ws, size_t ws_size,
                              hipStream_t stream) {
  const void* ctx = d_in[0];
  const void* mot = d_in[1];
  const void* xyz = d_in[2];
  const void* wqk = d_in[3];
  const void* wv  = d_in[4];
  const void* bv  = d_in[5];
  const void* wt  = d_in[6];
  const void* bt  = d_in[7];
  const void* gnw = d_in[8];
  const void* gnb = d_in[9];
  const void* pa  = d_in[10];
  const void* al  = d_in[11];
  float* ws = (float*)d_ws;
  const bool big = ws_size >= (size_t)FULL_F * sizeof(float);

  if (ws_size < (size_t)WS_TOTAL * sizeof(float))
    fprintf(stderr, "[gma3d] WARNING ws_size=%zu < needed %zu\n",
            ws_size, (size_t)WS_TOTAL * sizeof(float));

  hipMemsetAsync(ws + OFF_SUMS, 0, (size_t)ZERO_F * sizeof(float), stream);

  k0_detect<<<1, 256, 0, stream>>>((const unsigned short*)ctx, ws + OFF_FLAG);
  k1_q_xyz<<<32, 256, 0, stream>>>(ctx, xyz, wqk, ws + OFF_FLAG,
                                   ws + OFF_QT, ws + OFF_QK,
                                   ws + OFF_XYZ4, ws + OFF_XYZK, ws + OFF_SUMS);
  k2_xv<<<128, 256, 0, stream>>>(mot, wv, bv, ws + OFF_FLAG,
                                 (unsigned short*)(ws + OFF_XVB));
  k2b_thr<<<32, 256, 0, stream>>>(ws + OFF_XYZ4, ws + OFF_SUMS, ws + OFF_THR);

  if (big) {
    unsigned short* a0 = (unsigned short*)(ws + OFF_A0);
    unsigned short* ae = (unsigned short*)(ws + OFF_AE);
    p1w_rs1<<<1024, 256, 0, stream>>>(ws + OFF_QT, ws + OFF_QK, ws + OFF_IRS1, a0);
    p2r_cs1<<<2048, 256, 0, stream>>>(a0, ws + OFF_IRS1, ws + OFF_ICS1);
    p3w_rs2<<<1024, 256, 0, stream>>>(ws + OFF_XYZ4, ws + OFF_XYZK,
                                      ws + OFF_IRS1, ws + OFF_ICS1, ws + OFF_THR,
                                      ws + OFF_IRS2, a0, ae);
    p4_cs2<<<1024, 256, 0, stream>>>(ae, ws + OFF_IRS2, ws + OFF_CS2);
    k7n_gma<<<512, 256, 0, stream>>>(a0, ae,
                                     (const unsigned short*)(ws + OFF_XVB),
                                     ws + OFF_IRS1, ws + OFF_IRS2,
                                     ws + OFF_ICS1, ws + OFF_CS2,
                                     ws + OFF_GMA);
    k8_res<<<1024, 256, 0, stream>>>(mot, wt, bt, ws + OFF_FLAG,
                                     ws + OFF_GMA, ws + OFF_G2, ws + OFF_CS2,
                                     ws + OFF_GN, ws + OFF_ICS1, 2);
  } else {
    p1_rs1<<<512, 256, 0, stream>>>(ws + OFF_QT, ws + OFF_QK, ws + OFF_IRS1);
    p2_cs1<<<512, 256, 0, stream>>>(ws + OFF_QT, ws + OFF_QK, ws + OFF_IRS1, ws + OFF_ICS1);
    p3_rs2<<<512, 256, 0, stream>>>(ws + OFF_QT, ws + OFF_QK,
                                    ws + OFF_XYZ4, ws + OFF_XYZK,
                                    ws + OFF_IRS1, ws + OFF_ICS1, ws + OFF_THR,
                                    ws + OFF_IRS2);
    k7_gma<<<1024, 256, 0, stream>>>(ws + OFF_QT, ws + OFF_XYZ4,
                                     (const unsigned short*)(ws + OFF_XVB),
                                     ws + OFF_IRS1, ws + OFF_IRS2,
                                     ws + OFF_ICS1, ws + OFF_THR,
                                     ws + OFF_GMA, ws + OFF_G2, ws + OFF_CS2);
    k8_res<<<1024, 256, 0, stream>>>(mot, wt, bt, ws + OFF_FLAG,
                                     ws + OFF_GMA, ws + OFF_G2, ws + OFF_CS2,
                                     ws + OFF_GN, ws + OFF_ICS1, 0);
  }

  k9_out<<<2048, 256, 0, stream>>>(ws + OFF_GMA, ws + OFF_GN, mot, gnw, gnb, pa, al,
                                   ws + OFF_FLAG, d_out);
}

// Round 7
// 269.059 us; speedup vs baseline: 1.1130x; 1.0553x over previous
//
#include <hip/hip_runtime.h>
#include <hip/hip_bf16.h>
#include <cstdio>

#define NB 2
#define NN 4096
#define NC 64
#define NQ 16
#define POS_COEF 0.1f

// ---- workspace layout (float offsets) ----
#define OFF_QT   0u            // [B][N][16] row-major q
#define OFF_QK   131072u       // [B][16][N] planar k-major q (coalesced stream)
#define OFF_XYZ4 262144u       // [B][N][4]  row-major xyz+sq
#define OFF_XYZK 294912u       // [B][4][N]  planar xyz+sq
#define OFF_IRS1 327680u       // [B][N]
#define OFF_IRS2 335872u       // [B][N]
#define OFF_THR  344064u       // [B][N]
#define OFF_ICS1 352256u       // [B][N]  1/(1e-9+cs1)
#define OFF_FLAG 360448u       // [16]
#define OFF_XVB  360464u       // [B][64][N] bf16 (262144 floats)
// --- zeroed region below ---
#define OFF_SUMS 622608u       // [B][4]
#define OFF_GN   622616u       // [2][B][8]
#define OFF_CS2  622648u       // [B][N] colsum of local
#define OFF_GMA  630840u       // [B][N][64]  G1/combined gma -> res in k8
#define OFF_G2   1155128u      // [B][N][64]  G2 (fallback path only; big path
                               // reuses it: qbf hi/lo + raw row sums)
#define OFF_QBH  OFF_G2            // [B][N][16] bf16 hi of q (65536 floats)
#define OFF_QBL  (OFF_G2 + 65536u) // [B][N][16] bf16 lo of q (65536 floats)
#define OFF_RS1R (OFF_G2 + 131072u) // [B][N] f32 raw rs1 sums (zeroed)
#define WS_TOTAL 1679416u
#define ZERO_F   (WS_TOTAL - OFF_SUMS)
// --- optional materialized exp matrices (bf16), used iff ws_size permits ---
#define OFF_A0   1679424u      // [B][N][N] bf16 exp(corr)     (16777216 floats)
#define OFF_AE   18456640u     // [B][N][N] bf16 exp(l0)       (16777216 floats)
#define FULL_F   35233856u

using bf16x8 = __attribute__((ext_vector_type(8))) short;
using f32x4v = __attribute__((ext_vector_type(4))) float;

__device__ __forceinline__ float rcpf_(float x) { return __builtin_amdgcn_rcpf(x); }
__device__ __forceinline__ unsigned short f2bf(float x) {
  __hip_bfloat16 h = __float2bfloat16(x);
  return *(unsigned short*)&h;
}
__device__ __forceinline__ float bf2f(unsigned short u) {
  unsigned v = ((unsigned)u) << 16;
  return __builtin_bit_cast(float, v);
}

__device__ __forceinline__ float ldin(const void* p, size_t i, bool f32) {
  return f32 ? ((const float*)p)[i]
             : __bfloat162float(((const __hip_bfloat16*)p)[i]);
}

// 16-term fma tree, named float4 row against named float4 row
#define DOT16M(A0,A1,A2,A3,B0,B1,B2,B3) \
  fmaf((A0).x,(B0).x, fmaf((A0).y,(B0).y, fmaf((A0).z,(B0).z, fmaf((A0).w,(B0).w, \
  fmaf((A1).x,(B1).x, fmaf((A1).y,(B1).y, fmaf((A1).z,(B1).z, fmaf((A1).w,(B1).w, \
  fmaf((A2).x,(B2).x, fmaf((A2).y,(B2).y, fmaf((A2).z,(B2).z, fmaf((A2).w,(B2).w, \
  fmaf((A3).x,(B3).x, fmaf((A3).y,(B3).y, fmaf((A3).z,(B3).z, (A3).w*(B3).w)))))))))))))))

// dot of named row (M0..M3) against column C of k-planes k0..k15
#define DOTC(M0,M1,M2,M3,C) \
  fmaf((M0).x,k0.C, fmaf((M0).y,k1.C, fmaf((M0).z,k2.C, fmaf((M0).w,k3.C, \
  fmaf((M1).x,k4.C, fmaf((M1).y,k5.C, fmaf((M1).z,k6.C, fmaf((M1).w,k7.C, \
  fmaf((M2).x,k8.C, fmaf((M2).y,k9.C, fmaf((M2).z,k10.C, fmaf((M2).w,k11.C, \
  fmaf((M3).x,k12.C, fmaf((M3).y,k13.C, fmaf((M3).z,k14.C, (M3).w*k15.C)))))))))))))))

// planar k-plane loads: lanes read consecutive float4 -> fully coalesced
#define LKPL(base, n0) \
  const float4 k0  = *(const float4*)((base) + 0*NN  + (n0)); \
  const float4 k1  = *(const float4*)((base) + 1*NN  + (n0)); \
  const float4 k2  = *(const float4*)((base) + 2*NN  + (n0)); \
  const float4 k3  = *(const float4*)((base) + 3*NN  + (n0)); \
  const float4 k4  = *(const float4*)((base) + 4*NN  + (n0)); \
  const float4 k5  = *(const float4*)((base) + 5*NN  + (n0)); \
  const float4 k6  = *(const float4*)((base) + 6*NN  + (n0)); \
  const float4 k7  = *(const float4*)((base) + 7*NN  + (n0)); \
  const float4 k8  = *(const float4*)((base) + 8*NN  + (n0)); \
  const float4 k9  = *(const float4*)((base) + 9*NN  + (n0)); \
  const float4 k10 = *(const float4*)((base) + 10*NN + (n0)); \
  const float4 k11 = *(const float4*)((base) + 11*NN + (n0)); \
  const float4 k12 = *(const float4*)((base) + 12*NN + (n0)); \
  const float4 k13 = *(const float4*)((base) + 13*NN + (n0)); \
  const float4 k14 = *(const float4*)((base) + 14*NN + (n0)); \
  const float4 k15 = *(const float4*)((base) + 15*NN + (n0));

#define WRED(s) { s += __shfl_xor(s, 32); s += __shfl_xor(s, 16); \
  s += __shfl_xor(s, 8); s += __shfl_xor(s, 4); s += __shfl_xor(s, 2); s += __shfl_xor(s, 1); }

#define LQROW(v, base) \
  const float4 v##0 = *(const float4*)((base)); \
  const float4 v##1 = *(const float4*)((base) + 4); \
  const float4 v##2 = *(const float4*)((base) + 8); \
  const float4 v##3 = *(const float4*)((base) + 12);

// K0: detect input dtype
__global__ __launch_bounds__(256) void k0_detect(
    const unsigned short* __restrict__ ctx_u16, float* __restrict__ flag) {
  const int tid = threadIdx.x;
  int bad = 0;
  for (int i = tid; i < 8192; i += 256) {
    const unsigned short u = ctx_u16[i];
    const int e = (u >> 7) & 0xFF;
    if (e >= 134 || (e >= 1 && e <= 100)) bad++;
  }
  __shared__ int cnt;
  if (tid == 0) cnt = 0;
  __syncthreads();
  atomicAdd(&cnt, bad);
  __syncthreads();
  if (tid == 0) flag[0] = (cnt > 256) ? 1.0f : 0.0f;
}

// K1: q = Wqk @ ctx (row-major + planar + bf16 hi/lo split for MFMA),
// xyz (row + planar), batch sums
__global__ __launch_bounds__(256) void k1_q_xyz(
    const void* __restrict__ ctx, const void* __restrict__ xyz,
    const void* __restrict__ wqk, const float* __restrict__ flag,
    float* __restrict__ qt, float* __restrict__ qk,
    float* __restrict__ xyz4, float* __restrict__ xyzk,
    float* __restrict__ sums,
    unsigned short* __restrict__ qbh, unsigned short* __restrict__ qbl) {
  const bool f32 = flag[0] > 0.5f;
  const int tid = threadIdx.x;
  const int b = blockIdx.x >> 4;
  const int n = ((blockIdx.x & 15) << 8) + tid;
  __shared__ float wqT[NQ * NC];  // [c][o]
  for (int i = tid; i < NQ * NC; i += 256) {
    int o = i & 15, c = i >> 4;
    wqT[c * 16 + o] = ldin(wqk, o * 64 + c, f32);
  }
  __syncthreads();
  float4 a0 = {0,0,0,0}, a1 = {0,0,0,0}, a2 = {0,0,0,0}, a3 = {0,0,0,0};
  const size_t cbase = (size_t)b * 64 * NN + n;
#pragma unroll 4
  for (int c = 0; c < 64; ++c) {
    float x = ldin(ctx, cbase + (size_t)c * NN, f32);
    const float4 w0 = *(const float4*)(wqT + c * 16 + 0);
    const float4 w1 = *(const float4*)(wqT + c * 16 + 4);
    const float4 w2 = *(const float4*)(wqT + c * 16 + 8);
    const float4 w3 = *(const float4*)(wqT + c * 16 + 12);
    a0.x = fmaf(w0.x, x, a0.x); a0.y = fmaf(w0.y, x, a0.y); a0.z = fmaf(w0.z, x, a0.z); a0.w = fmaf(w0.w, x, a0.w);
    a1.x = fmaf(w1.x, x, a1.x); a1.y = fmaf(w1.y, x, a1.y); a1.z = fmaf(w1.z, x, a1.z); a1.w = fmaf(w1.w, x, a1.w);
    a2.x = fmaf(w2.x, x, a2.x); a2.y = fmaf(w2.y, x, a2.y); a2.z = fmaf(w2.z, x, a2.z); a2.w = fmaf(w2.w, x, a2.w);
    a3.x = fmaf(w3.x, x, a3.x); a3.y = fmaf(w3.y, x, a3.y); a3.z = fmaf(w3.z, x, a3.z); a3.w = fmaf(w3.w, x, a3.w);
  }
  float* qp = qt + (size_t)(b * NN + n) * 16;
  *(float4*)(qp + 0) = a0; *(float4*)(qp + 4) = a1;
  *(float4*)(qp + 8) = a2; *(float4*)(qp + 12) = a3;
  float* kq = qk + (size_t)b * 16 * NN + n;
  kq[0*NN]=a0.x;  kq[1*NN]=a0.y;  kq[2*NN]=a0.z;  kq[3*NN]=a0.w;
  kq[4*NN]=a1.x;  kq[5*NN]=a1.y;  kq[6*NN]=a1.z;  kq[7*NN]=a1.w;
  kq[8*NN]=a2.x;  kq[9*NN]=a2.y;  kq[10*NN]=a2.z; kq[11*NN]=a2.w;
  kq[12*NN]=a3.x; kq[13*NN]=a3.y; kq[14*NN]=a3.z; kq[15*NN]=a3.w;
  if (qbh) {
    // bf16 hi/lo split of the q row for the MFMA corr kernel
    const float v0=a0.x, v1=a0.y, v2=a0.z, v3=a0.w;
    const float v4=a1.x, v5=a1.y, v6=a1.z, v7=a1.w;
    const float v8=a2.x, v9=a2.y, v10=a2.z, v11=a2.w;
    const float v12=a3.x, v13=a3.y, v14=a3.z, v15=a3.w;
#define HL(I, V) \
    const unsigned short h##I = f2bf(V); \
    const unsigned short l##I = f2bf((V) - bf2f(h##I));
    HL(0,v0) HL(1,v1) HL(2,v2) HL(3,v3) HL(4,v4) HL(5,v5) HL(6,v6) HL(7,v7)
    HL(8,v8) HL(9,v9) HL(10,v10) HL(11,v11) HL(12,v12) HL(13,v13) HL(14,v14) HL(15,v15)
#undef HL
#define PK(A,B) ((unsigned)(A) | ((unsigned)(B) << 16))
    uint4 H0, H1, L0, L1;
    H0.x = PK(h0,h1);   H0.y = PK(h2,h3);   H0.z = PK(h4,h5);   H0.w = PK(h6,h7);
    H1.x = PK(h8,h9);   H1.y = PK(h10,h11); H1.z = PK(h12,h13); H1.w = PK(h14,h15);
    L0.x = PK(l0,l1);   L0.y = PK(l2,l3);   L0.z = PK(l4,l5);   L0.w = PK(l6,l7);
    L1.x = PK(l8,l9);   L1.y = PK(l10,l11); L1.z = PK(l12,l13); L1.w = PK(l14,l15);
#undef PK
    unsigned short* qhp = qbh + (size_t)(b * NN + n) * 16;
    unsigned short* qlp = qbl + (size_t)(b * NN + n) * 16;
    *(uint4*)(qhp) = H0; *(uint4*)(qhp + 8) = H1;
    *(uint4*)(qlp) = L0; *(uint4*)(qlp + 8) = L1;
  }
  float xx = ldin(xyz, (size_t)(b * NN + n) * 3 + 0, f32);
  float yy = ldin(xyz, (size_t)(b * NN + n) * 3 + 1, f32);
  float zz = ldin(xyz, (size_t)(b * NN + n) * 3 + 2, f32);
  float4 p; p.x = xx; p.y = yy; p.z = zz; p.w = fmaf(xx, xx, fmaf(yy, yy, zz * zz));
  *(float4*)(xyz4 + (size_t)(b * NN + n) * 4) = p;
  float* kx = xyzk + (size_t)b * 4 * NN + n;
  kx[0*NN]=p.x; kx[1*NN]=p.y; kx[2*NN]=p.z; kx[3*NN]=p.w;
  float sx = p.x, sy = p.y, sz = p.z, sw = p.w;
  WRED(sx) WRED(sy) WRED(sz) WRED(sw)
  if ((tid & 63) == 0) {
    atomicAdd(&sums[b * 4 + 0], sx);
    atomicAdd(&sums[b * 4 + 1], sy);
    atomicAdd(&sums[b * 4 + 2], sz);
    atomicAdd(&sums[b * 4 + 3], sw);
  }
}

// K2: xv = Wv @ motion + bv, bf16 channel-major [b][c][n]
__global__ __launch_bounds__(256) void k2_xv(
    const void* __restrict__ mot, const void* __restrict__ wv,
    const void* __restrict__ bv, const float* __restrict__ flag,
    unsigned short* __restrict__ xvb) {
  const bool f32 = flag[0] > 0.5f;
  const int tid = threadIdx.x;
  const int b = blockIdx.x >> 6;
  const int n = ((blockIdx.x & 63) << 6) + (tid >> 2);
  const int og = tid & 3;
  __shared__ float wvT[NC * NC];
  __shared__ float bvs[NC];
  for (int i = tid; i < NC * NC; i += 256) {
    int o = i & 63, c = i >> 6;
    wvT[c * 64 + o] = ldin(wv, o * 64 + c, f32);
  }
  if (tid < 64) bvs[tid] = ldin(bv, tid, f32);
  __syncthreads();
  float4 a0 = *(const float4*)(bvs + og * 16 + 0);
  float4 a1 = *(const float4*)(bvs + og * 16 + 4);
  float4 a2 = *(const float4*)(bvs + og * 16 + 8);
  float4 a3 = *(const float4*)(bvs + og * 16 + 12);
  const size_t mbase = (size_t)b * 64 * NN + n;
#pragma unroll 4
  for (int c = 0; c < 64; ++c) {
    float x = ldin(mot, mbase + (size_t)c * NN, f32);
    const float4 w0 = *(const float4*)(wvT + c * 64 + og * 16 + 0);
    const float4 w1 = *(const float4*)(wvT + c * 64 + og * 16 + 4);
    const float4 w2 = *(const float4*)(wvT + c * 64 + og * 16 + 8);
    const float4 w3 = *(const float4*)(wvT + c * 64 + og * 16 + 12);
    a0.x = fmaf(w0.x, x, a0.x); a0.y = fmaf(w0.y, x, a0.y); a0.z = fmaf(w0.z, x, a0.z); a0.w = fmaf(w0.w, x, a0.w);
    a1.x = fmaf(w1.x, x, a1.x); a1.y = fmaf(w1.y, x, a1.y); a1.z = fmaf(w1.z, x, a1.z); a1.w = fmaf(w1.w, x, a1.w);
    a2.x = fmaf(w2.x, x, a2.x); a2.y = fmaf(w2.y, x, a2.y); a2.z = fmaf(w2.z, x, a2.z); a2.w = fmaf(w2.w, x, a2.w);
    a3.x = fmaf(w3.x, x, a3.x); a3.y = fmaf(w3.y, x, a3.y); a3.z = fmaf(w3.z, x, a3.z); a3.w = fmaf(w3.w, x, a3.w);
  }
  unsigned short* xb = xvb + (size_t)b * 64 * NN + n;
  const int o0 = og * 16;
  xb[(size_t)(o0 + 0) * NN] = f2bf(a0.x);  xb[(size_t)(o0 + 1) * NN] = f2bf(a0.y);
  xb[(size_t)(o0 + 2) * NN] = f2bf(a0.z);  xb[(size_t)(o0 + 3) * NN] = f2bf(a0.w);
  xb[(size_t)(o0 + 4) * NN] = f2bf(a1.x);  xb[(size_t)(o0 + 5) * NN] = f2bf(a1.y);
  xb[(size_t)(o0 + 6) * NN] = f2bf(a1.z);  xb[(size_t)(o0 + 7) * NN] = f2bf(a1.w);
  xb[(size_t)(o0 + 8) * NN] = f2bf(a2.x);  xb[(size_t)(o0 + 9) * NN] = f2bf(a2.y);
  xb[(size_t)(o0 +10) * NN] = f2bf(a2.z);  xb[(size_t)(o0 +11) * NN] = f2bf(a2.w);
  xb[(size_t)(o0 +12) * NN] = f2bf(a3.x);  xb[(size_t)(o0 +13) * NN] = f2bf(a3.y);
  xb[(size_t)(o0 +14) * NN] = f2bf(a3.z);  xb[(size_t)(o0 +15) * NN] = f2bf(a3.w);
}

// K2b: thr[n] = 0.1*(1e-9 + csd[n]) analytic
__global__ __launch_bounds__(256) void k2b_thr(
    const float* __restrict__ xyz4, const float* __restrict__ sums,
    float* __restrict__ thr) {
  const int idx = blockIdx.x * 256 + threadIdx.x;
  const int b = idx >> 12;
  const float4 pn = *(const float4*)(xyz4 + (size_t)idx * 4);
  const float Px = sums[b * 4 + 0], Py = sums[b * 4 + 1];
  const float Pz = sums[b * 4 + 2], S1 = sums[b * 4 + 3];
  float csd = fmaf((float)NN, pn.w, S1)
            - 2.f * (pn.x * Px + pn.y * Py + pn.z * Pz);
  thr[idx] = POS_COEF * (1e-9f + csd);
}

// ===================== fallback (round-13) p1/p3/k7 =====================

__global__ __launch_bounds__(256) void p1_rs1(
    const float* __restrict__ qt, const float* __restrict__ qk,
    float* __restrict__ irs1) {
  const int tid = threadIdx.x;
  const int b = blockIdx.x >> 8;
  const int m0 = (blockIdx.x & 255) << 4;
  const int w = tid >> 6, lane = tid & 63;
  const float* qb = qt + (size_t)b * NN * 16;
  const float* kb = qk + (size_t)b * 16 * NN;
  const int mA = m0 + w, mB = m0 + w + 4, mC = m0 + w + 8, mD = m0 + w + 12;
  LQROW(ma, qb + (size_t)mA * 16)
  LQROW(mb, qb + (size_t)mB * 16)
  LQROW(mc, qb + (size_t)mC * 16)
  LQROW(md, qb + (size_t)mD * 16)
  float sA = 0.f, sB = 0.f, sC = 0.f, sD = 0.f;
  for (int it = 0; it < 16; ++it) {
    const int n0 = (it << 8) + (lane << 2);
    LKPL(kb, n0)
    sA += __expf(fminf(DOTC(ma0,ma1,ma2,ma3,x), 80.f));
    sA += __expf(fminf(DOTC(ma0,ma1,ma2,ma3,y), 80.f));
    sA += __expf(fminf(DOTC(ma0,ma1,ma2,ma3,z), 80.f));
    sA += __expf(fminf(DOTC(ma0,ma1,ma2,ma3,w), 80.f));
    sB += __expf(fminf(DOTC(mb0,mb1,mb2,mb3,x), 80.f));
    sB += __expf(fminf(DOTC(mb0,mb1,mb2,mb3,y), 80.f));
    sB += __expf(fminf(DOTC(mb0,mb1,mb2,mb3,z), 80.f));
    sB += __expf(fminf(DOTC(mb0,mb1,mb2,mb3,w), 80.f));
    sC += __expf(fminf(DOTC(mc0,mc1,mc2,mc3,x), 80.f));
    sC += __expf(fminf(DOTC(mc0,mc1,mc2,mc3,y), 80.f));
    sC += __expf(fminf(DOTC(mc0,mc1,mc2,mc3,z), 80.f));
    sC += __expf(fminf(DOTC(mc0,mc1,mc2,mc3,w), 80.f));
    sD += __expf(fminf(DOTC(md0,md1,md2,md3,x), 80.f));
    sD += __expf(fminf(DOTC(md0,md1,md2,md3,y), 80.f));
    sD += __expf(fminf(DOTC(md0,md1,md2,md3,z), 80.f));
    sD += __expf(fminf(DOTC(md0,md1,md2,md3,w), 80.f));
  }
  WRED(sA) WRED(sB) WRED(sC) WRED(sD)
  if (lane == 0) {
    irs1[b * NN + mA] = rcpf_(sA);
    irs1[b * NN + mB] = rcpf_(sB);
    irs1[b * NN + mC] = rcpf_(sC);
    irs1[b * NN + mD] = rcpf_(sD);
  }
}

__global__ __launch_bounds__(256) void p3_rs2(
    const float* __restrict__ qt, const float* __restrict__ qk,
    const float* __restrict__ xyz4, const float* __restrict__ xyzk,
    const float* __restrict__ irs1, const float* __restrict__ ics1,
    const float* __restrict__ thr, float* __restrict__ irs2) {
  const int tid = threadIdx.x;
  const int b = blockIdx.x >> 8;
  const int m0 = (blockIdx.x & 255) << 4;
  const int w = tid >> 6, lane = tid & 63;
  const float* qb = qt + (size_t)b * NN * 16;
  const float* kb = qk + (size_t)b * 16 * NN;
  const float* xk = xyzk + (size_t)b * 4 * NN;
  const int mA = m0 + w, mB = m0 + w + 4, mC = m0 + w + 8, mD = m0 + w + 12;
  LQROW(ma, qb + (size_t)mA * 16)
  LQROW(mb, qb + (size_t)mB * 16)
  LQROW(mc, qb + (size_t)mC * 16)
  LQROW(md, qb + (size_t)mD * 16)
  const float4 pmA = *(const float4*)(xyz4 + ((size_t)b * NN + mA) * 4);
  const float4 pmB = *(const float4*)(xyz4 + ((size_t)b * NN + mB) * 4);
  const float4 pmC = *(const float4*)(xyz4 + ((size_t)b * NN + mC) * 4);
  const float4 pmD = *(const float4*)(xyz4 + ((size_t)b * NN + mD) * 4);
  const float rA = irs1[b * NN + mA];
  const float rB = irs1[b * NN + mB];
  const float rC = irs1[b * NN + mC];
  const float rD = irs1[b * NN + mD];
  float sA = 0.f, sB = 0.f, sC = 0.f, sD = 0.f;
#define P3C(S, M0,M1,M2,M3, PM, R, C) { \
    float corr_ = DOTC(M0,M1,M2,M3,C); \
    float a1v_ = __expf(fminf(corr_, 80.f)) * (R) * ic.C; \
    float dd_ = (PM).w + pw.C - 2.f * ((PM).x * px.C + (PM).y * py.C + (PM).z * pz.C); \
    dd_ = fmaxf(dd_, 0.f); \
    float l0_ = (dd_ <= th.C) ? a1v_ : 0.f; \
    S += __expf(l0_); }
  for (int it = 0; it < 16; ++it) {
    const int n0 = (it << 8) + (lane << 2);
    LKPL(kb, n0)
    const float4 px = *(const float4*)(xk + 0*NN + n0);
    const float4 py = *(const float4*)(xk + 1*NN + n0);
    const float4 pz = *(const float4*)(xk + 2*NN + n0);
    const float4 pw = *(const float4*)(xk + 3*NN + n0);
    const float4 ic = *(const float4*)(ics1 + b * NN + n0);
    const float4 th = *(const float4*)(thr + b * NN + n0);
    P3C(sA, ma0,ma1,ma2,ma3, pmA, rA, x)
    P3C(sA, ma0,ma1,ma2,ma3, pmA, rA, y)
    P3C(sA, ma0,ma1,ma2,ma3, pmA, rA, z)
    P3C(sA, ma0,ma1,ma2,ma3, pmA, rA, w)
    P3C(sB, mb0,mb1,mb2,mb3, pmB, rB, x)
    P3C(sB, mb0,mb1,mb2,mb3, pmB, rB, y)
    P3C(sB, mb0,mb1,mb2,mb3, pmB, rB, z)
    P3C(sB, mb0,mb1,mb2,mb3, pmB, rB, w)
    P3C(sC, mc0,mc1,mc2,mc3, pmC, rC, x)
    P3C(sC, mc0,mc1,mc2,mc3, pmC, rC, y)
    P3C(sC, mc0,mc1,mc2,mc3, pmC, rC, z)
    P3C(sC, mc0,mc1,mc2,mc3, pmC, rC, w)
    P3C(sD, md0,md1,md2,md3, pmD, rD, x)
    P3C(sD, md0,md1,md2,md3, pmD, rD, y)
    P3C(sD, md0,md1,md2,md3, pmD, rD, z)
    P3C(sD, md0,md1,md2,md3, pmD, rD, w)
  }
#undef P3C
  WRED(sA) WRED(sB) WRED(sC) WRED(sD)
  if (lane == 0) {
    irs2[b * NN + mA] = rcpf_(sA);
    irs2[b * NN + mB] = rcpf_(sB);
    irs2[b * NN + mC] = rcpf_(sC);
    irs2[b * NN + mD] = rcpf_(sD);
  }
}

__global__ __launch_bounds__(256) void k7_gma(
    const float* __restrict__ qt, const float* __restrict__ xyz4,
    const unsigned short* __restrict__ xvb,
    const float* __restrict__ irs1, const float* __restrict__ irs2,
    const float* __restrict__ ics1, const float* __restrict__ thr,
    float* __restrict__ g1, float* __restrict__ g2, float* __restrict__ cs2) {
  const int tid = threadIdx.x;
  const int bid = blockIdx.x;
  const int msl = bid & 7;
  const int nb = (bid >> 3) & 63;
  const int b = bid >> 9;
  const int n0 = nb << 6;
  const int mstart = msl << 9;
  __shared__ __align__(16) unsigned short attns1[64 * 72];
  __shared__ __align__(16) unsigned short attns2[64 * 72];
  __shared__ __align__(16) unsigned short xvs[64 * 72];
  const float* qb = qt + (size_t)b * NN * 16;
  const float* pb = xyz4 + (size_t)b * NN * 4;
  const int ni = tid & 63, aw = tid >> 6;
  const int na = n0 + ni;
  const float* qnp = qb + (size_t)na * 16;
  LQROW(q, qnp)
  const float4 pn = *(const float4*)(pb + (size_t)na * 4);
  const float ics1n = ics1[b * NN + na];
  const float thr_n = thr[b * NN + na];
  const int lane = tid & 63, wv = tid >> 6;
  const int lr = lane & 15, quad = lane >> 4;
  const int nw = wv << 4;
  f32x4v acc0 = {0,0,0,0}, acc1 = {0,0,0,0}, acc2 = {0,0,0,0}, acc3 = {0,0,0,0};
  f32x4v d0 = {0,0,0,0}, d1 = {0,0,0,0}, d2 = {0,0,0,0}, d3 = {0,0,0,0};
  float csacc = 0.f;
#define COMPA(MOFF, D1, D2) { \
    const int m_ = __builtin_amdgcn_readfirstlane(mw + (MOFF)); \
    const float* qm_ = qb + (size_t)m_ * 16; \
    LQROW(wq, qm_) \
    float corr_ = DOT16M(q0, q1, q2, q3, wq0, wq1, wq2, wq3); \
    const float4 pm_ = *(const float4*)(pb + (size_t)m_ * 4); \
    float a1v_ = __expf(fminf(corr_, 80.f)) * irs1[b * NN + m_] * ics1n; \
    float dd_ = pm_.w + pn.w - 2.f * (pm_.x * pn.x + pm_.y * pn.y + pm_.z * pn.z); \
    dd_ = fmaxf(dd_, 0.f); \
    float l0_ = (dd_ <= thr_n) ? a1v_ : 0.f; \
    float l2n_ = __expf(l0_) * irs2[b * NN + m_]; \
    D1 = f2bf(a1v_); D2 = f2bf(l2n_); csacc += l2n_; }
  for (int mt = 0; mt < 8; ++mt) {
    const int m0 = mstart + (mt << 6);
    __syncthreads();
    {
      const int c = tid >> 2, part = tid & 3;
      const unsigned short* src = xvb + ((size_t)b * 64 + c) * NN + m0 + part * 16;
      unsigned short* dst = xvs + c * 72 + part * 16;
      *(uint4*)dst = *(const uint4*)src;
      *(uint4*)(dst + 8) = *(const uint4*)(src + 8);
    }
    const int mw = m0 + (aw << 4);
#pragma unroll
    for (int g = 0; g < 4; ++g) {
      ushort4 u1, u2;
      COMPA(g * 4 + 0, u1.x, u2.x)
      COMPA(g * 4 + 1, u1.y, u2.y)
      COMPA(g * 4 + 2, u1.z, u2.z)
      COMPA(g * 4 + 3, u1.w, u2.w)
      *(ushort4*)(attns1 + ni * 72 + (aw << 4) + (g << 2)) = u1;
      *(ushort4*)(attns2 + ni * 72 + (aw << 4) + (g << 2)) = u2;
    }
    __syncthreads();
#pragma unroll
    for (int h = 0; h < 2; ++h) {
      const bf16x8 a1 = *(const bf16x8*)(attns1 + (nw + lr) * 72 + h * 32 + quad * 8);
      const bf16x8 a2 = *(const bf16x8*)(attns2 + (nw + lr) * 72 + h * 32 + quad * 8);
      const bf16x8 b0 = *(const bf16x8*)(xvs + (lr) * 72 + h * 32 + quad * 8);
      const bf16x8 b1 = *(const bf16x8*)(xvs + (16 + lr) * 72 + h * 32 + quad * 8);
      const bf16x8 b2 = *(const bf16x8*)(xvs + (32 + lr) * 72 + h * 32 + quad * 8);
      const bf16x8 b3 = *(const bf16x8*)(xvs + (48 + lr) * 72 + h * 32 + quad * 8);
      acc0 = __builtin_amdgcn_mfma_f32_16x16x32_bf16(a1, b0, acc0, 0, 0, 0);
      acc1 = __builtin_amdgcn_mfma_f32_16x16x32_bf16(a1, b1, acc1, 0, 0, 0);
      acc2 = __builtin_amdgcn_mfma_f32_16x16x32_bf16(a1, b2, acc2, 0, 0, 0);
      acc3 = __builtin_amdgcn_mfma_f32_16x16x32_bf16(a1, b3, acc3, 0, 0, 0);
      d0 = __builtin_amdgcn_mfma_f32_16x16x32_bf16(a2, b0, d0, 0, 0, 0);
      d1 = __builtin_amdgcn_mfma_f32_16x16x32_bf16(a2, b1, d1, 0, 0, 0);
      d2 = __builtin_amdgcn_mfma_f32_16x16x32_bf16(a2, b2, d2, 0, 0, 0);
      d3 = __builtin_amdgcn_mfma_f32_16x16x32_bf16(a2, b3, d3, 0, 0, 0);
    }
  }
#undef COMPA
  atomicAdd(&cs2[b * NN + na], csacc);
#define EPI(ACC, DST, CT) { \
    float* g_ = (DST) + ((size_t)b * NN + n0 + nw + (quad << 2)) * 64 + (CT) * 16 + lr; \
    atomicAdd(g_ + 0,   ACC[0]); \
    atomicAdd(g_ + 64,  ACC[1]); \
    atomicAdd(g_ + 128, ACC[2]); \
    atomicAdd(g_ + 192, ACC[3]); }
  EPI(acc0, g1, 0) EPI(acc1, g1, 1) EPI(acc2, g1, 2) EPI(acc3, g1, 3)
  EPI(d0, g2, 0) EPI(d1, g2, 1) EPI(d2, g2, 2) EPI(d3, g2, 3)
#undef EPI
}

// ============ materialized-exp path (used iff ws_size permits) ============

// P1M: a0 tile [64m x 64n] per block via bf16-split MFMA.
// q = hi + lo (hi=bf16(q), lo=bf16(q-hi)).  One K=32 mfma with A=[hi,lo]
// against B=[hi,hi] plus one against B=[lo,lo] gives the exact 4-term
// product -- corr to ~2^-16 relative, far below a0's bf16 rounding.
// L2 q-traffic: 64 MB total (vs p1w's 1.07 GB).  Epilogue: exp -> bf16 ->
// LDS transpose (stride 72, 2-way = free) -> coalesced 32B stores + row-sum
// partials (2 shfl + 1 atomic per row per block).
__global__ __launch_bounds__(256) void p1m_corr(
    const unsigned short* __restrict__ qbh, const unsigned short* __restrict__ qbl,
    float* __restrict__ rs1raw, unsigned short* __restrict__ a0g) {
  const int tid = threadIdx.x;
  const int nt = blockIdx.x & 63;
  const int mt = (blockIdx.x >> 6) & 63;
  const int b  = blockIdx.x >> 12;
  const int m0 = mt << 6, n0 = nt << 6;
  const int w = tid >> 6, l = tid & 63;
  const int lr = l & 15, quad = l >> 4;
  const int qk8 = (quad & 1) << 3;
  __shared__ __align__(16) unsigned short t0[64 * 72];
  const unsigned short* qh = qbh + (size_t)b * NN * 16;
  const unsigned short* qlo = qbl + (size_t)b * NN * 16;
  // A frag: rows m0 + w*16 + lr; k 0-15 = hi, k 16-31 = lo (quad selects)
  const int arow = m0 + (w << 4) + lr;
  const bf16x8 afrag = *(const bf16x8*)((quad < 2 ? qh : qlo) + (size_t)arow * 16 + qk8);
  f32x4v acc0 = {0,0,0,0}, acc1 = {0,0,0,0}, acc2 = {0,0,0,0}, acc3 = {0,0,0,0};
#define DOS(ACC, S) { \
    const int brow_ = n0 + ((S) << 4) + lr; \
    const bf16x8 bhh_ = *(const bf16x8*)(qh + (size_t)brow_ * 16 + qk8); \
    const bf16x8 bll_ = *(const bf16x8*)(qlo + (size_t)brow_ * 16 + qk8); \
    ACC = __builtin_amdgcn_mfma_f32_16x16x32_bf16(afrag, bhh_, ACC, 0, 0, 0); \
    ACC = __builtin_amdgcn_mfma_f32_16x16x32_bf16(afrag, bll_, ACC, 0, 0, 0); }
  DOS(acc0, 0) DOS(acc1, 1) DOS(acc2, 2) DOS(acc3, 3)
#undef DOS
  // exp + bf16 -> LDS (C layout: row = quad*4+j within wave's 16, col = lr)
  unsigned short* tw = t0 + (w << 4) * 72;
#define EPW(ACC, S) { \
    tw[((quad << 2) + 0) * 72 + ((S) << 4) + lr] = f2bf(__expf(fminf(ACC[0], 80.f))); \
    tw[((quad << 2) + 1) * 72 + ((S) << 4) + lr] = f2bf(__expf(fminf(ACC[1], 80.f))); \
    tw[((quad << 2) + 2) * 72 + ((S) << 4) + lr] = f2bf(__expf(fminf(ACC[2], 80.f))); \
    tw[((quad << 2) + 3) * 72 + ((S) << 4) + lr] = f2bf(__expf(fminf(ACC[3], 80.f))); }
  EPW(acc0, 0) EPW(acc1, 1) EPW(acc2, 2) EPW(acc3, 3)
#undef EPW
  __syncthreads();
  // coalesced write-out + rounded row sums
  const int row = tid >> 2, cb = (tid & 3) << 4;
  const unsigned short* src = t0 + row * 72 + cb;
  const uint4 u0 = *(const uint4*)(src);
  const uint4 u1 = *(const uint4*)(src + 8);
  unsigned short* dst = a0g + (size_t)b * NN * NN + (size_t)(m0 + row) * NN + n0 + cb;
  *(uint4*)dst = u0;
  *(uint4*)(dst + 8) = u1;
  float s = 0.f;
#define SUM2(U) { s += bf2f((unsigned short)((U) & 0xffffu)) + bf2f((unsigned short)((U) >> 16)); }
  SUM2(u0.x) SUM2(u0.y) SUM2(u0.z) SUM2(u0.w)
  SUM2(u1.x) SUM2(u1.y) SUM2(u1.z) SUM2(u1.w)
#undef SUM2
  s += __shfl_xor(s, 1);
  s += __shfl_xor(s, 2);
  if ((tid & 3) == 0) atomicAdd(&rs1raw[b * NN + m0 + row], s);
}

// K_INV: irs1[i] = 1/rs1raw[i]
__global__ __launch_bounds__(256) void k_inv(
    const float* __restrict__ raw, float* __restrict__ irs1) {
  const int i = blockIdx.x * 256 + threadIdx.x;
  irs1[i] = rcpf_(raw[i]);
}

// P2R: cs1 via SYMMETRY of corr: cs1[n] = sum_m a0[n][m]*irs1[m].
__global__ __launch_bounds__(256) void p2r_cs1(
    const unsigned short* __restrict__ a0g, const float* __restrict__ irs1,
    float* __restrict__ ics1) {
  const int tid = threadIdx.x;
  const int w = tid >> 6, l = tid & 63;
  const int bi = blockIdx.x;                 // 0..2047
  const int b = bi >> 10;
  const int n = ((bi & 1023) << 2) + w;      // 4 rows per block, 1 per wave
  const unsigned short* row = a0g + ((size_t)b * NN + n) * NN;
  const float* ir = irs1 + b * NN;
  float s = 0.f;
#pragma unroll
  for (int it = 0; it < 8; ++it) {
    const int m = (it << 9) + (l << 3);
    const uint4 u = *(const uint4*)(row + m);
    const float4 i0 = *(const float4*)(ir + m);
    const float4 i1 = *(const float4*)(ir + m + 4);
    s = fmaf(bf2f((unsigned short)(u.x & 0xffffu)), i0.x, s);
    s = fmaf(bf2f((unsigned short)(u.x >> 16)),     i0.y, s);
    s = fmaf(bf2f((unsigned short)(u.y & 0xffffu)), i0.z, s);
    s = fmaf(bf2f((unsigned short)(u.y >> 16)),     i0.w, s);
    s = fmaf(bf2f((unsigned short)(u.z & 0xffffu)), i1.x, s);
    s = fmaf(bf2f((unsigned short)(u.z >> 16)),     i1.y, s);
    s = fmaf(bf2f((unsigned short)(u.w & 0xffffu)), i1.z, s);
    s = fmaf(bf2f((unsigned short)(u.w >> 16)),     i1.w, s);
  }
  WRED(s)
  if (l == 0) ics1[b * NN + n] = rcpf_(1e-9f + s);
}

// P3W: reads a0 rows (16B/lane), stores ae[m][n]=bf16(exp(l0)) (16B/lane),
// sums ROUNDED values.  8 cols/lane wide layout, 2 rows/wave, 1024 blocks.
__global__ __launch_bounds__(256) void p3w_rs2(
    const float* __restrict__ xyz4, const float* __restrict__ xyzk,
    const float* __restrict__ irs1, const float* __restrict__ ics1,
    const float* __restrict__ thr, float* __restrict__ irs2,
    const unsigned short* __restrict__ a0g, unsigned short* __restrict__ aeg) {
  const int tid = threadIdx.x;
  const int b = blockIdx.x >> 9;
  const int m0 = (blockIdx.x & 511) << 3;
  const int w = tid >> 6, lane = tid & 63;
  const float* xk = xyzk + (size_t)b * 4 * NN;
  const unsigned short* ab = a0g + (size_t)b * NN * NN;
  unsigned short* eb = aeg + (size_t)b * NN * NN;
  const int mA = m0 + (w << 1), mB = mA + 1;
  const float4 pmA = *(const float4*)(xyz4 + ((size_t)b * NN + mA) * 4);
  const float4 pmB = *(const float4*)(xyz4 + ((size_t)b * NN + mB) * 4);
  const float rA = irs1[b * NN + mA];
  const float rB = irs1[b * NN + mB];
  float sA = 0.f, sB = 0.f;
#define P3E(S, OUT, A0W, SH, PM, R, PX, PY, PZ, PW, IC, TH) { \
    float a1v_ = bf2f((unsigned short)(((A0W) >> (SH)) & 0xffffu)) * (R) * (IC); \
    float dd_ = (PM).w + (PW) - 2.f * ((PM).x * (PX) + (PM).y * (PY) + (PM).z * (PZ)); \
    dd_ = fmaxf(dd_, 0.f); \
    float l0_ = (dd_ <= (TH)) ? a1v_ : 0.f; \
    const unsigned short us_ = f2bf(__expf(l0_)); OUT = us_; S += bf2f(us_); }
  for (int it = 0; it < 8; ++it) {
    const int n0 = (it << 9) + (lane << 3);
    const float4 pxl = *(const float4*)(xk + 0*NN + n0);
    const float4 pxh = *(const float4*)(xk + 0*NN + n0 + 4);
    const float4 pyl = *(const float4*)(xk + 1*NN + n0);
    const float4 pyh = *(const float4*)(xk + 1*NN + n0 + 4);
    const float4 pzl = *(const float4*)(xk + 2*NN + n0);
    const float4 pzh = *(const float4*)(xk + 2*NN + n0 + 4);
    const float4 pwl = *(const float4*)(xk + 3*NN + n0);
    const float4 pwh = *(const float4*)(xk + 3*NN + n0 + 4);
    const float4 icl = *(const float4*)(ics1 + b * NN + n0);
    const float4 ich = *(const float4*)(ics1 + b * NN + n0 + 4);
    const float4 thl = *(const float4*)(thr + b * NN + n0);
    const float4 thh = *(const float4*)(thr + b * NN + n0 + 4);
    const uint4 rAu = *(const uint4*)(ab + (size_t)mA * NN + n0);
    const uint4 rBu = *(const uint4*)(ab + (size_t)mB * NN + n0);
    unsigned short e0, e1, e2, e3, e4, e5, e6, e7;
    P3E(sA, e0, rAu.x, 0,  pmA, rA, pxl.x, pyl.x, pzl.x, pwl.x, icl.x, thl.x)
    P3E(sA, e1, rAu.x, 16, pmA, rA, pxl.y, pyl.y, pzl.y, pwl.y, icl.y, thl.y)
    P3E(sA, e2, rAu.y, 0,  pmA, rA, pxl.z, pyl.z, pzl.z, pwl.z, icl.z, thl.z)
    P3E(sA, e3, rAu.y, 16, pmA, rA, pxl.w, pyl.w, pzl.w, pwl.w, icl.w, thl.w)
    P3E(sA, e4, rAu.z, 0,  pmA, rA, pxh.x, pyh.x, pzh.x, pwh.x, ich.x, thh.x)
    P3E(sA, e5, rAu.z, 16, pmA, rA, pxh.y, pyh.y, pzh.y, pwh.y, ich.y, thh.y)
    P3E(sA, e6, rAu.w, 0,  pmA, rA, pxh.z, pyh.z, pzh.z, pwh.z, ich.z, thh.z)
    P3E(sA, e7, rAu.w, 16, pmA, rA, pxh.w, pyh.w, pzh.w, pwh.w, ich.w, thh.w)
    {
      uint4 U_;
      U_.x = (unsigned)e0 | ((unsigned)e1 << 16);
      U_.y = (unsigned)e2 | ((unsigned)e3 << 16);
      U_.z = (unsigned)e4 | ((unsigned)e5 << 16);
      U_.w = (unsigned)e6 | ((unsigned)e7 << 16);
      *(uint4*)(eb + (size_t)mA * NN + n0) = U_;
    }
    P3E(sB, e0, rBu.x, 0,  pmB, rB, pxl.x, pyl.x, pzl.x, pwl.x, icl.x, thl.x)
    P3E(sB, e1, rBu.x, 16, pmB, rB, pxl.y, pyl.y, pzl.y, pwl.y, icl.y, thl.y)
    P3E(sB, e2, rBu.y, 0,  pmB, rB, pxl.z, pyl.z, pzl.z, pwl.z, icl.z, thl.z)
    P3E(sB, e3, rBu.y, 16, pmB, rB, pxl.w, pyl.w, pzl.w, pwl.w, icl.w, thl.w)
    P3E(sB, e4, rBu.z, 0,  pmB, rB, pxh.x, pyh.x, pzh.x, pwh.x, ich.x, thh.x)
    P3E(sB, e5, rBu.z, 16, pmB, rB, pxh.y, pyh.y, pzh.y, pwh.y, ich.y, thh.y)
    P3E(sB, e6, rBu.w, 0,  pmB, rB, pxh.z, pyh.z, pzh.z, pwh.z, ich.z, thh.z)
    P3E(sB, e7, rBu.w, 16, pmB, rB, pxh.w, pyh.w, pzh.w, pwh.w, ich.w, thh.w)
    {
      uint4 U_;
      U_.x = (unsigned)e0 | ((unsigned)e1 << 16);
      U_.y = (unsigned)e2 | ((unsigned)e3 << 16);
      U_.z = (unsigned)e4 | ((unsigned)e5 << 16);
      U_.w = (unsigned)e6 | ((unsigned)e7 << 16);
      *(uint4*)(eb + (size_t)mB * NN + n0) = U_;
    }
  }
#undef P3E
  WRED(sA) WRED(sB)
  if (lane == 0) {
    irs2[b * NN + mA] = rcpf_(sA);
    irs2[b * NN + mB] = rcpf_(sB);
  }
}

// P4: cs2[n] = sum_m bf16(bf16(ae[m][n]) * irs2[m]) -- exact match of what
// k7n stages into the MFMA.  1024 blocks (64-row m strips).
__global__ __launch_bounds__(256) void p4_cs2(
    const unsigned short* __restrict__ aeg, const float* __restrict__ irs2,
    float* __restrict__ cs2) {
  const int tid = threadIdx.x;
  const int bid = blockIdx.x;              // B*8*64 = 1024 blocks
  const int ms = bid & 63;                 // m strip (64 rows)
  const int ng = (bid >> 6) & 7;           // n group (512 cols)
  const int b  = bid >> 9;
  const int n2 = (ng << 9) + (tid << 1);   // 2 columns per thread
  const unsigned short* eb = aeg + (size_t)b * NN * NN + n2;
  const float* r2 = irs2 + b * NN;
  float s0 = 0.f, s1 = 0.f;
  const int m0 = ms << 6;
#pragma unroll 4
  for (int m = m0; m < m0 + 64; ++m) {
    const unsigned u = *(const unsigned*)(eb + (size_t)m * NN);
    const float r = r2[m];
    s0 += bf2f(f2bf(bf2f((unsigned short)(u & 0xffffu)) * r));
    s1 += bf2f(f2bf(bf2f((unsigned short)(u >> 16)) * r));
  }
  atomicAdd(&cs2[b * NN + n2], s0);
  atomicAdd(&cs2[b * NN + n2 + 1], s1);
}

// LDS swizzle: spreads both the b32 transpose-writes (2-way, free) and the
// b128 reads (uniform) across banks.
#define SW(r) ((((r) & 7) << 4) ^ ((((r) >> 3) & 3) << 5))

// K7N: GMA with fused g1/g2 combine (needs cs2 from p4).
__global__ __launch_bounds__(256) void k7n_gma(
    const unsigned short* __restrict__ a0g, const unsigned short* __restrict__ aeg,
    const unsigned short* __restrict__ xvb,
    const float* __restrict__ irs1, const float* __restrict__ irs2,
    const float* __restrict__ ics1, const float* __restrict__ cs2,
    float* __restrict__ gma) {
  const int tid = threadIdx.x;
  const int bid = blockIdx.x;              // 512 blocks: B * 64 nb * 4 msl
  const int msl = bid & 3;
  const int nb  = (bid >> 2) & 63;
  const int b   = bid >> 8;
  const int n0 = nb << 6;
  const int mstart = msl << 10;            // 1024-row m strip -> 16 tiles
  __shared__ __align__(16) unsigned short attns1[2][64 * 64];
  __shared__ __align__(16) unsigned short attns2[2][64 * 64];
  __shared__ __align__(16) unsigned short xvs[2][64 * 64];
  const unsigned short* ab = a0g + (size_t)b * NN * NN;
  const unsigned short* ebp = aeg + (size_t)b * NN * NN;
  const float* irs1b = irs1 + b * NN;
  const float* irs2b = irs2 + b * NN;
  const int w = tid >> 6, l = tid & 63;
  const int lrow0 = (w << 4) + ((l >> 3) << 1);
  const int nc8 = (l & 7) << 3;
  const int gcol = n0 + nc8;
  const int xc = tid >> 2, xpart = tid & 3;
  const unsigned short* xvp = xvb + ((size_t)b * 64 + xc) * NN;
  const int lr = l & 15, quad = l >> 4;
  const int nw = w << 4;
  f32x4v acc0 = {0,0,0,0}, acc1 = {0,0,0,0}, acc2 = {0,0,0,0}, acc3 = {0,0,0,0};
  f32x4v d0 = {0,0,0,0}, d1 = {0,0,0,0}, d2 = {0,0,0,0}, d3 = {0,0,0,0};

  uint4 pa0A, pa1A, pe0A, pe1A, pv0A, pv1A;
  uint4 pa0B, pa1B, pe0B, pe1B, pv0B, pv1B;
  float r1aA, r1bA, r2aA, r2bA, r1aB, r1bB, r2aB, r2bB;

#define ISSUE(S, MT) { \
    const int m0_ = mstart + ((MT) << 6); \
    const size_t ra_ = (size_t)(m0_ + lrow0) * NN + gcol; \
    pa0##S = *(const uint4*)(ab + ra_); \
    pa1##S = *(const uint4*)(ab + ra_ + NN); \
    pe0##S = *(const uint4*)(ebp + ra_); \
    pe1##S = *(const uint4*)(ebp + ra_ + NN); \
    pv0##S = *(const uint4*)(xvp + m0_ + (xpart << 4)); \
    pv1##S = *(const uint4*)(xvp + m0_ + (xpart << 4) + 8); \
    r1a##S = irs1b[m0_ + lrow0]; r1b##S = irs1b[m0_ + lrow0 + 1]; \
    r2a##S = irs2b[m0_ + lrow0]; r2b##S = irs2b[m0_ + lrow0 + 1]; }

#define CVW(D0, D1, SH, J, R0, R1, ARR) { \
    const float v0_ = bf2f((unsigned short)(((D0) >> (SH)) & 0xffffu)) * (R0); \
    const float v1_ = bf2f((unsigned short)(((D1) >> (SH)) & 0xffffu)) * (R1); \
    const unsigned pk_ = (unsigned)f2bf(v0_) | ((unsigned)f2bf(v1_) << 16); \
    const int nl_ = nc8 + (J); \
    *(unsigned*)((char*)(ARR) + ((((nl_) << 7) + (lrow0 << 1)) ^ SW(nl_))) = pk_; }

#define WR8(U0, U1, R0, R1, ARR) \
    CVW(U0.x, U1.x, 0,  0, R0, R1, ARR) CVW(U0.x, U1.x, 16, 1, R0, R1, ARR) \
    CVW(U0.y, U1.y, 0,  2, R0, R1, ARR) CVW(U0.y, U1.y, 16, 3, R0, R1, ARR) \
    CVW(U0.z, U1.z, 0,  4, R0, R1, ARR) CVW(U0.z, U1.z, 16, 5, R0, R1, ARR) \
    CVW(U0.w, U1.w, 0,  6, R0, R1, ARR) CVW(U0.w, U1.w, 16, 7, R0, R1, ARR)

#define STX(XARR, PV0, PV1) { \
    const int xb_ = (xc << 7) + (xpart << 5); \
    *(uint4*)((char*)(XARR) + ((xb_) ^ SW(xc))) = PV0; \
    *(uint4*)((char*)(XARR) + ((xb_ + 16) ^ SW(xc))) = PV1; }

#define LDSW(ARR, ROW, H, Q) \
    (*(const bf16x8*)((const char*)(ARR) + \
      ((((ROW) << 7) + ((H) << 6) + ((Q) << 4)) ^ SW(ROW))))

#define MPH(A1P, A2P, XVP_) { \
    for (int h = 0; h < 2; ++h) { \
      const bf16x8 fa1 = LDSW(A1P, nw + lr, h, quad); \
      const bf16x8 fa2 = LDSW(A2P, nw + lr, h, quad); \
      const bf16x8 fb0 = LDSW(XVP_, lr, h, quad); \
      const bf16x8 fb1 = LDSW(XVP_, 16 + lr, h, quad); \
      const bf16x8 fb2 = LDSW(XVP_, 32 + lr, h, quad); \
      const bf16x8 fb3 = LDSW(XVP_, 48 + lr, h, quad); \
      acc0 = __builtin_amdgcn_mfma_f32_16x16x32_bf16(fa1, fb0, acc0, 0, 0, 0); \
      acc1 = __builtin_amdgcn_mfma_f32_16x16x32_bf16(fa1, fb1, acc1, 0, 0, 0); \
      acc2 = __builtin_amdgcn_mfma_f32_16x16x32_bf16(fa1, fb2, acc2, 0, 0, 0); \
      acc3 = __builtin_amdgcn_mfma_f32_16x16x32_bf16(fa1, fb3, acc3, 0, 0, 0); \
      d0 = __builtin_amdgcn_mfma_f32_16x16x32_bf16(fa2, fb0, d0, 0, 0, 0); \
      d1 = __builtin_amdgcn_mfma_f32_16x16x32_bf16(fa2, fb1, d1, 0, 0, 0); \
      d2 = __builtin_amdgcn_mfma_f32_16x16x32_bf16(fa2, fb2, d2, 0, 0, 0); \
      d3 = __builtin_amdgcn_mfma_f32_16x16x32_bf16(fa2, fb3, d3, 0, 0, 0); \
    } }

  ISSUE(A, 0)
  ISSUE(B, 1)
  for (int mt = 0; mt < 16; mt += 2) {
    WR8(pa0A, pa1A, r1aA, r1bA, attns1[0])
    WR8(pe0A, pe1A, r2aA, r2bA, attns2[0])
    STX(xvs[0], pv0A, pv1A)
    __syncthreads();
    if (mt + 2 < 16) { ISSUE(A, mt + 2) }
    MPH(attns1[0], attns2[0], xvs[0])
    WR8(pa0B, pa1B, r1aB, r1bB, attns1[1])
    WR8(pe0B, pe1B, r2aB, r2bB, attns2[1])
    STX(xvs[1], pv0B, pv1B)
    __syncthreads();
    if (mt + 3 < 16) { ISSUE(B, mt + 3) }
    MPH(attns1[1], attns2[1], xvs[1])
  }
#undef ISSUE
#undef CVW
#undef WR8
#undef STX
#undef LDSW
#undef MPH
  float w10, w11, w12, w13, w20, w21, w22, w23;
  {
    const int nr = n0 + nw + (quad << 2);
    w10 = ics1[b * NN + nr + 0]; w20 = rcpf_(1e-9f + cs2[b * NN + nr + 0]);
    w11 = ics1[b * NN + nr + 1]; w21 = rcpf_(1e-9f + cs2[b * NN + nr + 1]);
    w12 = ics1[b * NN + nr + 2]; w22 = rcpf_(1e-9f + cs2[b * NN + nr + 2]);
    w13 = ics1[b * NN + nr + 3]; w23 = rcpf_(1e-9f + cs2[b * NN + nr + 3]);
  }
#define EPI(ACC, DD, CT) { \
    float* g_ = gma + ((size_t)b * NN + n0 + nw + (quad << 2)) * 64 + (CT) * 16 + lr; \
    atomicAdd(g_ + 0,   fmaf(ACC[0], w10, DD[0] * w20)); \
    atomicAdd(g_ + 64,  fmaf(ACC[1], w11, DD[1] * w21)); \
    atomicAdd(g_ + 128, fmaf(ACC[2], w12, DD[2] * w22)); \
    atomicAdd(g_ + 192, fmaf(ACC[3], w13, DD[3] * w23)); }
  EPI(acc0, d0, 0) EPI(acc1, d1, 1) EPI(acc2, d2, 2) EPI(acc3, d3, 3)
#undef EPI
}

// ===================== common p2 / k8 / k9 =====================

__global__ __launch_bounds__(256) void p2_cs1(
    const float* __restrict__ qt, const float* __restrict__ qk,
    const float* __restrict__ irs1, float* __restrict__ ics1) {
  const int tid = threadIdx.x;
  const int b = blockIdx.x >> 8;
  const int n0t = (blockIdx.x & 255) << 4;
  const int w = tid >> 6, lane = tid & 63;
  const float* qb = qt + (size_t)b * NN * 16;
  const float* kb = qk + (size_t)b * 16 * NN;
  const int nA = n0t + w, nB = n0t + w + 4, nC = n0t + w + 8, nD = n0t + w + 12;
  LQROW(na, qb + (size_t)nA * 16)
  LQROW(nb, qb + (size_t)nB * 16)
  LQROW(nc, qb + (size_t)nC * 16)
  LQROW(nd, qb + (size_t)nD * 16)
  float sA = 0.f, sB = 0.f, sC = 0.f, sD = 0.f;
  for (int it = 0; it < 16; ++it) {
    const int m0 = (it << 8) + (lane << 2);
    LKPL(kb, m0)
    const float4 r1 = *(const float4*)(irs1 + b * NN + m0);
    sA = fmaf(__expf(fminf(DOTC(na0,na1,na2,na3,x), 80.f)), r1.x, sA);
    sA = fmaf(__expf(fminf(DOTC(na0,na1,na2,na3,y), 80.f)), r1.y, sA);
    sA = fmaf(__expf(fminf(DOTC(na0,na1,na2,na3,z), 80.f)), r1.z, sA);
    sA = fmaf(__expf(fminf(DOTC(na0,na1,na2,na3,w), 80.f)), r1.w, sA);
    sB = fmaf(__expf(fminf(DOTC(nb0,nb1,nb2,nb3,x), 80.f)), r1.x, sB);
    sB = fmaf(__expf(fminf(DOTC(nb0,nb1,nb2,nb3,y), 80.f)), r1.y, sB);
    sB = fmaf(__expf(fminf(DOTC(nb0,nb1,nb2,nb3,z), 80.f)), r1.z, sB);
    sB = fmaf(__expf(fminf(DOTC(nb0,nb1,nb2,nb3,w), 80.f)), r1.w, sB);
    sC = fmaf(__expf(fminf(DOTC(nc0,nc1,nc2,nc3,x), 80.f)), r1.x, sC);
    sC = fmaf(__expf(fminf(DOTC(nc0,nc1,nc2,nc3,y), 80.f)), r1.y, sC);
    sC = fmaf(__expf(fminf(DOTC(nc0,nc1,nc2,nc3,z), 80.f)), r1.z, sC);
    sC = fmaf(__expf(fminf(DOTC(nc0,nc1,nc2,nc3,w), 80.f)), r1.w, sC);
    sD = fmaf(__expf(fminf(DOTC(nd0,nd1,nd2,nd3,x), 80.f)), r1.x, sD);
    sD = fmaf(__expf(fminf(DOTC(nd0,nd1,nd2,nd3,y), 80.f)), r1.y, sD);
    sD = fmaf(__expf(fminf(DOTC(nd0,nd1,nd2,nd3,z), 80.f)), r1.z, sD);
    sD = fmaf(__expf(fminf(DOTC(nd0,nd1,nd2,nd3,w), 80.f)), r1.w, sD);
  }
  WRED(sA) WRED(sB) WRED(sC) WRED(sD)
  if (lane == 0) {
    ics1[b * NN + nA] = rcpf_(1e-9f + sA);
    ics1[b * NN + nB] = rcpf_(1e-9f + sB);
    ics1[b * NN + nC] = rcpf_(1e-9f + sC);
    ics1[b * NN + nD] = rcpf_(1e-9f + sD);
  }
}

// mode 0: gma = g1 + g2*ics2 (fallback);  mode 2: gma already combined in g1.
__global__ __launch_bounds__(256) void k8_res(
    const void* __restrict__ mot, const void* __restrict__ wt,
    const void* __restrict__ bt, const float* __restrict__ flag,
    float* __restrict__ g1_res, const float* __restrict__ g2,
    const float* __restrict__ cs2, float* __restrict__ gn,
    const float* __restrict__ ics1, int g1mode) {
  const bool f32 = flag[0] > 0.5f;
  const int tid = threadIdx.x;
  const int bid = blockIdx.x;
  const int b = bid >> 9;
  const int n0 = (bid & 511) << 3;
  __shared__ float wtT[64 * 65];
  __shared__ float bts[64];
  __shared__ float md[8 * 64];
  __shared__ float gs[8], gss[8];
  for (int i = tid; i < 4096; i += 256) {
    int o = i & 63, c = i >> 6;
    wtT[c * 65 + o] = ldin(wt, o * 64 + c, f32);
  }
  if (tid < 64) bts[tid] = ldin(bt, tid, f32);
  if (tid < 8) { gs[tid] = 0.f; gss[tid] = 0.f; }
#pragma unroll
  for (int r = 0; r < 2; ++r) {
    const int idx = tid * 2 + r;
    const int c = idx & 63, nl = idx >> 6;
    const size_t gi = ((size_t)b * NN + n0 + nl) * 64 + c;
    float gmav;
    if (g1mode == 2) {
      gmav = g1_res[gi];
    } else {
      const float ics2n = rcpf_(1e-9f + cs2[b * NN + n0 + nl]);
      float g1v = g1_res[gi];
      if (g1mode == 1) g1v *= ics1[b * NN + n0 + nl];
      gmav = fmaf(g2[gi], ics2n, g1v);
    }
    md[nl * 64 + c] = ldin(mot, ((size_t)b * 64 + c) * NN + n0 + nl, f32) - gmav;
  }
  __syncthreads();
  const int o = tid & 63, ng = tid >> 6;
  const int nl0 = ng * 2, nl1 = ng * 2 + 1;
  float a0 = bts[o], a1 = bts[o];
#pragma unroll 8
  for (int c = 0; c < 64; ++c) {
    float w = wtT[c * 65 + o];
    a0 = fmaf(w, md[nl0 * 64 + c], a0);
    a1 = fmaf(w, md[nl1 * 64 + c], a1);
  }
  g1_res[((size_t)b * NN + n0 + nl0) * 64 + o] = a0;
  g1_res[((size_t)b * NN + n0 + nl1) * 64 + o] = a1;
  atomicAdd(&gs[o >> 3], a0 + a1);
  atomicAdd(&gss[o >> 3], a0 * a0 + a1 * a1);
  __syncthreads();
  if (tid < 8) atomicAdd(&gn[b * 8 + tid], gs[tid]);
  else if (tid < 16) atomicAdd(&gn[16 + b * 8 + (tid - 8)], gss[tid - 8]);
}

__global__ __launch_bounds__(256) void k9_out(
    const float* __restrict__ res, const float* __restrict__ gn,
    const void* __restrict__ mot,
    const void* __restrict__ gnw, const void* __restrict__ gnb,
    const void* __restrict__ pa, const void* __restrict__ al,
    const float* __restrict__ flag, void* __restrict__ out) {
  const bool f32 = flag[0] > 0.5f;
  const int idx = blockIdx.x * 256 + threadIdx.x;
  const int n = idx & 4095;
  const int c = (idx >> 12) & 63;
  const int b = idx >> 18;
  const int g = c >> 3;
  const float inv_cnt = 1.f / 32768.f;
  float mean = gn[b * 8 + g] * inv_cnt;
  float var = gn[16 + b * 8 + g] * inv_cnt - mean * mean;
  var = fmaxf(var, 0.f);
  float rstd = rsqrtf(var + 1e-5f);
  float r = res[((size_t)b * NN + n) * 64 + c];
  float y = (r - mean) * rstd * ldin(gnw, c, f32) + ldin(gnb, c, f32);
  float slope = ldin(pa, 0, f32);
  y = (y >= 0.f) ? y : slope * y;
  float o = ldin(al, 0, f32) * y + ldin(mot, idx, f32);
  if (f32) ((float*)out)[idx] = o;
  else     ((__hip_bfloat16*)out)[idx] = __float2bfloat16(o);
}

extern "C" void kernel_launch(void* const* d_in, const int* in_sizes, int n_in,
                              void* d_out, int out_size, void* d_ws, size_t ws_size,
                              hipStream_t stream) {
  const void* ctx = d_in[0];
  const void* mot = d_in[1];
  const void* xyz = d_in[2];
  const void* wqk = d_in[3];
  const void* wv  = d_in[4];
  const void* bv  = d_in[5];
  const void* wt  = d_in[6];
  const void* bt  = d_in[7];
  const void* gnw = d_in[8];
  const void* gnb = d_in[9];
  const void* pa  = d_in[10];
  const void* al  = d_in[11];
  float* ws = (float*)d_ws;
  const bool big = ws_size >= (size_t)FULL_F * sizeof(float);

  if (ws_size < (size_t)WS_TOTAL * sizeof(float))
    fprintf(stderr, "[gma3d] WARNING ws_size=%zu < needed %zu\n",
            ws_size, (size_t)WS_TOTAL * sizeof(float));

  hipMemsetAsync(ws + OFF_SUMS, 0, (size_t)ZERO_F * sizeof(float), stream);

  k0_detect<<<1, 256, 0, stream>>>((const unsigned short*)ctx, ws + OFF_FLAG);
  k1_q_xyz<<<32, 256, 0, stream>>>(ctx, xyz, wqk, ws + OFF_FLAG,
                                   ws + OFF_QT, ws + OFF_QK,
                                   ws + OFF_XYZ4, ws + OFF_XYZK, ws + OFF_SUMS,
                                   big ? (unsigned short*)(ws + OFF_QBH) : (unsigned short*)nullptr,
                                   big ? (unsigned short*)(ws + OFF_QBL) : (unsigned short*)nullptr);
  k2_xv<<<128, 256, 0, stream>>>(mot, wv, bv, ws + OFF_FLAG,
                                 (unsigned short*)(ws + OFF_XVB));
  k2b_thr<<<32, 256, 0, stream>>>(ws + OFF_XYZ4, ws + OFF_SUMS, ws + OFF_THR);

  if (big) {
    unsigned short* a0 = (unsigned short*)(ws + OFF_A0);
    unsigned short* ae = (unsigned short*)(ws + OFF_AE);
    p1m_corr<<<8192, 256, 0, stream>>>((const unsigned short*)(ws + OFF_QBH),
                                       (const unsigned short*)(ws + OFF_QBL),
                                       ws + OFF_RS1R, a0);
    k_inv<<<32, 256, 0, stream>>>(ws + OFF_RS1R, ws + OFF_IRS1);
    p2r_cs1<<<2048, 256, 0, stream>>>(a0, ws + OFF_IRS1, ws + OFF_ICS1);
    p3w_rs2<<<1024, 256, 0, stream>>>(ws + OFF_XYZ4, ws + OFF_XYZK,
                                      ws + OFF_IRS1, ws + OFF_ICS1, ws + OFF_THR,
                                      ws + OFF_IRS2, a0, ae);
    p4_cs2<<<1024, 256, 0, stream>>>(ae, ws + OFF_IRS2, ws + OFF_CS2);
    k7n_gma<<<512, 256, 0, stream>>>(a0, ae,
                                     (const unsigned short*)(ws + OFF_XVB),
                                     ws + OFF_IRS1, ws + OFF_IRS2,
                                     ws + OFF_ICS1, ws + OFF_CS2,
                                     ws + OFF_GMA);
    k8_res<<<1024, 256, 0, stream>>>(mot, wt, bt, ws + OFF_FLAG,
                                     ws + OFF_GMA, ws + OFF_G2, ws + OFF_CS2,
                                     ws + OFF_GN, ws + OFF_ICS1, 2);
  } else {
    p1_rs1<<<512, 256, 0, stream>>>(ws + OFF_QT, ws + OFF_QK, ws + OFF_IRS1);
    p2_cs1<<<512, 256, 0, stream>>>(ws + OFF_QT, ws + OFF_QK, ws + OFF_IRS1, ws + OFF_ICS1);
    p3_rs2<<<512, 256, 0, stream>>>(ws + OFF_QT, ws + OFF_QK,
                                    ws + OFF_XYZ4, ws + OFF_XYZK,
                                    ws + OFF_IRS1, ws + OFF_ICS1, ws + OFF_THR,
                                    ws + OFF_IRS2);
    k7_gma<<<1024, 256, 0, stream>>>(ws + OFF_QT, ws + OFF_XYZ4,
                                     (const unsigned short*)(ws + OFF_XVB),
                                     ws + OFF_IRS1, ws + OFF_IRS2,
                                     ws + OFF_ICS1, ws + OFF_THR,
                                     ws + OFF_GMA, ws + OFF_G2, ws + OFF_CS2);
    k8_res<<<1024, 256, 0, stream>>>(mot, wt, bt, ws + OFF_FLAG,
                                     ws + OFF_GMA, ws + OFF_G2, ws + OFF_CS2,
                                     ws + OFF_GN, ws + OFF_ICS1, 0);
  }

  k9_out<<<2048, 256, 0, stream>>>(ws + OFF_GMA, ws + OFF_GN, mot, gnw, gnb, pa, al,
                                   ws + OFF_FLAG, d_out);
}

// Round 8
// 264.632 us; speedup vs baseline: 1.1316x; 1.0167x over previous
//
#include <hip/hip_runtime.h>
#include <hip/hip_bf16.h>
#include <cstdio>

#define NB 2
#define NN 4096
#define NC 64
#define NQ 16
#define POS_COEF 0.1f

// ---- workspace layout (float offsets) ----
#define OFF_QT   0u            // [B][N][16] row-major q
#define OFF_QK   131072u       // [B][16][N] planar k-major q (coalesced stream)
#define OFF_XYZ4 262144u       // [B][N][4]  row-major xyz+sq
#define OFF_XYZK 294912u       // [B][4][N]  planar xyz+sq
#define OFF_IRS1 327680u       // [B][N]
#define OFF_IRS2 335872u       // [B][N]
#define OFF_THR  344064u       // [B][N]
#define OFF_ICS1 352256u       // [B][N]  1/(1e-9+cs1)
#define OFF_FLAG 360448u       // [16]
#define OFF_XVB  360464u       // [B][64][N] bf16 (262144 floats)
// --- zeroed region below ---
#define OFF_SUMS 622608u       // [B][4]
#define OFF_GN   622616u       // [2][B][8]
#define OFF_CS2  622648u       // [B][N] colsum of local
#define OFF_GMA  630840u       // [B][N][64]  G1/combined gma -> res in k8
#define OFF_G2   1155128u      // [B][N][64]  G2 (fallback path only; big path
                               // reuses it: qbf hi/lo + raw row sums)
#define OFF_QBH  OFF_G2            // [B][N][16] bf16 hi of q (65536 floats)
#define OFF_QBL  (OFF_G2 + 65536u) // [B][N][16] bf16 lo of q (65536 floats)
#define OFF_RS1R (OFF_G2 + 131072u) // [B][N] f32 raw rs1 sums (zeroed)
#define WS_TOTAL 1679416u
#define ZERO_F   (WS_TOTAL - OFF_SUMS)
// --- optional materialized exp matrices (bf16), used iff ws_size permits ---
#define OFF_A0   1679424u      // [B][N][N] bf16 exp(corr)     (16777216 floats)
#define OFF_AE   18456640u     // [B][N][N] bf16 exp(l0)       (16777216 floats)
#define FULL_F   35233856u

using bf16x8 = __attribute__((ext_vector_type(8))) short;
using f32x4v = __attribute__((ext_vector_type(4))) float;

__device__ __forceinline__ float rcpf_(float x) { return __builtin_amdgcn_rcpf(x); }
__device__ __forceinline__ unsigned short f2bf(float x) {
  __hip_bfloat16 h = __float2bfloat16(x);
  return *(unsigned short*)&h;
}
__device__ __forceinline__ float bf2f(unsigned short u) {
  unsigned v = ((unsigned)u) << 16;
  return __builtin_bit_cast(float, v);
}

__device__ __forceinline__ float ldin(const void* p, size_t i, bool f32) {
  return f32 ? ((const float*)p)[i]
             : __bfloat162float(((const __hip_bfloat16*)p)[i]);
}

// 16-term fma tree, named float4 row against named float4 row
#define DOT16M(A0,A1,A2,A3,B0,B1,B2,B3) \
  fmaf((A0).x,(B0).x, fmaf((A0).y,(B0).y, fmaf((A0).z,(B0).z, fmaf((A0).w,(B0).w, \
  fmaf((A1).x,(B1).x, fmaf((A1).y,(B1).y, fmaf((A1).z,(B1).z, fmaf((A1).w,(B1).w, \
  fmaf((A2).x,(B2).x, fmaf((A2).y,(B2).y, fmaf((A2).z,(B2).z, fmaf((A2).w,(B2).w, \
  fmaf((A3).x,(B3).x, fmaf((A3).y,(B3).y, fmaf((A3).z,(B3).z, (A3).w*(B3).w)))))))))))))))

// dot of named row (M0..M3) against column C of k-planes k0..k15
#define DOTC(M0,M1,M2,M3,C) \
  fmaf((M0).x,k0.C, fmaf((M0).y,k1.C, fmaf((M0).z,k2.C, fmaf((M0).w,k3.C, \
  fmaf((M1).x,k4.C, fmaf((M1).y,k5.C, fmaf((M1).z,k6.C, fmaf((M1).w,k7.C, \
  fmaf((M2).x,k8.C, fmaf((M2).y,k9.C, fmaf((M2).z,k10.C, fmaf((M2).w,k11.C, \
  fmaf((M3).x,k12.C, fmaf((M3).y,k13.C, fmaf((M3).z,k14.C, (M3).w*k15.C)))))))))))))))

// planar k-plane loads: lanes read consecutive float4 -> fully coalesced
#define LKPL(base, n0) \
  const float4 k0  = *(const float4*)((base) + 0*NN  + (n0)); \
  const float4 k1  = *(const float4*)((base) + 1*NN  + (n0)); \
  const float4 k2  = *(const float4*)((base) + 2*NN  + (n0)); \
  const float4 k3  = *(const float4*)((base) + 3*NN  + (n0)); \
  const float4 k4  = *(const float4*)((base) + 4*NN  + (n0)); \
  const float4 k5  = *(const float4*)((base) + 5*NN  + (n0)); \
  const float4 k6  = *(const float4*)((base) + 6*NN  + (n0)); \
  const float4 k7  = *(const float4*)((base) + 7*NN  + (n0)); \
  const float4 k8  = *(const float4*)((base) + 8*NN  + (n0)); \
  const float4 k9  = *(const float4*)((base) + 9*NN  + (n0)); \
  const float4 k10 = *(const float4*)((base) + 10*NN + (n0)); \
  const float4 k11 = *(const float4*)((base) + 11*NN + (n0)); \
  const float4 k12 = *(const float4*)((base) + 12*NN + (n0)); \
  const float4 k13 = *(const float4*)((base) + 13*NN + (n0)); \
  const float4 k14 = *(const float4*)((base) + 14*NN + (n0)); \
  const float4 k15 = *(const float4*)((base) + 15*NN + (n0));

#define WRED(s) { s += __shfl_xor(s, 32); s += __shfl_xor(s, 16); \
  s += __shfl_xor(s, 8); s += __shfl_xor(s, 4); s += __shfl_xor(s, 2); s += __shfl_xor(s, 1); }

#define LQROW(v, base) \
  const float4 v##0 = *(const float4*)((base)); \
  const float4 v##1 = *(const float4*)((base) + 4); \
  const float4 v##2 = *(const float4*)((base) + 8); \
  const float4 v##3 = *(const float4*)((base) + 12);

// K0: detect input dtype
__global__ __launch_bounds__(256) void k0_detect(
    const unsigned short* __restrict__ ctx_u16, float* __restrict__ flag) {
  const int tid = threadIdx.x;
  int bad = 0;
  for (int i = tid; i < 8192; i += 256) {
    const unsigned short u = ctx_u16[i];
    const int e = (u >> 7) & 0xFF;
    if (e >= 134 || (e >= 1 && e <= 100)) bad++;
  }
  __shared__ int cnt;
  if (tid == 0) cnt = 0;
  __syncthreads();
  atomicAdd(&cnt, bad);
  __syncthreads();
  if (tid == 0) flag[0] = (cnt > 256) ? 1.0f : 0.0f;
}

// K1: q = Wqk @ ctx (row-major + planar + bf16 hi/lo split for MFMA),
// xyz (row + planar), batch sums
__global__ __launch_bounds__(256) void k1_q_xyz(
    const void* __restrict__ ctx, const void* __restrict__ xyz,
    const void* __restrict__ wqk, const float* __restrict__ flag,
    float* __restrict__ qt, float* __restrict__ qk,
    float* __restrict__ xyz4, float* __restrict__ xyzk,
    float* __restrict__ sums,
    unsigned short* __restrict__ qbh, unsigned short* __restrict__ qbl) {
  const bool f32 = flag[0] > 0.5f;
  const int tid = threadIdx.x;
  const int b = blockIdx.x >> 4;
  const int n = ((blockIdx.x & 15) << 8) + tid;
  __shared__ float wqT[NQ * NC];  // [c][o]
  for (int i = tid; i < NQ * NC; i += 256) {
    int o = i & 15, c = i >> 4;
    wqT[c * 16 + o] = ldin(wqk, o * 64 + c, f32);
  }
  __syncthreads();
  float4 a0 = {0,0,0,0}, a1 = {0,0,0,0}, a2 = {0,0,0,0}, a3 = {0,0,0,0};
  const size_t cbase = (size_t)b * 64 * NN + n;
#pragma unroll 4
  for (int c = 0; c < 64; ++c) {
    float x = ldin(ctx, cbase + (size_t)c * NN, f32);
    const float4 w0 = *(const float4*)(wqT + c * 16 + 0);
    const float4 w1 = *(const float4*)(wqT + c * 16 + 4);
    const float4 w2 = *(const float4*)(wqT + c * 16 + 8);
    const float4 w3 = *(const float4*)(wqT + c * 16 + 12);
    a0.x = fmaf(w0.x, x, a0.x); a0.y = fmaf(w0.y, x, a0.y); a0.z = fmaf(w0.z, x, a0.z); a0.w = fmaf(w0.w, x, a0.w);
    a1.x = fmaf(w1.x, x, a1.x); a1.y = fmaf(w1.y, x, a1.y); a1.z = fmaf(w1.z, x, a1.z); a1.w = fmaf(w1.w, x, a1.w);
    a2.x = fmaf(w2.x, x, a2.x); a2.y = fmaf(w2.y, x, a2.y); a2.z = fmaf(w2.z, x, a2.z); a2.w = fmaf(w2.w, x, a2.w);
    a3.x = fmaf(w3.x, x, a3.x); a3.y = fmaf(w3.y, x, a3.y); a3.z = fmaf(w3.z, x, a3.z); a3.w = fmaf(w3.w, x, a3.w);
  }
  float* qp = qt + (size_t)(b * NN + n) * 16;
  *(float4*)(qp + 0) = a0; *(float4*)(qp + 4) = a1;
  *(float4*)(qp + 8) = a2; *(float4*)(qp + 12) = a3;
  float* kq = qk + (size_t)b * 16 * NN + n;
  kq[0*NN]=a0.x;  kq[1*NN]=a0.y;  kq[2*NN]=a0.z;  kq[3*NN]=a0.w;
  kq[4*NN]=a1.x;  kq[5*NN]=a1.y;  kq[6*NN]=a1.z;  kq[7*NN]=a1.w;
  kq[8*NN]=a2.x;  kq[9*NN]=a2.y;  kq[10*NN]=a2.z; kq[11*NN]=a2.w;
  kq[12*NN]=a3.x; kq[13*NN]=a3.y; kq[14*NN]=a3.z; kq[15*NN]=a3.w;
  if (qbh) {
    const float v0=a0.x, v1=a0.y, v2=a0.z, v3=a0.w;
    const float v4=a1.x, v5=a1.y, v6=a1.z, v7=a1.w;
    const float v8=a2.x, v9=a2.y, v10=a2.z, v11=a2.w;
    const float v12=a3.x, v13=a3.y, v14=a3.z, v15=a3.w;
#define HL(I, V) \
    const unsigned short h##I = f2bf(V); \
    const unsigned short l##I = f2bf((V) - bf2f(h##I));
    HL(0,v0) HL(1,v1) HL(2,v2) HL(3,v3) HL(4,v4) HL(5,v5) HL(6,v6) HL(7,v7)
    HL(8,v8) HL(9,v9) HL(10,v10) HL(11,v11) HL(12,v12) HL(13,v13) HL(14,v14) HL(15,v15)
#undef HL
#define PK(A,B) ((unsigned)(A) | ((unsigned)(B) << 16))
    uint4 H0, H1, L0, L1;
    H0.x = PK(h0,h1);   H0.y = PK(h2,h3);   H0.z = PK(h4,h5);   H0.w = PK(h6,h7);
    H1.x = PK(h8,h9);   H1.y = PK(h10,h11); H1.z = PK(h12,h13); H1.w = PK(h14,h15);
    L0.x = PK(l0,l1);   L0.y = PK(l2,l3);   L0.z = PK(l4,l5);   L0.w = PK(l6,l7);
    L1.x = PK(l8,l9);   L1.y = PK(l10,l11); L1.z = PK(l12,l13); L1.w = PK(l14,l15);
#undef PK
    unsigned short* qhp = qbh + (size_t)(b * NN + n) * 16;
    unsigned short* qlp = qbl + (size_t)(b * NN + n) * 16;
    *(uint4*)(qhp) = H0; *(uint4*)(qhp + 8) = H1;
    *(uint4*)(qlp) = L0; *(uint4*)(qlp + 8) = L1;
  }
  float xx = ldin(xyz, (size_t)(b * NN + n) * 3 + 0, f32);
  float yy = ldin(xyz, (size_t)(b * NN + n) * 3 + 1, f32);
  float zz = ldin(xyz, (size_t)(b * NN + n) * 3 + 2, f32);
  float4 p; p.x = xx; p.y = yy; p.z = zz; p.w = fmaf(xx, xx, fmaf(yy, yy, zz * zz));
  *(float4*)(xyz4 + (size_t)(b * NN + n) * 4) = p;
  float* kx = xyzk + (size_t)b * 4 * NN + n;
  kx[0*NN]=p.x; kx[1*NN]=p.y; kx[2*NN]=p.z; kx[3*NN]=p.w;
  float sx = p.x, sy = p.y, sz = p.z, sw = p.w;
  WRED(sx) WRED(sy) WRED(sz) WRED(sw)
  if ((tid & 63) == 0) {
    atomicAdd(&sums[b * 4 + 0], sx);
    atomicAdd(&sums[b * 4 + 1], sy);
    atomicAdd(&sums[b * 4 + 2], sz);
    atomicAdd(&sums[b * 4 + 3], sw);
  }
}

// K2: xv = Wv @ motion + bv, bf16 channel-major [b][c][n]
__global__ __launch_bounds__(256) void k2_xv(
    const void* __restrict__ mot, const void* __restrict__ wv,
    const void* __restrict__ bv, const float* __restrict__ flag,
    unsigned short* __restrict__ xvb) {
  const bool f32 = flag[0] > 0.5f;
  const int tid = threadIdx.x;
  const int b = blockIdx.x >> 6;
  const int n = ((blockIdx.x & 63) << 6) + (tid >> 2);
  const int og = tid & 3;
  __shared__ float wvT[NC * NC];
  __shared__ float bvs[NC];
  for (int i = tid; i < NC * NC; i += 256) {
    int o = i & 63, c = i >> 6;
    wvT[c * 64 + o] = ldin(wv, o * 64 + c, f32);
  }
  if (tid < 64) bvs[tid] = ldin(bv, tid, f32);
  __syncthreads();
  float4 a0 = *(const float4*)(bvs + og * 16 + 0);
  float4 a1 = *(const float4*)(bvs + og * 16 + 4);
  float4 a2 = *(const float4*)(bvs + og * 16 + 8);
  float4 a3 = *(const float4*)(bvs + og * 16 + 12);
  const size_t mbase = (size_t)b * 64 * NN + n;
#pragma unroll 4
  for (int c = 0; c < 64; ++c) {
    float x = ldin(mot, mbase + (size_t)c * NN, f32);
    const float4 w0 = *(const float4*)(wvT + c * 64 + og * 16 + 0);
    const float4 w1 = *(const float4*)(wvT + c * 64 + og * 16 + 4);
    const float4 w2 = *(const float4*)(wvT + c * 64 + og * 16 + 8);
    const float4 w3 = *(const float4*)(wvT + c * 64 + og * 16 + 12);
    a0.x = fmaf(w0.x, x, a0.x); a0.y = fmaf(w0.y, x, a0.y); a0.z = fmaf(w0.z, x, a0.z); a0.w = fmaf(w0.w, x, a0.w);
    a1.x = fmaf(w1.x, x, a1.x); a1.y = fmaf(w1.y, x, a1.y); a1.z = fmaf(w1.z, x, a1.z); a1.w = fmaf(w1.w, x, a1.w);
    a2.x = fmaf(w2.x, x, a2.x); a2.y = fmaf(w2.y, x, a2.y); a2.z = fmaf(w2.z, x, a2.z); a2.w = fmaf(w2.w, x, a2.w);
    a3.x = fmaf(w3.x, x, a3.x); a3.y = fmaf(w3.y, x, a3.y); a3.z = fmaf(w3.z, x, a3.z); a3.w = fmaf(w3.w, x, a3.w);
  }
  unsigned short* xb = xvb + (size_t)b * 64 * NN + n;
  const int o0 = og * 16;
  xb[(size_t)(o0 + 0) * NN] = f2bf(a0.x);  xb[(size_t)(o0 + 1) * NN] = f2bf(a0.y);
  xb[(size_t)(o0 + 2) * NN] = f2bf(a0.z);  xb[(size_t)(o0 + 3) * NN] = f2bf(a0.w);
  xb[(size_t)(o0 + 4) * NN] = f2bf(a1.x);  xb[(size_t)(o0 + 5) * NN] = f2bf(a1.y);
  xb[(size_t)(o0 + 6) * NN] = f2bf(a1.z);  xb[(size_t)(o0 + 7) * NN] = f2bf(a1.w);
  xb[(size_t)(o0 + 8) * NN] = f2bf(a2.x);  xb[(size_t)(o0 + 9) * NN] = f2bf(a2.y);
  xb[(size_t)(o0 +10) * NN] = f2bf(a2.z);  xb[(size_t)(o0 +11) * NN] = f2bf(a2.w);
  xb[(size_t)(o0 +12) * NN] = f2bf(a3.x);  xb[(size_t)(o0 +13) * NN] = f2bf(a3.y);
  xb[(size_t)(o0 +14) * NN] = f2bf(a3.z);  xb[(size_t)(o0 +15) * NN] = f2bf(a3.w);
}

// K2b: thr[n] = 0.1*(1e-9 + csd[n]) analytic
__global__ __launch_bounds__(256) void k2b_thr(
    const float* __restrict__ xyz4, const float* __restrict__ sums,
    float* __restrict__ thr) {
  const int idx = blockIdx.x * 256 + threadIdx.x;
  const int b = idx >> 12;
  const float4 pn = *(const float4*)(xyz4 + (size_t)idx * 4);
  const float Px = sums[b * 4 + 0], Py = sums[b * 4 + 1];
  const float Pz = sums[b * 4 + 2], S1 = sums[b * 4 + 3];
  float csd = fmaf((float)NN, pn.w, S1)
            - 2.f * (pn.x * Px + pn.y * Py + pn.z * Pz);
  thr[idx] = POS_COEF * (1e-9f + csd);
}

// ===================== fallback (round-13) p1/p3/k7 =====================

__global__ __launch_bounds__(256) void p1_rs1(
    const float* __restrict__ qt, const float* __restrict__ qk,
    float* __restrict__ irs1) {
  const int tid = threadIdx.x;
  const int b = blockIdx.x >> 8;
  const int m0 = (blockIdx.x & 255) << 4;
  const int w = tid >> 6, lane = tid & 63;
  const float* qb = qt + (size_t)b * NN * 16;
  const float* kb = qk + (size_t)b * 16 * NN;
  const int mA = m0 + w, mB = m0 + w + 4, mC = m0 + w + 8, mD = m0 + w + 12;
  LQROW(ma, qb + (size_t)mA * 16)
  LQROW(mb, qb + (size_t)mB * 16)
  LQROW(mc, qb + (size_t)mC * 16)
  LQROW(md, qb + (size_t)mD * 16)
  float sA = 0.f, sB = 0.f, sC = 0.f, sD = 0.f;
  for (int it = 0; it < 16; ++it) {
    const int n0 = (it << 8) + (lane << 2);
    LKPL(kb, n0)
    sA += __expf(fminf(DOTC(ma0,ma1,ma2,ma3,x), 80.f));
    sA += __expf(fminf(DOTC(ma0,ma1,ma2,ma3,y), 80.f));
    sA += __expf(fminf(DOTC(ma0,ma1,ma2,ma3,z), 80.f));
    sA += __expf(fminf(DOTC(ma0,ma1,ma2,ma3,w), 80.f));
    sB += __expf(fminf(DOTC(mb0,mb1,mb2,mb3,x), 80.f));
    sB += __expf(fminf(DOTC(mb0,mb1,mb2,mb3,y), 80.f));
    sB += __expf(fminf(DOTC(mb0,mb1,mb2,mb3,z), 80.f));
    sB += __expf(fminf(DOTC(mb0,mb1,mb2,mb3,w), 80.f));
    sC += __expf(fminf(DOTC(mc0,mc1,mc2,mc3,x), 80.f));
    sC += __expf(fminf(DOTC(mc0,mc1,mc2,mc3,y), 80.f));
    sC += __expf(fminf(DOTC(mc0,mc1,mc2,mc3,z), 80.f));
    sC += __expf(fminf(DOTC(mc0,mc1,mc2,mc3,w), 80.f));
    sD += __expf(fminf(DOTC(md0,md1,md2,md3,x), 80.f));
    sD += __expf(fminf(DOTC(md0,md1,md2,md3,y), 80.f));
    sD += __expf(fminf(DOTC(md0,md1,md2,md3,z), 80.f));
    sD += __expf(fminf(DOTC(md0,md1,md2,md3,w), 80.f));
  }
  WRED(sA) WRED(sB) WRED(sC) WRED(sD)
  if (lane == 0) {
    irs1[b * NN + mA] = rcpf_(sA);
    irs1[b * NN + mB] = rcpf_(sB);
    irs1[b * NN + mC] = rcpf_(sC);
    irs1[b * NN + mD] = rcpf_(sD);
  }
}

__global__ __launch_bounds__(256) void p3_rs2(
    const float* __restrict__ qt, const float* __restrict__ qk,
    const float* __restrict__ xyz4, const float* __restrict__ xyzk,
    const float* __restrict__ irs1, const float* __restrict__ ics1,
    const float* __restrict__ thr, float* __restrict__ irs2) {
  const int tid = threadIdx.x;
  const int b = blockIdx.x >> 8;
  const int m0 = (blockIdx.x & 255) << 4;
  const int w = tid >> 6, lane = tid & 63;
  const float* qb = qt + (size_t)b * NN * 16;
  const float* kb = qk + (size_t)b * 16 * NN;
  const float* xk = xyzk + (size_t)b * 4 * NN;
  const int mA = m0 + w, mB = m0 + w + 4, mC = m0 + w + 8, mD = m0 + w + 12;
  LQROW(ma, qb + (size_t)mA * 16)
  LQROW(mb, qb + (size_t)mB * 16)
  LQROW(mc, qb + (size_t)mC * 16)
  LQROW(md, qb + (size_t)mD * 16)
  const float4 pmA = *(const float4*)(xyz4 + ((size_t)b * NN + mA) * 4);
  const float4 pmB = *(const float4*)(xyz4 + ((size_t)b * NN + mB) * 4);
  const float4 pmC = *(const float4*)(xyz4 + ((size_t)b * NN + mC) * 4);
  const float4 pmD = *(const float4*)(xyz4 + ((size_t)b * NN + mD) * 4);
  const float rA = irs1[b * NN + mA];
  const float rB = irs1[b * NN + mB];
  const float rC = irs1[b * NN + mC];
  const float rD = irs1[b * NN + mD];
  float sA = 0.f, sB = 0.f, sC = 0.f, sD = 0.f;
#define P3C(S, M0,M1,M2,M3, PM, R, C) { \
    float corr_ = DOTC(M0,M1,M2,M3,C); \
    float a1v_ = __expf(fminf(corr_, 80.f)) * (R) * ic.C; \
    float dd_ = (PM).w + pw.C - 2.f * ((PM).x * px.C + (PM).y * py.C + (PM).z * pz.C); \
    dd_ = fmaxf(dd_, 0.f); \
    float l0_ = (dd_ <= th.C) ? a1v_ : 0.f; \
    S += __expf(l0_); }
  for (int it = 0; it < 16; ++it) {
    const int n0 = (it << 8) + (lane << 2);
    LKPL(kb, n0)
    const float4 px = *(const float4*)(xk + 0*NN + n0);
    const float4 py = *(const float4*)(xk + 1*NN + n0);
    const float4 pz = *(const float4*)(xk + 2*NN + n0);
    const float4 pw = *(const float4*)(xk + 3*NN + n0);
    const float4 ic = *(const float4*)(ics1 + b * NN + n0);
    const float4 th = *(const float4*)(thr + b * NN + n0);
    P3C(sA, ma0,ma1,ma2,ma3, pmA, rA, x)
    P3C(sA, ma0,ma1,ma2,ma3, pmA, rA, y)
    P3C(sA, ma0,ma1,ma2,ma3, pmA, rA, z)
    P3C(sA, ma0,ma1,ma2,ma3, pmA, rA, w)
    P3C(sB, mb0,mb1,mb2,mb3, pmB, rB, x)
    P3C(sB, mb0,mb1,mb2,mb3, pmB, rB, y)
    P3C(sB, mb0,mb1,mb2,mb3, pmB, rB, z)
    P3C(sB, mb0,mb1,mb2,mb3, pmB, rB, w)
    P3C(sC, mc0,mc1,mc2,mc3, pmC, rC, x)
    P3C(sC, mc0,mc1,mc2,mc3, pmC, rC, y)
    P3C(sC, mc0,mc1,mc2,mc3, pmC, rC, z)
    P3C(sC, mc0,mc1,mc2,mc3, pmC, rC, w)
    P3C(sD, md0,md1,md2,md3, pmD, rD, x)
    P3C(sD, md0,md1,md2,md3, pmD, rD, y)
    P3C(sD, md0,md1,md2,md3, pmD, rD, z)
    P3C(sD, md0,md1,md2,md3, pmD, rD, w)
  }
#undef P3C
  WRED(sA) WRED(sB) WRED(sC) WRED(sD)
  if (lane == 0) {
    irs2[b * NN + mA] = rcpf_(sA);
    irs2[b * NN + mB] = rcpf_(sB);
    irs2[b * NN + mC] = rcpf_(sC);
    irs2[b * NN + mD] = rcpf_(sD);
  }
}

__global__ __launch_bounds__(256) void k7_gma(
    const float* __restrict__ qt, const float* __restrict__ xyz4,
    const unsigned short* __restrict__ xvb,
    const float* __restrict__ irs1, const float* __restrict__ irs2,
    const float* __restrict__ ics1, const float* __restrict__ thr,
    float* __restrict__ g1, float* __restrict__ g2, float* __restrict__ cs2) {
  const int tid = threadIdx.x;
  const int bid = blockIdx.x;
  const int msl = bid & 7;
  const int nb = (bid >> 3) & 63;
  const int b = bid >> 9;
  const int n0 = nb << 6;
  const int mstart = msl << 9;
  __shared__ __align__(16) unsigned short attns1[64 * 72];
  __shared__ __align__(16) unsigned short attns2[64 * 72];
  __shared__ __align__(16) unsigned short xvs[64 * 72];
  const float* qb = qt + (size_t)b * NN * 16;
  const float* pb = xyz4 + (size_t)b * NN * 4;
  const int ni = tid & 63, aw = tid >> 6;
  const int na = n0 + ni;
  const float* qnp = qb + (size_t)na * 16;
  LQROW(q, qnp)
  const float4 pn = *(const float4*)(pb + (size_t)na * 4);
  const float ics1n = ics1[b * NN + na];
  const float thr_n = thr[b * NN + na];
  const int lane = tid & 63, wv = tid >> 6;
  const int lr = lane & 15, quad = lane >> 4;
  const int nw = wv << 4;
  f32x4v acc0 = {0,0,0,0}, acc1 = {0,0,0,0}, acc2 = {0,0,0,0}, acc3 = {0,0,0,0};
  f32x4v d0 = {0,0,0,0}, d1 = {0,0,0,0}, d2 = {0,0,0,0}, d3 = {0,0,0,0};
  float csacc = 0.f;
#define COMPA(MOFF, D1, D2) { \
    const int m_ = __builtin_amdgcn_readfirstlane(mw + (MOFF)); \
    const float* qm_ = qb + (size_t)m_ * 16; \
    LQROW(wq, qm_) \
    float corr_ = DOT16M(q0, q1, q2, q3, wq0, wq1, wq2, wq3); \
    const float4 pm_ = *(const float4*)(pb + (size_t)m_ * 4); \
    float a1v_ = __expf(fminf(corr_, 80.f)) * irs1[b * NN + m_] * ics1n; \
    float dd_ = pm_.w + pn.w - 2.f * (pm_.x * pn.x + pm_.y * pn.y + pm_.z * pn.z); \
    dd_ = fmaxf(dd_, 0.f); \
    float l0_ = (dd_ <= thr_n) ? a1v_ : 0.f; \
    float l2n_ = __expf(l0_) * irs2[b * NN + m_]; \
    D1 = f2bf(a1v_); D2 = f2bf(l2n_); csacc += l2n_; }
  for (int mt = 0; mt < 8; ++mt) {
    const int m0 = mstart + (mt << 6);
    __syncthreads();
    {
      const int c = tid >> 2, part = tid & 3;
      const unsigned short* src = xvb + ((size_t)b * 64 + c) * NN + m0 + part * 16;
      unsigned short* dst = xvs + c * 72 + part * 16;
      *(uint4*)dst = *(const uint4*)src;
      *(uint4*)(dst + 8) = *(const uint4*)(src + 8);
    }
    const int mw = m0 + (aw << 4);
#pragma unroll
    for (int g = 0; g < 4; ++g) {
      ushort4 u1, u2;
      COMPA(g * 4 + 0, u1.x, u2.x)
      COMPA(g * 4 + 1, u1.y, u2.y)
      COMPA(g * 4 + 2, u1.z, u2.z)
      COMPA(g * 4 + 3, u1.w, u2.w)
      *(ushort4*)(attns1 + ni * 72 + (aw << 4) + (g << 2)) = u1;
      *(ushort4*)(attns2 + ni * 72 + (aw << 4) + (g << 2)) = u2;
    }
    __syncthreads();
#pragma unroll
    for (int h = 0; h < 2; ++h) {
      const bf16x8 a1 = *(const bf16x8*)(attns1 + (nw + lr) * 72 + h * 32 + quad * 8);
      const bf16x8 a2 = *(const bf16x8*)(attns2 + (nw + lr) * 72 + h * 32 + quad * 8);
      const bf16x8 b0 = *(const bf16x8*)(xvs + (lr) * 72 + h * 32 + quad * 8);
      const bf16x8 b1 = *(const bf16x8*)(xvs + (16 + lr) * 72 + h * 32 + quad * 8);
      const bf16x8 b2 = *(const bf16x8*)(xvs + (32 + lr) * 72 + h * 32 + quad * 8);
      const bf16x8 b3 = *(const bf16x8*)(xvs + (48 + lr) * 72 + h * 32 + quad * 8);
      acc0 = __builtin_amdgcn_mfma_f32_16x16x32_bf16(a1, b0, acc0, 0, 0, 0);
      acc1 = __builtin_amdgcn_mfma_f32_16x16x32_bf16(a1, b1, acc1, 0, 0, 0);
      acc2 = __builtin_amdgcn_mfma_f32_16x16x32_bf16(a1, b2, acc2, 0, 0, 0);
      acc3 = __builtin_amdgcn_mfma_f32_16x16x32_bf16(a1, b3, acc3, 0, 0, 0);
      d0 = __builtin_amdgcn_mfma_f32_16x16x32_bf16(a2, b0, d0, 0, 0, 0);
      d1 = __builtin_amdgcn_mfma_f32_16x16x32_bf16(a2, b1, d1, 0, 0, 0);
      d2 = __builtin_amdgcn_mfma_f32_16x16x32_bf16(a2, b2, d2, 0, 0, 0);
      d3 = __builtin_amdgcn_mfma_f32_16x16x32_bf16(a2, b3, d3, 0, 0, 0);
    }
  }
#undef COMPA
  atomicAdd(&cs2[b * NN + na], csacc);
#define EPI(ACC, DST, CT) { \
    float* g_ = (DST) + ((size_t)b * NN + n0 + nw + (quad << 2)) * 64 + (CT) * 16 + lr; \
    atomicAdd(g_ + 0,   ACC[0]); \
    atomicAdd(g_ + 64,  ACC[1]); \
    atomicAdd(g_ + 128, ACC[2]); \
    atomicAdd(g_ + 192, ACC[3]); }
  EPI(acc0, g1, 0) EPI(acc1, g1, 1) EPI(acc2, g1, 2) EPI(acc3, g1, 3)
  EPI(d0, g2, 0) EPI(d1, g2, 1) EPI(d2, g2, 2) EPI(d3, g2, 3)
#undef EPI
}

// ============ materialized-exp path (used iff ws_size permits) ============

// P1M: a0 tile [64m x 64n] per block via bf16-split MFMA (round-7 WIN).
__global__ __launch_bounds__(256) void p1m_corr(
    const unsigned short* __restrict__ qbh, const unsigned short* __restrict__ qbl,
    float* __restrict__ rs1raw, unsigned short* __restrict__ a0g) {
  const int tid = threadIdx.x;
  const int nt = blockIdx.x & 63;
  const int mt = (blockIdx.x >> 6) & 63;
  const int b  = blockIdx.x >> 12;
  const int m0 = mt << 6, n0 = nt << 6;
  const int w = tid >> 6, l = tid & 63;
  const int lr = l & 15, quad = l >> 4;
  const int qk8 = (quad & 1) << 3;
  __shared__ __align__(16) unsigned short t0[64 * 72];
  const unsigned short* qh = qbh + (size_t)b * NN * 16;
  const unsigned short* qlo = qbl + (size_t)b * NN * 16;
  const int arow = m0 + (w << 4) + lr;
  const bf16x8 afrag = *(const bf16x8*)((quad < 2 ? qh : qlo) + (size_t)arow * 16 + qk8);
  f32x4v acc0 = {0,0,0,0}, acc1 = {0,0,0,0}, acc2 = {0,0,0,0}, acc3 = {0,0,0,0};
#define DOS(ACC, S) { \
    const int brow_ = n0 + ((S) << 4) + lr; \
    const bf16x8 bhh_ = *(const bf16x8*)(qh + (size_t)brow_ * 16 + qk8); \
    const bf16x8 bll_ = *(const bf16x8*)(qlo + (size_t)brow_ * 16 + qk8); \
    ACC = __builtin_amdgcn_mfma_f32_16x16x32_bf16(afrag, bhh_, ACC, 0, 0, 0); \
    ACC = __builtin_amdgcn_mfma_f32_16x16x32_bf16(afrag, bll_, ACC, 0, 0, 0); }
  DOS(acc0, 0) DOS(acc1, 1) DOS(acc2, 2) DOS(acc3, 3)
#undef DOS
  unsigned short* tw = t0 + (w << 4) * 72;
#define EPW(ACC, S) { \
    tw[((quad << 2) + 0) * 72 + ((S) << 4) + lr] = f2bf(__expf(fminf(ACC[0], 80.f))); \
    tw[((quad << 2) + 1) * 72 + ((S) << 4) + lr] = f2bf(__expf(fminf(ACC[1], 80.f))); \
    tw[((quad << 2) + 2) * 72 + ((S) << 4) + lr] = f2bf(__expf(fminf(ACC[2], 80.f))); \
    tw[((quad << 2) + 3) * 72 + ((S) << 4) + lr] = f2bf(__expf(fminf(ACC[3], 80.f))); }
  EPW(acc0, 0) EPW(acc1, 1) EPW(acc2, 2) EPW(acc3, 3)
#undef EPW
  __syncthreads();
  const int row = tid >> 2, cb = (tid & 3) << 4;
  const unsigned short* src = t0 + row * 72 + cb;
  const uint4 u0 = *(const uint4*)(src);
  const uint4 u1 = *(const uint4*)(src + 8);
  unsigned short* dst = a0g + (size_t)b * NN * NN + (size_t)(m0 + row) * NN + n0 + cb;
  *(uint4*)dst = u0;
  *(uint4*)(dst + 8) = u1;
  float s = 0.f;
#define SUM2(U) { s += bf2f((unsigned short)((U) & 0xffffu)) + bf2f((unsigned short)((U) >> 16)); }
  SUM2(u0.x) SUM2(u0.y) SUM2(u0.z) SUM2(u0.w)
  SUM2(u1.x) SUM2(u1.y) SUM2(u1.z) SUM2(u1.w)
#undef SUM2
  s += __shfl_xor(s, 1);
  s += __shfl_xor(s, 2);
  if ((tid & 3) == 0) atomicAdd(&rs1raw[b * NN + m0 + row], s);
}

// K_INV: irs1[i] = 1/rs1raw[i]
__global__ __launch_bounds__(256) void k_inv(
    const float* __restrict__ raw, float* __restrict__ irs1) {
  const int i = blockIdx.x * 256 + threadIdx.x;
  irs1[i] = rcpf_(raw[i]);
}

// P2R: cs1 via SYMMETRY of corr: cs1[n] = sum_m a0[n][m]*irs1[m].
__global__ __launch_bounds__(256) void p2r_cs1(
    const unsigned short* __restrict__ a0g, const float* __restrict__ irs1,
    float* __restrict__ ics1) {
  const int tid = threadIdx.x;
  const int w = tid >> 6, l = tid & 63;
  const int bi = blockIdx.x;                 // 0..2047
  const int b = bi >> 10;
  const int n = ((bi & 1023) << 2) + w;      // 4 rows per block, 1 per wave
  const unsigned short* row = a0g + ((size_t)b * NN + n) * NN;
  const float* ir = irs1 + b * NN;
  float s = 0.f;
#pragma unroll
  for (int it = 0; it < 8; ++it) {
    const int m = (it << 9) + (l << 3);
    const uint4 u = *(const uint4*)(row + m);
    const float4 i0 = *(const float4*)(ir + m);
    const float4 i1 = *(const float4*)(ir + m + 4);
    s = fmaf(bf2f((unsigned short)(u.x & 0xffffu)), i0.x, s);
    s = fmaf(bf2f((unsigned short)(u.x >> 16)),     i0.y, s);
    s = fmaf(bf2f((unsigned short)(u.y & 0xffffu)), i0.z, s);
    s = fmaf(bf2f((unsigned short)(u.y >> 16)),     i0.w, s);
    s = fmaf(bf2f((unsigned short)(u.z & 0xffffu)), i1.x, s);
    s = fmaf(bf2f((unsigned short)(u.z >> 16)),     i1.y, s);
    s = fmaf(bf2f((unsigned short)(u.w & 0xffffu)), i1.z, s);
    s = fmaf(bf2f((unsigned short)(u.w >> 16)),     i1.w, s);
  }
  WRED(s)
  if (l == 0) ics1[b * NN + n] = rcpf_(1e-9f + s);
}

// P3W: reads a0 rows (16B/lane), stores ae[m][n]=bf16(exp(l0)) (16B/lane),
// sums ROUNDED values.  r8: 4 rows/wave (16/block, 512 blocks) -- n-side
// vector streams amortize over 4 rows, halving their L2 traffic.  Same
// per-element ops and order -> bit-exact vs 2-row version.
__global__ __launch_bounds__(256) void p3w_rs2(
    const float* __restrict__ xyz4, const float* __restrict__ xyzk,
    const float* __restrict__ irs1, const float* __restrict__ ics1,
    const float* __restrict__ thr, float* __restrict__ irs2,
    const unsigned short* __restrict__ a0g, unsigned short* __restrict__ aeg) {
  const int tid = threadIdx.x;
  const int b = blockIdx.x >> 8;
  const int m0 = (blockIdx.x & 255) << 4;
  const int w = tid >> 6, lane = tid & 63;
  const float* xk = xyzk + (size_t)b * 4 * NN;
  const unsigned short* ab = a0g + (size_t)b * NN * NN;
  unsigned short* eb = aeg + (size_t)b * NN * NN;
  const int mA = m0 + (w << 2), mB = mA + 1, mC = mA + 2, mD = mA + 3;
  const float4 pmA = *(const float4*)(xyz4 + ((size_t)b * NN + mA) * 4);
  const float4 pmB = *(const float4*)(xyz4 + ((size_t)b * NN + mB) * 4);
  const float4 pmC = *(const float4*)(xyz4 + ((size_t)b * NN + mC) * 4);
  const float4 pmD = *(const float4*)(xyz4 + ((size_t)b * NN + mD) * 4);
  const float rA = irs1[b * NN + mA];
  const float rB = irs1[b * NN + mB];
  const float rC = irs1[b * NN + mC];
  const float rD = irs1[b * NN + mD];
  float sA = 0.f, sB = 0.f, sC = 0.f, sD = 0.f;
#define P3E(S, OUT, A0W, SH, PM, R, PX, PY, PZ, PW, IC, TH) { \
    float a1v_ = bf2f((unsigned short)(((A0W) >> (SH)) & 0xffffu)) * (R) * (IC); \
    float dd_ = (PM).w + (PW) - 2.f * ((PM).x * (PX) + (PM).y * (PY) + (PM).z * (PZ)); \
    dd_ = fmaxf(dd_, 0.f); \
    float l0_ = (dd_ <= (TH)) ? a1v_ : 0.f; \
    const unsigned short us_ = f2bf(__expf(l0_)); OUT = us_; S += bf2f(us_); }
#define PROW(S, RU, PM, R, MROW) { \
    unsigned short e0, e1, e2, e3, e4, e5, e6, e7; \
    P3E(S, e0, RU.x, 0,  PM, R, pxl.x, pyl.x, pzl.x, pwl.x, icl.x, thl.x) \
    P3E(S, e1, RU.x, 16, PM, R, pxl.y, pyl.y, pzl.y, pwl.y, icl.y, thl.y) \
    P3E(S, e2, RU.y, 0,  PM, R, pxl.z, pyl.z, pzl.z, pwl.z, icl.z, thl.z) \
    P3E(S, e3, RU.y, 16, PM, R, pxl.w, pyl.w, pzl.w, pwl.w, icl.w, thl.w) \
    P3E(S, e4, RU.z, 0,  PM, R, pxh.x, pyh.x, pzh.x, pwh.x, ich.x, thh.x) \
    P3E(S, e5, RU.z, 16, PM, R, pxh.y, pyh.y, pzh.y, pwh.y, ich.y, thh.y) \
    P3E(S, e6, RU.w, 0,  PM, R, pxh.z, pyh.z, pzh.z, pwh.z, ich.z, thh.z) \
    P3E(S, e7, RU.w, 16, PM, R, pxh.w, pyh.w, pzh.w, pwh.w, ich.w, thh.w) \
    uint4 U_; \
    U_.x = (unsigned)e0 | ((unsigned)e1 << 16); \
    U_.y = (unsigned)e2 | ((unsigned)e3 << 16); \
    U_.z = (unsigned)e4 | ((unsigned)e5 << 16); \
    U_.w = (unsigned)e6 | ((unsigned)e7 << 16); \
    *(uint4*)(eb + (size_t)(MROW) * NN + n0) = U_; }
  for (int it = 0; it < 8; ++it) {
    const int n0 = (it << 9) + (lane << 3);
    const float4 pxl = *(const float4*)(xk + 0*NN + n0);
    const float4 pxh = *(const float4*)(xk + 0*NN + n0 + 4);
    const float4 pyl = *(const float4*)(xk + 1*NN + n0);
    const float4 pyh = *(const float4*)(xk + 1*NN + n0 + 4);
    const float4 pzl = *(const float4*)(xk + 2*NN + n0);
    const float4 pzh = *(const float4*)(xk + 2*NN + n0 + 4);
    const float4 pwl = *(const float4*)(xk + 3*NN + n0);
    const float4 pwh = *(const float4*)(xk + 3*NN + n0 + 4);
    const float4 icl = *(const float4*)(ics1 + b * NN + n0);
    const float4 ich = *(const float4*)(ics1 + b * NN + n0 + 4);
    const float4 thl = *(const float4*)(thr + b * NN + n0);
    const float4 thh = *(const float4*)(thr + b * NN + n0 + 4);
    const uint4 rAu = *(const uint4*)(ab + (size_t)mA * NN + n0);
    const uint4 rBu = *(const uint4*)(ab + (size_t)mB * NN + n0);
    const uint4 rCu = *(const uint4*)(ab + (size_t)mC * NN + n0);
    const uint4 rDu = *(const uint4*)(ab + (size_t)mD * NN + n0);
    PROW(sA, rAu, pmA, rA, mA)
    PROW(sB, rBu, pmB, rB, mB)
    PROW(sC, rCu, pmC, rC, mC)
    PROW(sD, rDu, pmD, rD, mD)
  }
#undef PROW
#undef P3E
  WRED(sA) WRED(sB) WRED(sC) WRED(sD)
  if (lane == 0) {
    irs2[b * NN + mA] = rcpf_(sA);
    irs2[b * NN + mB] = rcpf_(sB);
    irs2[b * NN + mC] = rcpf_(sC);
    irs2[b * NN + mD] = rcpf_(sD);
  }
}

// P4: cs2[n] = sum_m bf16(bf16(ae[m][n]) * irs2[m]) -- exact match of what
// k7n stages into the MFMA.  1024 blocks (64-row m strips).
__global__ __launch_bounds__(256) void p4_cs2(
    const unsigned short* __restrict__ aeg, const float* __restrict__ irs2,
    float* __restrict__ cs2) {
  const int tid = threadIdx.x;
  const int bid = blockIdx.x;              // B*8*64 = 1024 blocks
  const int ms = bid & 63;                 // m strip (64 rows)
  const int ng = (bid >> 6) & 7;           // n group (512 cols)
  const int b  = bid >> 9;
  const int n2 = (ng << 9) + (tid << 1);   // 2 columns per thread
  const unsigned short* eb = aeg + (size_t)b * NN * NN + n2;
  const float* r2 = irs2 + b * NN;
  float s0 = 0.f, s1 = 0.f;
  const int m0 = ms << 6;
#pragma unroll 4
  for (int m = m0; m < m0 + 64; ++m) {
    const unsigned u = *(const unsigned*)(eb + (size_t)m * NN);
    const float r = r2[m];
    s0 += bf2f(f2bf(bf2f((unsigned short)(u & 0xffffu)) * r));
    s1 += bf2f(f2bf(bf2f((unsigned short)(u >> 16)) * r));
  }
  atomicAdd(&cs2[b * NN + n2], s0);
  atomicAdd(&cs2[b * NN + n2 + 1], s1);
}

// LDS swizzle: spreads both the b32 transpose-writes (2-way, free) and the
// b128 reads (uniform) across banks.
#define SW(r) ((((r) & 7) << 4) ^ ((((r) >> 3) & 3) << 5))

// K7N: GMA with fused g1/g2 combine (needs cs2 from p4).  r8: s_setprio
// around the MFMA cluster (T5; dbuf phases give wave role diversity).
__global__ __launch_bounds__(256) void k7n_gma(
    const unsigned short* __restrict__ a0g, const unsigned short* __restrict__ aeg,
    const unsigned short* __restrict__ xvb,
    const float* __restrict__ irs1, const float* __restrict__ irs2,
    const float* __restrict__ ics1, const float* __restrict__ cs2,
    float* __restrict__ gma) {
  const int tid = threadIdx.x;
  const int bid = blockIdx.x;              // 512 blocks: B * 64 nb * 4 msl
  const int msl = bid & 3;
  const int nb  = (bid >> 2) & 63;
  const int b   = bid >> 8;
  const int n0 = nb << 6;
  const int mstart = msl << 10;            // 1024-row m strip -> 16 tiles
  __shared__ __align__(16) unsigned short attns1[2][64 * 64];
  __shared__ __align__(16) unsigned short attns2[2][64 * 64];
  __shared__ __align__(16) unsigned short xvs[2][64 * 64];
  const unsigned short* ab = a0g + (size_t)b * NN * NN;
  const unsigned short* ebp = aeg + (size_t)b * NN * NN;
  const float* irs1b = irs1 + b * NN;
  const float* irs2b = irs2 + b * NN;
  const int w = tid >> 6, l = tid & 63;
  const int lrow0 = (w << 4) + ((l >> 3) << 1);
  const int nc8 = (l & 7) << 3;
  const int gcol = n0 + nc8;
  const int xc = tid >> 2, xpart = tid & 3;
  const unsigned short* xvp = xvb + ((size_t)b * 64 + xc) * NN;
  const int lr = l & 15, quad = l >> 4;
  const int nw = w << 4;
  f32x4v acc0 = {0,0,0,0}, acc1 = {0,0,0,0}, acc2 = {0,0,0,0}, acc3 = {0,0,0,0};
  f32x4v d0 = {0,0,0,0}, d1 = {0,0,0,0}, d2 = {0,0,0,0}, d3 = {0,0,0,0};

  uint4 pa0A, pa1A, pe0A, pe1A, pv0A, pv1A;
  uint4 pa0B, pa1B, pe0B, pe1B, pv0B, pv1B;
  float r1aA, r1bA, r2aA, r2bA, r1aB, r1bB, r2aB, r2bB;

#define ISSUE(S, MT) { \
    const int m0_ = mstart + ((MT) << 6); \
    const size_t ra_ = (size_t)(m0_ + lrow0) * NN + gcol; \
    pa0##S = *(const uint4*)(ab + ra_); \
    pa1##S = *(const uint4*)(ab + ra_ + NN); \
    pe0##S = *(const uint4*)(ebp + ra_); \
    pe1##S = *(const uint4*)(ebp + ra_ + NN); \
    pv0##S = *(const uint4*)(xvp + m0_ + (xpart << 4)); \
    pv1##S = *(const uint4*)(xvp + m0_ + (xpart << 4) + 8); \
    r1a##S = irs1b[m0_ + lrow0]; r1b##S = irs1b[m0_ + lrow0 + 1]; \
    r2a##S = irs2b[m0_ + lrow0]; r2b##S = irs2b[m0_ + lrow0 + 1]; }

#define CVW(D0, D1, SH, J, R0, R1, ARR) { \
    const float v0_ = bf2f((unsigned short)(((D0) >> (SH)) & 0xffffu)) * (R0); \
    const float v1_ = bf2f((unsigned short)(((D1) >> (SH)) & 0xffffu)) * (R1); \
    const unsigned pk_ = (unsigned)f2bf(v0_) | ((unsigned)f2bf(v1_) << 16); \
    const int nl_ = nc8 + (J); \
    *(unsigned*)((char*)(ARR) + ((((nl_) << 7) + (lrow0 << 1)) ^ SW(nl_))) = pk_; }

#define WR8(U0, U1, R0, R1, ARR) \
    CVW(U0.x, U1.x, 0,  0, R0, R1, ARR) CVW(U0.x, U1.x, 16, 1, R0, R1, ARR) \
    CVW(U0.y, U1.y, 0,  2, R0, R1, ARR) CVW(U0.y, U1.y, 16, 3, R0, R1, ARR) \
    CVW(U0.z, U1.z, 0,  4, R0, R1, ARR) CVW(U0.z, U1.z, 16, 5, R0, R1, ARR) \
    CVW(U0.w, U1.w, 0,  6, R0, R1, ARR) CVW(U0.w, U1.w, 16, 7, R0, R1, ARR)

#define STX(XARR, PV0, PV1) { \
    const int xb_ = (xc << 7) + (xpart << 5); \
    *(uint4*)((char*)(XARR) + ((xb_) ^ SW(xc))) = PV0; \
    *(uint4*)((char*)(XARR) + ((xb_ + 16) ^ SW(xc))) = PV1; }

#define LDSW(ARR, ROW, H, Q) \
    (*(const bf16x8*)((const char*)(ARR) + \
      ((((ROW) << 7) + ((H) << 6) + ((Q) << 4)) ^ SW(ROW))))

#define MPH(A1P, A2P, XVP_) { \
    __builtin_amdgcn_s_setprio(1); \
    for (int h = 0; h < 2; ++h) { \
      const bf16x8 fa1 = LDSW(A1P, nw + lr, h, quad); \
      const bf16x8 fa2 = LDSW(A2P, nw + lr, h, quad); \
      const bf16x8 fb0 = LDSW(XVP_, lr, h, quad); \
      const bf16x8 fb1 = LDSW(XVP_, 16 + lr, h, quad); \
      const bf16x8 fb2 = LDSW(XVP_, 32 + lr, h, quad); \
      const bf16x8 fb3 = LDSW(XVP_, 48 + lr, h, quad); \
      acc0 = __builtin_amdgcn_mfma_f32_16x16x32_bf16(fa1, fb0, acc0, 0, 0, 0); \
      acc1 = __builtin_amdgcn_mfma_f32_16x16x32_bf16(fa1, fb1, acc1, 0, 0, 0); \
      acc2 = __builtin_amdgcn_mfma_f32_16x16x32_bf16(fa1, fb2, acc2, 0, 0, 0); \
      acc3 = __builtin_amdgcn_mfma_f32_16x16x32_bf16(fa1, fb3, acc3, 0, 0, 0); \
      d0 = __builtin_amdgcn_mfma_f32_16x16x32_bf16(fa2, fb0, d0, 0, 0, 0); \
      d1 = __builtin_amdgcn_mfma_f32_16x16x32_bf16(fa2, fb1, d1, 0, 0, 0); \
      d2 = __builtin_amdgcn_mfma_f32_16x16x32_bf16(fa2, fb2, d2, 0, 0, 0); \
      d3 = __builtin_amdgcn_mfma_f32_16x16x32_bf16(fa2, fb3, d3, 0, 0, 0); \
    } \
    __builtin_amdgcn_s_setprio(0); }

  ISSUE(A, 0)
  ISSUE(B, 1)
  for (int mt = 0; mt < 16; mt += 2) {
    WR8(pa0A, pa1A, r1aA, r1bA, attns1[0])
    WR8(pe0A, pe1A, r2aA, r2bA, attns2[0])
    STX(xvs[0], pv0A, pv1A)
    __syncthreads();
    if (mt + 2 < 16) { ISSUE(A, mt + 2) }
    MPH(attns1[0], attns2[0], xvs[0])
    WR8(pa0B, pa1B, r1aB, r1bB, attns1[1])
    WR8(pe0B, pe1B, r2aB, r2bB, attns2[1])
    STX(xvs[1], pv0B, pv1B)
    __syncthreads();
    if (mt + 3 < 16) { ISSUE(B, mt + 3) }
    MPH(attns1[1], attns2[1], xvs[1])
  }
#undef ISSUE
#undef CVW
#undef WR8
#undef STX
#undef LDSW
#undef MPH
  float w10, w11, w12, w13, w20, w21, w22, w23;
  {
    const int nr = n0 + nw + (quad << 2);
    w10 = ics1[b * NN + nr + 0]; w20 = rcpf_(1e-9f + cs2[b * NN + nr + 0]);
    w11 = ics1[b * NN + nr + 1]; w21 = rcpf_(1e-9f + cs2[b * NN + nr + 1]);
    w12 = ics1[b * NN + nr + 2]; w22 = rcpf_(1e-9f + cs2[b * NN + nr + 2]);
    w13 = ics1[b * NN + nr + 3]; w23 = rcpf_(1e-9f + cs2[b * NN + nr + 3]);
  }
#define EPI(ACC, DD, CT) { \
    float* g_ = gma + ((size_t)b * NN + n0 + nw + (quad << 2)) * 64 + (CT) * 16 + lr; \
    atomicAdd(g_ + 0,   fmaf(ACC[0], w10, DD[0] * w20)); \
    atomicAdd(g_ + 64,  fmaf(ACC[1], w11, DD[1] * w21)); \
    atomicAdd(g_ + 128, fmaf(ACC[2], w12, DD[2] * w22)); \
    atomicAdd(g_ + 192, fmaf(ACC[3], w13, DD[3] * w23)); }
  EPI(acc0, d0, 0) EPI(acc1, d1, 1) EPI(acc2, d2, 2) EPI(acc3, d3, 3)
#undef EPI
}

// ===================== common p2 / k8 / k9 =====================

__global__ __launch_bounds__(256) void p2_cs1(
    const float* __restrict__ qt, const float* __restrict__ qk,
    const float* __restrict__ irs1, float* __restrict__ ics1) {
  const int tid = threadIdx.x;
  const int b = blockIdx.x >> 8;
  const int n0t = (blockIdx.x & 255) << 4;
  const int w = tid >> 6, lane = tid & 63;
  const float* qb = qt + (size_t)b * NN * 16;
  const float* kb = qk + (size_t)b * 16 * NN;
  const int nA = n0t + w, nB = n0t + w + 4, nC = n0t + w + 8, nD = n0t + w + 12;
  LQROW(na, qb + (size_t)nA * 16)
  LQROW(nb, qb + (size_t)nB * 16)
  LQROW(nc, qb + (size_t)nC * 16)
  LQROW(nd, qb + (size_t)nD * 16)
  float sA = 0.f, sB = 0.f, sC = 0.f, sD = 0.f;
  for (int it = 0; it < 16; ++it) {
    const int m0 = (it << 8) + (lane << 2);
    LKPL(kb, m0)
    const float4 r1 = *(const float4*)(irs1 + b * NN + m0);
    sA = fmaf(__expf(fminf(DOTC(na0,na1,na2,na3,x), 80.f)), r1.x, sA);
    sA = fmaf(__expf(fminf(DOTC(na0,na1,na2,na3,y), 80.f)), r1.y, sA);
    sA = fmaf(__expf(fminf(DOTC(na0,na1,na2,na3,z), 80.f)), r1.z, sA);
    sA = fmaf(__expf(fminf(DOTC(na0,na1,na2,na3,w), 80.f)), r1.w, sA);
    sB = fmaf(__expf(fminf(DOTC(nb0,nb1,nb2,nb3,x), 80.f)), r1.x, sB);
    sB = fmaf(__expf(fminf(DOTC(nb0,nb1,nb2,nb3,y), 80.f)), r1.y, sB);
    sB = fmaf(__expf(fminf(DOTC(nb0,nb1,nb2,nb3,z), 80.f)), r1.z, sB);
    sB = fmaf(__expf(fminf(DOTC(nb0,nb1,nb2,nb3,w), 80.f)), r1.w, sB);
    sC = fmaf(__expf(fminf(DOTC(nc0,nc1,nc2,nc3,x), 80.f)), r1.x, sC);
    sC = fmaf(__expf(fminf(DOTC(nc0,nc1,nc2,nc3,y), 80.f)), r1.y, sC);
    sC = fmaf(__expf(fminf(DOTC(nc0,nc1,nc2,nc3,z), 80.f)), r1.z, sC);
    sC = fmaf(__expf(fminf(DOTC(nc0,nc1,nc2,nc3,w), 80.f)), r1.w, sC);
    sD = fmaf(__expf(fminf(DOTC(nd0,nd1,nd2,nd3,x), 80.f)), r1.x, sD);
    sD = fmaf(__expf(fminf(DOTC(nd0,nd1,nd2,nd3,y), 80.f)), r1.y, sD);
    sD = fmaf(__expf(fminf(DOTC(nd0,nd1,nd2,nd3,z), 80.f)), r1.z, sD);
    sD = fmaf(__expf(fminf(DOTC(nd0,nd1,nd2,nd3,w), 80.f)), r1.w, sD);
  }
  WRED(sA) WRED(sB) WRED(sC) WRED(sD)
  if (lane == 0) {
    ics1[b * NN + nA] = rcpf_(1e-9f + sA);
    ics1[b * NN + nB] = rcpf_(1e-9f + sB);
    ics1[b * NN + nC] = rcpf_(1e-9f + sC);
    ics1[b * NN + nD] = rcpf_(1e-9f + sD);
  }
}

// mode 0: gma = g1 + g2*ics2 (fallback);  mode 2: gma already combined in g1.
__global__ __launch_bounds__(256) void k8_res(
    const void* __restrict__ mot, const void* __restrict__ wt,
    const void* __restrict__ bt, const float* __restrict__ flag,
    float* __restrict__ g1_res, const float* __restrict__ g2,
    const float* __restrict__ cs2, float* __restrict__ gn,
    const float* __restrict__ ics1, int g1mode) {
  const bool f32 = flag[0] > 0.5f;
  const int tid = threadIdx.x;
  const int bid = blockIdx.x;
  const int b = bid >> 9;
  const int n0 = (bid & 511) << 3;
  __shared__ float wtT[64 * 65];
  __shared__ float bts[64];
  __shared__ float md[8 * 64];
  __shared__ float gs[8], gss[8];
  for (int i = tid; i < 4096; i += 256) {
    int o = i & 63, c = i >> 6;
    wtT[c * 65 + o] = ldin(wt, o * 64 + c, f32);
  }
  if (tid < 64) bts[tid] = ldin(bt, tid, f32);
  if (tid < 8) { gs[tid] = 0.f; gss[tid] = 0.f; }
#pragma unroll
  for (int r = 0; r < 2; ++r) {
    const int idx = tid * 2 + r;
    const int c = idx & 63, nl = idx >> 6;
    const size_t gi = ((size_t)b * NN + n0 + nl) * 64 + c;
    float gmav;
    if (g1mode == 2) {
      gmav = g1_res[gi];
    } else {
      const float ics2n = rcpf_(1e-9f + cs2[b * NN + n0 + nl]);
      float g1v = g1_res[gi];
      if (g1mode == 1) g1v *= ics1[b * NN + n0 + nl];
      gmav = fmaf(g2[gi], ics2n, g1v);
    }
    md[nl * 64 + c] = ldin(mot, ((size_t)b * 64 + c) * NN + n0 + nl, f32) - gmav;
  }
  __syncthreads();
  const int o = tid & 63, ng = tid >> 6;
  const int nl0 = ng * 2, nl1 = ng * 2 + 1;
  float a0 = bts[o], a1 = bts[o];
#pragma unroll 8
  for (int c = 0; c < 64; ++c) {
    float w = wtT[c * 65 + o];
    a0 = fmaf(w, md[nl0 * 64 + c], a0);
    a1 = fmaf(w, md[nl1 * 64 + c], a1);
  }
  g1_res[((size_t)b * NN + n0 + nl0) * 64 + o] = a0;
  g1_res[((size_t)b * NN + n0 + nl1) * 64 + o] = a1;
  atomicAdd(&gs[o >> 3], a0 + a1);
  atomicAdd(&gss[o >> 3], a0 * a0 + a1 * a1);
  __syncthreads();
  if (tid < 8) atomicAdd(&gn[b * 8 + tid], gs[tid]);
  else if (tid < 16) atomicAdd(&gn[16 + b * 8 + (tid - 8)], gss[tid - 8]);
}

// K9T: tiled output epilogue.  Phase 1: coalesced float4 reads of res
// [n][c], GN+PReLU+alpha in registers, LDS transpose to [c][n].  Phase 2:
// coalesced bf16 motion reads + output writes along n.  Bit-exact per
// element vs the old k9 (same op sequence), but ~64x fewer read requests.
__global__ __launch_bounds__(256) void k9t_out(
    const float* __restrict__ res, const float* __restrict__ gn,
    const void* __restrict__ mot,
    const void* __restrict__ gnw, const void* __restrict__ gnb,
    const void* __restrict__ pa, const void* __restrict__ al,
    const float* __restrict__ flag, void* __restrict__ out) {
  const bool f32 = flag[0] > 0.5f;
  const int tid = threadIdx.x;
  const int b = blockIdx.x >> 7;           // 256 blocks: B x 128 n-tiles
  const int n0 = (blockIdx.x & 127) << 5;  // 32 n per tile
  __shared__ float ty[64][33];             // [c][n] transposed, +1 pad
  const float inv_cnt = 1.f / 32768.f;
  const float slope = ldin(pa, 0, f32);
  const float alv = ldin(al, 0, f32);
  // phase 1: each thread: one n-row (row), 8 consecutive c (one group g)
  {
    const int row = tid >> 3;              // 32 rows, 8 threads/row
    const int cseg = (tid & 7) << 3;       // 8 cols, g = cseg>>3 uniform
    const int g = cseg >> 3;
    const float mean = gn[b * 8 + g] * inv_cnt;
    float var = gn[16 + b * 8 + g] * inv_cnt - mean * mean;
    var = fmaxf(var, 0.f);
    const float rstd = rsqrtf(var + 1e-5f);
    const float* rp = res + ((size_t)b * NN + n0 + row) * 64 + cseg;
    const float4 v0 = *(const float4*)rp;
    const float4 v1 = *(const float4*)(rp + 4);
#define GNP(V, J) { \
      const int c_ = cseg + (J); \
      float y_ = (V - mean) * rstd * ldin(gnw, c_, f32) + ldin(gnb, c_, f32); \
      y_ = (y_ >= 0.f) ? y_ : slope * y_; \
      ty[c_][row] = alv * y_; }
    GNP(v0.x, 0) GNP(v0.y, 1) GNP(v0.z, 2) GNP(v0.w, 3)
    GNP(v1.x, 4) GNP(v1.y, 5) GNP(v1.z, 6) GNP(v1.w, 7)
#undef GNP
  }
  __syncthreads();
  // phase 2: each thread: one c, 8 consecutive n; coalesced mot/out.
  {
    const int c = tid >> 2;                // 64 c
    const int ns = (tid & 3) << 3;         // 8 n's
    const size_t mbase = ((size_t)b * 64 + c) * NN + n0 + ns;
    if (f32) {
      const float* mp = (const float*)mot + mbase;
      float* op = (float*)out + mbase;
#pragma unroll
      for (int j = 0; j < 8; ++j) op[j] = ty[c][ns + j] + mp[j];
    } else {
      const __hip_bfloat16* mp = (const __hip_bfloat16*)mot + mbase;
      __hip_bfloat16* op = (__hip_bfloat16*)out + mbase;
#pragma unroll
      for (int j = 0; j < 8; ++j)
        op[j] = __float2bfloat16(ty[c][ns + j] + __bfloat162float(mp[j]));
    }
  }
}

extern "C" void kernel_launch(void* const* d_in, const int* in_sizes, int n_in,
                              void* d_out, int out_size, void* d_ws, size_t ws_size,
                              hipStream_t stream) {
  const void* ctx = d_in[0];
  const void* mot = d_in[1];
  const void* xyz = d_in[2];
  const void* wqk = d_in[3];
  const void* wv  = d_in[4];
  const void* bv  = d_in[5];
  const void* wt  = d_in[6];
  const void* bt  = d_in[7];
  const void* gnw = d_in[8];
  const void* gnb = d_in[9];
  const void* pa  = d_in[10];
  const void* al  = d_in[11];
  float* ws = (float*)d_ws;
  const bool big = ws_size >= (size_t)FULL_F * sizeof(float);

  if (ws_size < (size_t)WS_TOTAL * sizeof(float))
    fprintf(stderr, "[gma3d] WARNING ws_size=%zu < needed %zu\n",
            ws_size, (size_t)WS_TOTAL * sizeof(float));

  hipMemsetAsync(ws + OFF_SUMS, 0, (size_t)ZERO_F * sizeof(float), stream);

  k0_detect<<<1, 256, 0, stream>>>((const unsigned short*)ctx, ws + OFF_FLAG);
  k1_q_xyz<<<32, 256, 0, stream>>>(ctx, xyz, wqk, ws + OFF_FLAG,
                                   ws + OFF_QT, ws + OFF_QK,
                                   ws + OFF_XYZ4, ws + OFF_XYZK, ws + OFF_SUMS,
                                   big ? (unsigned short*)(ws + OFF_QBH) : (unsigned short*)nullptr,
                                   big ? (unsigned short*)(ws + OFF_QBL) : (unsigned short*)nullptr);
  k2_xv<<<128, 256, 0, stream>>>(mot, wv, bv, ws + OFF_FLAG,
                                 (unsigned short*)(ws + OFF_XVB));
  k2b_thr<<<32, 256, 0, stream>>>(ws + OFF_XYZ4, ws + OFF_SUMS, ws + OFF_THR);

  if (big) {
    unsigned short* a0 = (unsigned short*)(ws + OFF_A0);
    unsigned short* ae = (unsigned short*)(ws + OFF_AE);
    p1m_corr<<<8192, 256, 0, stream>>>((const unsigned short*)(ws + OFF_QBH),
                                       (const unsigned short*)(ws + OFF_QBL),
                                       ws + OFF_RS1R, a0);
    k_inv<<<32, 256, 0, stream>>>(ws + OFF_RS1R, ws + OFF_IRS1);
    p2r_cs1<<<2048, 256, 0, stream>>>(a0, ws + OFF_IRS1, ws + OFF_ICS1);
    p3w_rs2<<<512, 256, 0, stream>>>(ws + OFF_XYZ4, ws + OFF_XYZK,
                                     ws + OFF_IRS1, ws + OFF_ICS1, ws + OFF_THR,
                                     ws + OFF_IRS2, a0, ae);
    p4_cs2<<<1024, 256, 0, stream>>>(ae, ws + OFF_IRS2, ws + OFF_CS2);
    k7n_gma<<<512, 256, 0, stream>>>(a0, ae,
                                     (const unsigned short*)(ws + OFF_XVB),
                                     ws + OFF_IRS1, ws + OFF_IRS2,
                                     ws + OFF_ICS1, ws + OFF_CS2,
                                     ws + OFF_GMA);
    k8_res<<<1024, 256, 0, stream>>>(mot, wt, bt, ws + OFF_FLAG,
                                     ws + OFF_GMA, ws + OFF_G2, ws + OFF_CS2,
                                     ws + OFF_GN, ws + OFF_ICS1, 2);
  } else {
    p1_rs1<<<512, 256, 0, stream>>>(ws + OFF_QT, ws + OFF_QK, ws + OFF_IRS1);
    p2_cs1<<<512, 256, 0, stream>>>(ws + OFF_QT, ws + OFF_QK, ws + OFF_IRS1, ws + OFF_ICS1);
    p3_rs2<<<512, 256, 0, stream>>>(ws + OFF_QT, ws + OFF_QK,
                                    ws + OFF_XYZ4, ws + OFF_XYZK,
                                    ws + OFF_IRS1, ws + OFF_ICS1, ws + OFF_THR,
                                    ws + OFF_IRS2);
    k7_gma<<<1024, 256, 0, stream>>>(ws + OFF_QT, ws + OFF_XYZ4,
                                     (const unsigned short*)(ws + OFF_XVB),
                                     ws + OFF_IRS1, ws + OFF_IRS2,
                                     ws + OFF_ICS1, ws + OFF_THR,
                                     ws + OFF_GMA, ws + OFF_G2, ws + OFF_CS2);
    k8_res<<<1024, 256, 0, stream>>>(mot, wt, bt, ws + OFF_FLAG,
                                     ws + OFF_GMA, ws + OFF_G2, ws + OFF_CS2,
                                     ws + OFF_GN, ws + OFF_ICS1, 0);
  }

  k9t_out<<<256, 256, 0, stream>>>(ws + OFF_GMA, ws + OFF_GN, mot, gnw, gnb, pa, al,
                                   ws + OFF_FLAG, d_out);
}